// Round 3
// baseline (3939.967 us; speedup 1.0000x reference)
//
#include <hip/hip_runtime.h>
#include <hip/hip_bf16.h>

typedef __hip_bfloat16 bf16;
typedef const void* cvp;

#define NN 20000
#define NE 160000
#define BN_EPS 1e-5f

#define GF_BIAS 1
#define GF_RELU 2

static __device__ __forceinline__ float b2f(const bf16 x){ return __bfloat162float(x); }
static __device__ __forceinline__ float bits2f(unsigned int u){ return __uint_as_float(u << 16); }
static __device__ __forceinline__ unsigned short f2bits(float f){
  bf16 h = __float2bfloat16(f);
  unsigned short u; __builtin_memcpy(&u, &h, 2); return u;
}
// dtype-flexible weight load: bf=true -> bf16, else fp32. Loads kept inside
// branches (not speculated) so the wrong-width interpretation is never read.
static __device__ __forceinline__ float ldw(cvp p, size_t i, bool bf){
  if (bf) { return b2f(((const bf16*)p)[i]); }
  else    { return ((const float*)p)[i]; }
}

static inline int cdiv(int a, int b){ return (a + b - 1) / b; }

// ---------------- diagnostics ----------------

// hdr[0] = dtype flag (1 = bf16 inputs, 0 = fp32 inputs); hdr[1] = first-NaN phase code
__global__ void k_probe(cvp ue, float* __restrict__ hdr){
  __shared__ int wild;
  if (threadIdx.x == 0) wild = 0;
  __syncthreads();
  const bf16* p = (const bf16*)ue;
  bool bad = false;
  for (int j = 0; j < 16; j++){
    float v = b2f(p[threadIdx.x * 16 + j]);
    if (!(v > -1e3f && v < 1e3f)) bad = true;   // catches NaN/Inf/wild
  }
  if (bad) wild = 1;
  __syncthreads();
  if (threadIdx.x == 0) hdr[0] = wild ? 0.f : 1.f;
}

__global__ void k_chk(const unsigned short* __restrict__ x, int n, float code,
                      float* __restrict__ hdr){
  bool bad = false;
  for (int k = blockIdx.x * 256 + threadIdx.x; k < n; k += gridDim.x * 256){
    if ((x[k] & 0x7F80u) == 0x7F80u) bad = true;   // bf16 Inf/NaN exponent
  }
  if (bad && hdr[1] == 0.f) hdr[1] = code;
}

__global__ void k_diag_out(const float* __restrict__ hdr, void* out){
  float d = hdr[1];
  if (d == 0.f) return;
  int i = blockIdx.x * 256 + threadIdx.x;
  if (i >= NN) return;
  float v = d * 1000.f + hdr[0] * 100.f;
  if (hdr[0] != 0.f) ((bf16*)out)[i] = __float2bfloat16(v);
  else               ((float*)out)[i] = v;
}

__global__ void k_wsdiag(const float* __restrict__ hdr, void* out, float val){
  int i = blockIdx.x * 256 + threadIdx.x;
  if (i >= NN) return;
  if (hdr[0] != 0.f) ((bf16*)out)[i] = __float2bfloat16(val);
  else               ((float*)out)[i] = val;
}

// ---------------- gather / degree ----------------

__global__ void k_gather(const int* __restrict__ uidx, const int* __restrict__ iidx,
                         cvp ue, cvp ie, bf16* __restrict__ x0,
                         const float* __restrict__ hdr){
  const bool bf = hdr[0] != 0.f;
  int idx = blockIdx.x * 256 + threadIdx.x;
  if (idx >= NN * 128) return;
  int i = idx >> 7, c = idx & 127;
  float v = (c < 64) ? ldw(ue, (size_t)uidx[i] * 64 + c, bf)
                     : ldw(ie, (size_t)iidx[i] * 64 + (c - 64), bf);
  x0[idx] = __float2bfloat16(v);
}

__global__ void k_indeg(const int* __restrict__ dst, float* __restrict__ indeg){
  int e = blockIdx.x * 256 + threadIdx.x;
  if (e < NE) atomicAdd(&indeg[dst[e]], 1.0f);
}

__global__ void k_norms(const float* __restrict__ indeg, float* __restrict__ dg,
                        float* __restrict__ dc, float* __restrict__ ic){
  int i = blockIdx.x * 256 + threadIdx.x;
  if (i >= NN) return;
  float d = indeg[i];
  dg[i] = rsqrtf(d + 1.0f);
  dc[i] = (d > 0.f) ? rsqrtf(d) : 0.f;
  ic[i] = 1.0f / fmaxf(d, 1.0f);
}

// ------- GEMM: C_bf16[M,N] = act( A1@B1 (+ A2@B2) + bias ), A bf16, B/bias dtype-flex -------

__global__ __launch_bounds__(256) void k_gemm2(
    const bf16* __restrict__ A1, cvp B1, int K1,
    const bf16* __restrict__ A2, cvp B2, int K2,
    cvp bias, bf16* __restrict__ C,
    int M, int Ncol, int flags, const float* __restrict__ hdr){
  const bool bf = hdr[0] != 0.f;
  __shared__ float As[16][68];
  __shared__ float Bs[16][64];
  const int tid = threadIdx.x;
  const int tx = tid & 15, ty = tid >> 4;
  const int row0 = blockIdx.y * 64, col0 = blockIdx.x * 64;
  const int am = tid >> 2;
  const int ak = (tid & 3) * 4;
  const int bn = tid & 63, bk = tid >> 6;

  float acc[4][4] = {{0.f}};
  const int npass = (A2 != nullptr) ? 2 : 1;

  for (int pass = 0; pass < npass; pass++){
    const bf16* A = pass ? A2 : A1;
    cvp B = pass ? B2 : B1;
    const int K = pass ? K2 : K1;
    for (int k0 = 0; k0 < K; k0 += 16){
      uint2 ra = make_uint2(0u, 0u);
      if (row0 + am < M) ra = *(const uint2*)(A + (size_t)(row0 + am) * K + k0 + ak);
      As[ak + 0][am] = bits2f(ra.x & 0xffffu); As[ak + 1][am] = bits2f(ra.x >> 16);
      As[ak + 2][am] = bits2f(ra.y & 0xffffu); As[ak + 3][am] = bits2f(ra.y >> 16);
#pragma unroll
      for (int i = 0; i < 4; i++){
        int kk = bk + i * 4;
        Bs[kk][bn] = ldw(B, (size_t)(k0 + kk) * Ncol + col0 + bn, bf);
      }
      __syncthreads();
#pragma unroll
      for (int kk = 0; kk < 16; kk++){
        const float4 a4 = *(const float4*)&As[kk][ty * 4];
        const float4 b4 = *(const float4*)&Bs[kk][tx * 4];
        acc[0][0] += a4.x * b4.x; acc[0][1] += a4.x * b4.y; acc[0][2] += a4.x * b4.z; acc[0][3] += a4.x * b4.w;
        acc[1][0] += a4.y * b4.x; acc[1][1] += a4.y * b4.y; acc[1][2] += a4.y * b4.z; acc[1][3] += a4.y * b4.w;
        acc[2][0] += a4.z * b4.x; acc[2][1] += a4.z * b4.y; acc[2][2] += a4.z * b4.z; acc[2][3] += a4.z * b4.w;
        acc[3][0] += a4.w * b4.x; acc[3][1] += a4.w * b4.y; acc[3][2] += a4.w * b4.z; acc[3][3] += a4.w * b4.w;
      }
      __syncthreads();
    }
  }

  const int cbase = col0 + tx * 4;
#pragma unroll
  for (int i = 0; i < 4; i++){
    int r = row0 + ty * 4 + i;
    if (r >= M) continue;
    float v0 = acc[i][0], v1 = acc[i][1], v2 = acc[i][2], v3 = acc[i][3];
    if (flags & GF_BIAS){
      v0 += ldw(bias, cbase + 0, bf); v1 += ldw(bias, cbase + 1, bf);
      v2 += ldw(bias, cbase + 2, bf); v3 += ldw(bias, cbase + 3, bf);
    }
    if (flags & GF_RELU){
      v0 = fmaxf(v0, 0.f); v1 = fmaxf(v1, 0.f); v2 = fmaxf(v2, 0.f); v3 = fmaxf(v3, 0.f);
    }
    unsigned int lo = (unsigned int)f2bits(v0) | ((unsigned int)f2bits(v1) << 16);
    unsigned int hi = (unsigned int)f2bits(v2) | ((unsigned int)f2bits(v3) << 16);
    *(uint2*)(C + (size_t)r * Ncol + cbase) = make_uint2(lo, hi);
  }
}

// ---------------- scatter: out_f32[dst] += sign*(w[s]*w[d]) * x_bf16[src] ----------------

__global__ void k_scatter(const int* __restrict__ src, const int* __restrict__ dst,
                          const float* __restrict__ wnode, float sign,
                          const bf16* __restrict__ x, float* __restrict__ out,
                          int qshift){
  int idx = blockIdx.x * 256 + threadIdx.x;
  int total = NE << qshift;
  if (idx >= total) return;
  int e = idx >> qshift, q = idx & ((1 << qshift) - 1);
  int F = 4 << qshift;
  int s = src[e], d = dst[e];
  float w = sign;
  if (wnode) w *= wnode[s] * wnode[d];
  int c = q * 4;
  uint2 r = *(const uint2*)(x + (size_t)s * F + c);
  float* o = out + (size_t)d * F + c;
  atomicAdd(o + 0, w * bits2f(r.x & 0xffffu));
  atomicAdd(o + 1, w * bits2f(r.x >> 16));
  atomicAdd(o + 2, w * bits2f(r.y & 0xffffu));
  atomicAdd(o + 3, w * bits2f(r.y >> 16));
}

__global__ void k_gcn_init(const bf16* __restrict__ xw, const float* __restrict__ dg,
                           cvp bias, float* __restrict__ out,
                           int fshift, int total, const float* __restrict__ hdr){
  const bool bf = hdr[0] != 0.f;
  int idx = blockIdx.x * 256 + threadIdx.x;
  if (idx >= total) return;
  int i = idx >> fshift, c = idx & ((1 << fshift) - 1);
  float w = dg[i];
  out[idx] = w * w * b2f(xw[idx]) + ldw(bias, c, bf);
}

// ---------------- batchnorm ----------------

__global__ void k_bn_stats(const float* __restrict__ x, float* __restrict__ stats, int F){
  int c = threadIdx.x & (F - 1);
  int rsub = threadIdx.x / F;
  int rpi = 256 / F;
  int r0 = blockIdx.x * 128;
  int rend = min(NN, r0 + 128);
  float s1 = 0.f, s2 = 0.f;
  for (int r = r0 + rsub; r < rend; r += rpi){
    float v = x[(size_t)r * F + c];
    s1 += v; s2 += v * v;
  }
  atomicAdd(&stats[c], s1);
  atomicAdd(&stats[F + c], s2);
}

__global__ void k_bn_apply(const float* __restrict__ x, const float* __restrict__ stats,
                           cvp g, cvp b, int fshift, int total, bf16* __restrict__ out,
                           const float* __restrict__ hdr){
  const bool bf = hdr[0] != 0.f;
  int idx = blockIdx.x * 256 + threadIdx.x;
  if (idx >= total) return;
  int F = 1 << fshift;
  int c = idx & (F - 1);
  float mu = stats[c] * (1.0f / NN);
  float var = fmaxf(stats[F + c] * (1.0f / NN) - mu * mu, 0.f);
  float v = (x[idx] - mu) * rsqrtf(var + BN_EPS) * ldw(g, c, bf) + ldw(b, c, bf);
  out[idx] = __float2bfloat16(fmaxf(v, 0.f));
}

__global__ void k_rowscale_cast(const float* __restrict__ in, const float* __restrict__ w,
                                bf16* __restrict__ out, int fshift, int total){
  int idx = blockIdx.x * 256 + threadIdx.x;
  if (idx >= total) return;
  float s = w ? w[idx >> fshift] : 1.0f;
  out[idx] = __float2bfloat16(in[idx] * s);
}

// ---------------- GAT ----------------

static __device__ __forceinline__ void atomicMaxF(float* a, float v){
  if (v >= 0.f) atomicMax((int*)a, __float_as_int(v));
  else          atomicMin((unsigned int*)a, __float_as_uint(v));
}

__global__ void k_gat_alar(const bf16* __restrict__ xp, cvp as_, cvp ad_,
                           float* __restrict__ al, float* __restrict__ ar,
                           float* __restrict__ m, const float* __restrict__ hdr){
  const bool bf = hdr[0] != 0.f;
  int idx = blockIdx.x * 256 + threadIdx.x;
  if (idx >= NN * 2) return;
  int i = idx >> 1, h = idx & 1;
  const bf16* row = xp + (size_t)i * 256 + h * 128;
  float sa = 0.f, sd = 0.f;
  for (int c = 0; c < 128; c++){
    float v = b2f(row[c]);
    sa += v * ldw(as_, h * 128 + c, bf);
    sd += v * ldw(ad_, h * 128 + c, bf);
  }
  al[idx] = sa; ar[idx] = sd;
  float e = sa + sd;
  m[idx] = (e > 0.f) ? e : 0.2f * e;
}

__global__ void k_gat_emax(const int* __restrict__ src, const int* __restrict__ dst,
                           const float* __restrict__ al, const float* __restrict__ ar,
                           float* __restrict__ m){
  int idx = blockIdx.x * 256 + threadIdx.x;
  if (idx >= NE * 2) return;
  int e = idx >> 1, h = idx & 1;
  int s = src[e], d = dst[e];
  float v = al[s * 2 + h] + ar[d * 2 + h];
  v = (v > 0.f) ? v : 0.2f * v;
  atomicMaxF(&m[d * 2 + h], v);
}

__global__ void k_gat_loop_init(const bf16* __restrict__ xp, const float* __restrict__ al,
                                const float* __restrict__ ar, const float* __restrict__ m,
                                float* __restrict__ denom, float* __restrict__ acc){
  int idx = blockIdx.x * 256 + threadIdx.x;
  if (idx >= NN * 64) return;
  int i = idx >> 6, rem = idx & 63;
  int h = rem >> 5, q = rem & 31, c = q * 4;
  int ih = i * 2 + h;
  float e = al[ih] + ar[ih];
  e = (e > 0.f) ? e : 0.2f * e;
  float ex = expf(e - m[ih]);
  if (q == 0) denom[ih] = ex;
  uint2 r = *(const uint2*)(xp + (size_t)i * 256 + h * 128 + c);
  float* arow = acc + (size_t)i * 256 + h * 128 + c;
  arow[0] = ex * bits2f(r.x & 0xffffu); arow[1] = ex * bits2f(r.x >> 16);
  arow[2] = ex * bits2f(r.y & 0xffffu); arow[3] = ex * bits2f(r.y >> 16);
}

__global__ void k_gat_eex(const int* __restrict__ src, const int* __restrict__ dst,
                          const float* __restrict__ al, const float* __restrict__ ar,
                          const float* __restrict__ m, float* __restrict__ exb,
                          float* __restrict__ denom){
  int idx = blockIdx.x * 256 + threadIdx.x;
  if (idx >= NE * 2) return;
  int e = idx >> 1, h = idx & 1;
  int s = src[e], d = dst[e];
  float v = al[s * 2 + h] + ar[d * 2 + h];
  v = (v > 0.f) ? v : 0.2f * v;
  float ex = expf(v - m[d * 2 + h]);
  exb[idx] = ex;
  atomicAdd(&denom[d * 2 + h], ex);
}

__global__ void k_gat_scatter(const int* __restrict__ src, const int* __restrict__ dst,
                              const float* __restrict__ exb, const bf16* __restrict__ xp,
                              float* __restrict__ acc){
  int idx = blockIdx.x * 256 + threadIdx.x;
  if (idx >= NE * 64) return;
  int e = idx >> 6, rem = idx & 63;
  int h = rem >> 5, q = rem & 31, c = q * 4;
  int s = src[e], d = dst[e];
  float w = exb[e * 2 + h];
  uint2 r = *(const uint2*)(xp + (size_t)s * 256 + h * 128 + c);
  float* arow = acc + (size_t)d * 256 + h * 128 + c;
  atomicAdd(arow + 0, w * bits2f(r.x & 0xffffu));
  atomicAdd(arow + 1, w * bits2f(r.x >> 16));
  atomicAdd(arow + 2, w * bits2f(r.y & 0xffffu));
  atomicAdd(arow + 3, w * bits2f(r.y >> 16));
}

__global__ void k_gat_final(const float* __restrict__ acc, const float* __restrict__ denom,
                            cvp bias, bf16* __restrict__ out,
                            const float* __restrict__ hdr){
  const bool bf = hdr[0] != 0.f;
  int idx = blockIdx.x * 256 + threadIdx.x;
  if (idx >= NN * 128) return;
  int i = idx >> 7, c = idx & 127;
  float d0 = fmaxf(denom[i * 2], 1e-30f), d1 = fmaxf(denom[i * 2 + 1], 1e-30f);
  float v = 0.5f * (acc[(size_t)i * 256 + c] / d0
                  + acc[(size_t)i * 256 + 128 + c] / d1) + ldw(bias, c, bf);
  out[idx] = __float2bfloat16((v > 0.f) ? v : expm1f(v));
}

// ---------------- final projection ----------------

__global__ void k_final(const bf16* __restrict__ x, cvp wp, cvp bp, void* out,
                        const float* __restrict__ hdr){
  const bool bf = hdr[0] != 0.f;
  int i = blockIdx.x;
  int t = threadIdx.x;
  float v = b2f(x[(size_t)i * 128 + t]) * ldw(wp, t, bf)
          + b2f(x[(size_t)i * 128 + 64 + t]) * ldw(wp, 64 + t, bf);
#pragma unroll
  for (int off = 32; off > 0; off >>= 1) v += __shfl_down(v, off, 64);
  if (t == 0){
    float r = v + ldw(bp, 0, bf);
    if (bf) ((bf16*)out)[i] = __float2bfloat16(r);
    else    ((float*)out)[i] = r;
  }
}

// ---------------- host ----------------

extern "C" void kernel_launch(void* const* d_in, const int* in_sizes, int n_in,
                              void* d_out, int out_size, void* d_ws, size_t ws_size,
                              hipStream_t stream){
  const int* uidx = (const int*)d_in[0];
  const int* iidx = (const int*)d_in[1];
  const int* eidx = (const int*)d_in[2];
  const int* src = eidx;
  const int* dst = eidx + NE;
  cvp ue  = d_in[3];
  cvp ie  = d_in[4];
  cvp W1  = d_in[5];  cvp b1  = d_in[6];
  cvp W2  = d_in[7];  cvp b2  = d_in[8];
  cvp Wg1 = d_in[9];  cvp bg1 = d_in[10];
  cvp gamma1 = d_in[11]; cvp beta1 = d_in[12];
  cvp Wg2 = d_in[13]; cvp bg2 = d_in[14];
  cvp gamma2 = d_in[15]; cvp beta2 = d_in[16];
  cvp Wsl = d_in[17]; cvp bsl = d_in[18];
  cvp Wsr = d_in[19];
  cvp Wc0 = d_in[20]; cvp Wc1 = d_in[21]; cvp bc = d_in[22];
  cvp Wgat1 = d_in[23]; cvp as1 = d_in[24]; cvp ad1 = d_in[25]; cvp bgat1 = d_in[26];
  cvp Wgat2 = d_in[27]; cvp as2 = d_in[28]; cvp ad2 = d_in[29]; cvp bgat2 = d_in[30];
  cvp Wp = d_in[31]; cvp bp = d_in[32];

  float* ws = (float*)d_ws;
  float* hdr = ws;                                 // 16 floats: [0]=dtype flag, [1]=diag
  const size_t ARENA = 16 + (size_t)NN * 9 + 512 + (size_t)NE * 2 + (size_t)NN * 640;
  const size_t NEEDED = ARENA * 4;

  if (ws_size < 64) return;   // can't even probe; output stays zero (signature absmax~7e-3)

  if (ws_size < NEEDED){
    hipMemsetAsync(hdr, 0, 64, stream);
    k_probe<<<1, 256, 0, stream>>>(ue, hdr);
    float val = 40000.f + (float)(ws_size >> 20) * 64.f;
    k_wsdiag<<<cdiv(NN, 256), 256, 0, stream>>>(hdr, d_out, val);
    return;
  }

  float* indeg = hdr + 16;                         // NN
  float* dg = indeg + NN;                          // NN
  float* dc = dg + NN;                             // NN
  float* ic = dc + NN;                             // NN
  float* al = ic + NN;                             // 2NN
  float* ar = al + 2 * NN;                         // 2NN
  float* mb = ar + 2 * NN;                         // 2NN
  float* dn = mb + 2 * NN;                         // 2NN
  float* stats = dn + 2 * NN;                      // 512
  float* exb = stats + 512;                        // 2NE
  float* S0 = exb + 2 * NE;                        // NN*256 f
  float* S1 = S0 + (size_t)NN * 256;               // NN*128 f
  float* P128 = S1 + (size_t)NN * 128;             // NN*64 f
  float* PA = P128 + (size_t)NN * 64;              // NN*128 f
  float* PB = PA + (size_t)NN * 128;               // NN*64 f

  bf16* x0b  = (bf16*)P128;
  bf16* h1b  = (bf16*)S1;
  bf16* h2b  = (bf16*)S0;
  bf16* xw1b = (bf16*)S1;
  float* g1f = S0;
  bf16* g1b  = (bf16*)PA;
  bf16* xw2b = (bf16*)P128;
  float* x3f = S1;
  bf16* x3b  = (bf16*)PB;
  float* aggf = S1;
  bf16* aggb = (bf16*)P128;
  bf16* x4b  = (bf16*)PA;
  float* tx1f = S1;
  bf16* tx1b = (bf16*)P128;
  bf16* x5b  = (bf16*)PB;
  bf16* xpb  = (bf16*)S1;
  float* accf = S0;
  bf16* x6b  = (bf16*)PA;
  bf16* x7b  = (bf16*)P128;

  auto gemm = [&](const bf16* A1, cvp B1, int K1, const bf16* A2, cvp B2, int K2,
                  cvp bias, bf16* C, int M, int Ncol, int flags){
    dim3 g(Ncol / 64, cdiv(M, 64));
    k_gemm2<<<g, 256, 0, stream>>>(A1, B1, K1, A2, B2, K2, bias, C, M, Ncol, flags, hdr);
  };
  auto chk = [&](const void* buf, int n, float code){
    k_chk<<<1024, 256, 0, stream>>>((const unsigned short*)buf, n, code, hdr);
  };

  hipMemsetAsync(ws, 0, (16 + (size_t)NN) * 4, stream);   // hdr + indeg
  k_probe<<<1, 256, 0, stream>>>(ue, hdr);
  k_indeg<<<cdiv(NE, 256), 256, 0, stream>>>(dst, indeg);
  k_norms<<<cdiv(NN, 256), 256, 0, stream>>>(indeg, dg, dc, ic);

  k_gather<<<cdiv(NN * 128, 256), 256, 0, stream>>>(uidx, iidx, ue, ie, x0b, hdr);
  chk(x0b, NN * 128, 1.f);

  // Phase A — MLP
  {
    const int CH = 4000;
    for (int ofs = 0; ofs < NN; ofs += CH){
      int mc = min(CH, NN - ofs);
      gemm(x0b + (size_t)ofs * 128, W1, 128, nullptr, nullptr, 0, b1, h1b, mc, 1024, GF_BIAS | GF_RELU);
      gemm(h1b, W2, 1024, nullptr, nullptr, 0, b2, h2b + (size_t)ofs * 512, mc, 512, GF_BIAS | GF_RELU);
    }
  }
  chk(h2b, NN * 512, 2.f);

  // Phase B — GCN1 + BN + relu
  gemm(h2b, Wg1, 512, nullptr, nullptr, 0, nullptr, xw1b, NN, 256, 0);
  k_gcn_init<<<cdiv(NN * 256, 256), 256, 0, stream>>>(xw1b, dg, bg1, g1f, 8, NN * 256, hdr);
  k_scatter<<<cdiv(NE * 64, 256), 256, 0, stream>>>(src, dst, dg, 1.f, xw1b, g1f, 6);
  hipMemsetAsync(stats, 0, 512 * 4, stream);
  k_bn_stats<<<cdiv(NN, 128), 256, 0, stream>>>(g1f, stats, 256);
  k_bn_apply<<<cdiv(NN * 256, 256), 256, 0, stream>>>(g1f, stats, gamma1, beta1, 8, NN * 256, g1b, hdr);
  chk(g1b, NN * 256, 3.f);

  // Phase C — GCN2 + BN + relu
  gemm(g1b, Wg2, 256, nullptr, nullptr, 0, nullptr, xw2b, NN, 128, 0);
  k_gcn_init<<<cdiv(NN * 128, 256), 256, 0, stream>>>(xw2b, dg, bg2, x3f, 7, NN * 128, hdr);
  k_scatter<<<cdiv(NE * 32, 256), 256, 0, stream>>>(src, dst, dg, 1.f, xw2b, x3f, 5);
  hipMemsetAsync(stats, 0, 256 * 4, stream);
  k_bn_stats<<<cdiv(NN, 128), 256, 0, stream>>>(x3f, stats, 128);
  k_bn_apply<<<cdiv(NN * 128, 256), 256, 0, stream>>>(x3f, stats, gamma2, beta2, 7, NN * 128, x3b, hdr);
  chk(x3b, NN * 128, 4.f);

  // Phase D — SAGE
  hipMemsetAsync(aggf, 0, (size_t)NN * 128 * 4, stream);
  k_scatter<<<cdiv(NE * 32, 256), 256, 0, stream>>>(src, dst, nullptr, 1.f, x3b, aggf, 5);
  k_rowscale_cast<<<cdiv(NN * 128, 256), 256, 0, stream>>>(aggf, ic, aggb, 7, NN * 128);
  gemm(aggb, Wsl, 128, x3b, Wsr, 128, bsl, x4b, NN, 128, GF_BIAS | GF_RELU);
  chk(x4b, NN * 128, 5.f);

  // Phase E — Cheb
  hipMemsetAsync(tx1f, 0, (size_t)NN * 128 * 4, stream);
  k_scatter<<<cdiv(NE * 32, 256), 256, 0, stream>>>(src, dst, dc, -1.f, x4b, tx1f, 5);
  k_rowscale_cast<<<cdiv(NN * 128, 256), 256, 0, stream>>>(tx1f, nullptr, tx1b, 7, NN * 128);
  gemm(x4b, Wc0, 128, tx1b, Wc1, 128, bc, x5b, NN, 128, GF_BIAS | GF_RELU);
  chk(x5b, NN * 128, 6.f);

  // Phases F/G — GAT
  auto gat_layer = [&](const bf16* xin, cvp Wg, cvp vas, cvp vad, cvp bg, bf16* xout){
    gemm(xin, Wg, 128, nullptr, nullptr, 0, nullptr, xpb, NN, 256, 0);
    k_gat_alar<<<cdiv(NN * 2, 256), 256, 0, stream>>>(xpb, vas, vad, al, ar, mb, hdr);
    k_gat_emax<<<cdiv(NE * 2, 256), 256, 0, stream>>>(src, dst, al, ar, mb);
    k_gat_loop_init<<<cdiv(NN * 64, 256), 256, 0, stream>>>(xpb, al, ar, mb, dn, accf);
    k_gat_eex<<<cdiv(NE * 2, 256), 256, 0, stream>>>(src, dst, al, ar, mb, exb, dn);
    k_gat_scatter<<<cdiv(NE * 64, 256), 256, 0, stream>>>(src, dst, exb, xpb, accf);
    k_gat_final<<<cdiv(NN * 128, 256), 256, 0, stream>>>(accf, dn, bg, xout, hdr);
  };

  gat_layer(x5b, Wgat1, as1, ad1, bgat1, x6b);
  chk(x6b, NN * 128, 7.f);
  gat_layer(x6b, Wgat2, as2, ad2, bgat2, x7b);
  chk(x7b, NN * 128, 8.f);

  k_final<<<NN, 64, 0, stream>>>(x7b, Wp, bp, d_out, hdr);
  k_diag_out<<<cdiv(NN, 256), 256, 0, stream>>>(hdr, d_out);
}

// Round 6
// 1548.077 us; speedup vs baseline: 2.5451x; 2.5451x over previous
//
#include <hip/hip_runtime.h>
#include <hip/hip_bf16.h>

typedef __hip_bfloat16 bf16;

#define NN 20000
#define NE 160000
#define BN_EPS 1e-5f

#define GF_BIAS 1
#define GF_RELU 2

static __device__ __forceinline__ float b2f(const bf16 x){ return __bfloat162float(x); }
static __device__ __forceinline__ float bits2f(unsigned int u){ return __uint_as_float(u << 16); }
static __device__ __forceinline__ unsigned short f2bits(float f){
  bf16 h = __float2bfloat16(f);
  unsigned short u; __builtin_memcpy(&u, &h, 2); return u;
}
static __device__ __forceinline__ float lrelu(float v){ return (v > 0.f) ? v : 0.2f * v; }

static inline int cdiv(int a, int b){ return (a + b - 1) / b; }

// ---------------- diagnostics (strip once green) ----------------

__global__ void k_chk_bf(const unsigned short* __restrict__ x, int n, int code,
                         int* __restrict__ diag){
  bool bad = false;
  for (int k = blockIdx.x * 256 + threadIdx.x; k < n; k += gridDim.x * 256)
    if ((x[k] & 0x7F80u) == 0x7F80u) bad = true;
  if (bad) atomicCAS(diag, 0, code);
}

__global__ void k_csrchk(const int* __restrict__ rowptr, const int* __restrict__ colsrc,
                         int* __restrict__ diag){
  bool bad = false;
  for (int i = blockIdx.x * 256 + threadIdx.x; i < NN; i += gridDim.x * 256){
    int a = rowptr[i], b = rowptr[i + 1];
    if (a < 0 || b < a || b > NE) bad = true;
  }
  for (int e = blockIdx.x * 256 + threadIdx.x; e < NE; e += gridDim.x * 256)
    if ((unsigned)colsrc[e] >= (unsigned)NN) bad = true;
  if (bad) atomicCAS(diag, 0, 9);
}

__global__ void k_diag_out(const int* __restrict__ diag, float* __restrict__ out){
  int d = *diag;
  if (d == 0) return;
  int i = blockIdx.x * 256 + threadIdx.x;
  if (i < NN) out[i] = (float)(d * 100);
}

// ---------------- CSR build ----------------

__global__ void k_ideg(const int* __restrict__ dst, int* __restrict__ ideg){
  int e = blockIdx.x * 256 + threadIdx.x;
  if (e < NE) atomicAdd(&ideg[dst[e]], 1);
}

__global__ __launch_bounds__(256) void k_scan(const int* __restrict__ ideg,
                                              int* __restrict__ rowptr,
                                              int* __restrict__ cursor){
  __shared__ int part[256];
  const int tid = threadIdx.x;
  const int STRIP = (NN + 255) / 256;
  const int lo = tid * STRIP, hi = min(NN, lo + STRIP);
  int s = 0;
  for (int i = lo; i < hi; i++) s += ideg[i];
  part[tid] = s;
  __syncthreads();
  for (int off = 1; off < 256; off <<= 1){
    int t = (tid >= off) ? part[tid - off] : 0;
    __syncthreads();
    part[tid] += t;
    __syncthreads();
  }
  int pre = part[tid] - s;
  for (int i = lo; i < hi; i++){
    rowptr[i] = pre; cursor[i] = pre; pre += ideg[i];
  }
  if (tid == 0) rowptr[NN] = NE;
}

__global__ void k_fill(const int* __restrict__ src, const int* __restrict__ dst,
                       int* __restrict__ cursor, int* __restrict__ colsrc){
  int e = blockIdx.x * 256 + threadIdx.x;
  if (e >= NE) return;
  int pos = atomicAdd(&cursor[dst[e]], 1);
  colsrc[pos] = src[e];
}

__global__ void k_norms(const int* __restrict__ ideg, float* __restrict__ dg,
                        float* __restrict__ dc, float* __restrict__ ic){
  int i = blockIdx.x * 256 + threadIdx.x;
  if (i >= NN) return;
  float d = (float)ideg[i];
  dg[i] = rsqrtf(d + 1.0f);                 // GCN: self-loops added
  dc[i] = (d > 0.f) ? rsqrtf(d) : 0.f;      // Cheb: no self-loops
  ic[i] = 1.0f / fmaxf(d, 1.0f);            // SAGE mean divisor
}

// ---------------- gather: fp32 embeddings -> bf16 x0 ----------------

__global__ void k_gather(const int* __restrict__ uidx, const int* __restrict__ iidx,
                         const float* __restrict__ ue, const float* __restrict__ ie,
                         bf16* __restrict__ x0){
  int idx = blockIdx.x * 256 + threadIdx.x;
  if (idx >= NN * 128) return;
  int i = idx >> 7, c = idx & 127;
  float v = (c < 64) ? ue[(size_t)uidx[i] * 64 + c] : ie[(size_t)iidx[i] * 64 + (c - 64)];
  x0[idx] = __float2bfloat16(v);
}

// ------- GEMM: C_bf16[M,N] = act( A1@B1 (+ A2@B2) + bias ), A bf16, B/bias fp32 -------

__global__ __launch_bounds__(256) void k_gemm2(
    const bf16* __restrict__ A1, const float* __restrict__ B1, int K1,
    const bf16* __restrict__ A2, const float* __restrict__ B2, int K2,
    const float* __restrict__ bias, bf16* __restrict__ C,
    int M, int Ncol, int flags){
  __shared__ float As[16][68];
  __shared__ float Bs[16][64];
  const int tid = threadIdx.x;
  const int tx = tid & 15, ty = tid >> 4;
  const int row0 = blockIdx.y * 64, col0 = blockIdx.x * 64;
  const int am = tid >> 2;
  const int ak = (tid & 3) * 4;
  const int bn = tid & 63, bk = tid >> 6;

  float acc[4][4] = {{0.f}};
  const int npass = (A2 != nullptr) ? 2 : 1;

  for (int pass = 0; pass < npass; pass++){
    const bf16* A = pass ? A2 : A1;
    const float* B = pass ? B2 : B1;
    const int K = pass ? K2 : K1;
    for (int k0 = 0; k0 < K; k0 += 16){
      uint2 ra = make_uint2(0u, 0u);
      if (row0 + am < M) ra = *(const uint2*)(A + (size_t)(row0 + am) * K + k0 + ak);
      As[ak + 0][am] = bits2f(ra.x & 0xffffu); As[ak + 1][am] = bits2f(ra.x >> 16);
      As[ak + 2][am] = bits2f(ra.y & 0xffffu); As[ak + 3][am] = bits2f(ra.y >> 16);
#pragma unroll
      for (int i = 0; i < 4; i++){
        int kk = bk + i * 4;
        Bs[kk][bn] = B[(size_t)(k0 + kk) * Ncol + col0 + bn];
      }
      __syncthreads();
#pragma unroll
      for (int kk = 0; kk < 16; kk++){
        const float4 a4 = *(const float4*)&As[kk][ty * 4];
        const float4 b4 = *(const float4*)&Bs[kk][tx * 4];
        acc[0][0] += a4.x * b4.x; acc[0][1] += a4.x * b4.y; acc[0][2] += a4.x * b4.z; acc[0][3] += a4.x * b4.w;
        acc[1][0] += a4.y * b4.x; acc[1][1] += a4.y * b4.y; acc[1][2] += a4.y * b4.z; acc[1][3] += a4.y * b4.w;
        acc[2][0] += a4.z * b4.x; acc[2][1] += a4.z * b4.y; acc[2][2] += a4.z * b4.z; acc[2][3] += a4.z * b4.w;
        acc[3][0] += a4.w * b4.x; acc[3][1] += a4.w * b4.y; acc[3][2] += a4.w * b4.z; acc[3][3] += a4.w * b4.w;
      }
      __syncthreads();
    }
  }

  const int cbase = col0 + tx * 4;
#pragma unroll
  for (int i = 0; i < 4; i++){
    int r = row0 + ty * 4 + i;
    if (r >= M) continue;
    float v0 = acc[i][0], v1 = acc[i][1], v2 = acc[i][2], v3 = acc[i][3];
    if (flags & GF_BIAS){
      v0 += bias[cbase + 0]; v1 += bias[cbase + 1];
      v2 += bias[cbase + 2]; v3 += bias[cbase + 3];
    }
    if (flags & GF_RELU){
      v0 = fmaxf(v0, 0.f); v1 = fmaxf(v1, 0.f); v2 = fmaxf(v2, 0.f); v3 = fmaxf(v3, 0.f);
    }
    unsigned int lo = (unsigned int)f2bits(v0) | ((unsigned int)f2bits(v1) << 16);
    unsigned int hi = (unsigned int)f2bits(v2) | ((unsigned int)f2bits(v3) << 16);
    *(uint2*)(C + (size_t)r * Ncol + cbase) = make_uint2(lo, hi);
  }
}

// ---------------- CSR aggregation (no atomics) ----------------
// mode 0 (GCN):  outf = dg[d]*Σ dg[s]x[s][c] + dg[d]^2 x[d][c] + bias[c]
// mode 1 (SAGE): outb = (Σ x[s][c]) * ic[d]
// mode 2 (Cheb): outb = -dc[d] * Σ dc[s] x[s][c]

__global__ void k_agg(const int* __restrict__ rowptr, const int* __restrict__ colsrc,
                      const bf16* __restrict__ x, const float* __restrict__ wn,
                      const float* __restrict__ icv, const float* __restrict__ bias,
                      float* __restrict__ outf, bf16* __restrict__ outb,
                      int fshift, int mode){
  int idx = blockIdx.x * 256 + threadIdx.x;
  int total = NN << fshift;
  if (idx >= total) return;
  int d = idx >> fshift, c = idx & ((1 << fshift) - 1);
  int F = 1 << fshift;
  int r0 = rowptr[d], r1 = rowptr[d + 1];
  float sum = 0.f;
  if (mode == 0){
    for (int r = r0; r < r1; r++){
      int s = colsrc[r];
      sum += wn[s] * b2f(x[(size_t)s * F + c]);
    }
    float w = wn[d];
    outf[idx] = w * sum + w * w * b2f(x[(size_t)d * F + c]) + bias[c];
  } else if (mode == 1){
    for (int r = r0; r < r1; r++)
      sum += b2f(x[(size_t)colsrc[r] * F + c]);
    outb[idx] = __float2bfloat16(sum * icv[d]);
  } else {
    for (int r = r0; r < r1; r++){
      int s = colsrc[r];
      sum += wn[s] * b2f(x[(size_t)s * F + c]);
    }
    outb[idx] = __float2bfloat16(-wn[d] * sum);
  }
}

// ---------------- batchnorm (training-mode, biased var) ----------------

__global__ void k_bn_stats(const float* __restrict__ x, float* __restrict__ stats, int F){
  int c = threadIdx.x & (F - 1);
  int rsub = threadIdx.x / F;
  int rpi = 256 / F;
  int r0 = blockIdx.x * 128;
  int rend = min(NN, r0 + 128);
  float s1 = 0.f, s2 = 0.f;
  for (int r = r0 + rsub; r < rend; r += rpi){
    float v = x[(size_t)r * F + c];
    s1 += v; s2 += v * v;
  }
  atomicAdd(&stats[c], s1);
  atomicAdd(&stats[F + c], s2);
}

__global__ void k_bn_apply(const float* __restrict__ x, const float* __restrict__ stats,
                           const float* __restrict__ g, const float* __restrict__ b,
                           int fshift, int total, bf16* __restrict__ out){
  int idx = blockIdx.x * 256 + threadIdx.x;
  if (idx >= total) return;
  int F = 1 << fshift;
  int c = idx & (F - 1);
  float mu = stats[c] * (1.0f / NN);
  float var = fmaxf(stats[F + c] * (1.0f / NN) - mu * mu, 0.f);
  float v = (x[idx] - mu) * rsqrtf(var + BN_EPS) * g[c] + b[c];
  out[idx] = __float2bfloat16(fmaxf(v, 0.f));
}

// ---------------- GAT ----------------

__global__ void k_gat_alar(const bf16* __restrict__ xp, const float* __restrict__ as_,
                           const float* __restrict__ ad_, float* __restrict__ al,
                           float* __restrict__ ar){
  int idx = blockIdx.x * 256 + threadIdx.x;
  if (idx >= NN * 2) return;
  int i = idx >> 1, h = idx & 1;
  const bf16* row = xp + (size_t)i * 256 + h * 128;
  const float* va = as_ + h * 128;
  const float* vd = ad_ + h * 128;
  float sa = 0.f, sd = 0.f;
  for (int c = 0; c < 128; c++){
    float v = b2f(row[c]);
    sa += v * va[c];
    sd += v * vd[c];
  }
  al[idx] = sa; ar[idx] = sd;
}

__global__ __launch_bounds__(64) void k_gat(const int* __restrict__ rowptr,
                                            const int* __restrict__ colsrc,
                                            const bf16* __restrict__ xp,
                                            const float* __restrict__ al,
                                            const float* __restrict__ ar,
                                            const float* __restrict__ bias,
                                            bf16* __restrict__ out){
  int d = blockIdx.x;
  int lane = threadIdx.x;
  int r0 = rowptr[d], r1 = rowptr[d + 1];
  float m[2], sm[2];
#pragma unroll
  for (int h = 0; h < 2; h++){
    float ard = ar[d * 2 + h];
    float eself = lrelu(al[d * 2 + h] + ard);
    float mx = eself;
    for (int r = r0 + lane; r < r1; r += 64)
      mx = fmaxf(mx, lrelu(al[colsrc[r] * 2 + h] + ard));
#pragma unroll
    for (int off = 32; off > 0; off >>= 1) mx = fmaxf(mx, __shfl_xor(mx, off));
    float ps = (lane == 0) ? expf(eself - mx) : 0.f;
    for (int r = r0 + lane; r < r1; r += 64)
      ps += expf(lrelu(al[colsrc[r] * 2 + h] + ard) - mx);
#pragma unroll
    for (int off = 32; off > 0; off >>= 1) ps += __shfl_xor(ps, off);
    m[h] = mx; sm[h] = ps;
  }
#pragma unroll
  for (int chunk = 0; chunk < 2; chunk++){
    int c = chunk * 64 + lane;
    float o[2];
#pragma unroll
    for (int h = 0; h < 2; h++){
      float ard = ar[d * 2 + h];
      float acc = expf(lrelu(al[d * 2 + h] + ard) - m[h]) * b2f(xp[(size_t)d * 256 + h * 128 + c]);
      for (int r = r0; r < r1; r++){
        int s = colsrc[r];
        float w = expf(lrelu(al[s * 2 + h] + ard) - m[h]);
        acc += w * b2f(xp[(size_t)s * 256 + h * 128 + c]);
      }
      o[h] = acc / sm[h];
    }
    float v = 0.5f * (o[0] + o[1]) + bias[c];
    out[(size_t)d * 128 + c] = __float2bfloat16((v > 0.f) ? v : expm1f(v));
  }
}

// ---------------- final projection ----------------

__global__ void k_final(const bf16* __restrict__ x, const float* __restrict__ wp,
                        const float* __restrict__ bp, float* __restrict__ out){
  int i = blockIdx.x;
  int t = threadIdx.x;
  float v = b2f(x[(size_t)i * 128 + t]) * wp[t]
          + b2f(x[(size_t)i * 128 + 64 + t]) * wp[64 + t];
#pragma unroll
  for (int off = 32; off > 0; off >>= 1) v += __shfl_down(v, off, 64);
  if (t == 0) out[i] = v + bp[0];
}

// ---------------- host ----------------

extern "C" void kernel_launch(void* const* d_in, const int* in_sizes, int n_in,
                              void* d_out, int out_size, void* d_ws, size_t ws_size,
                              hipStream_t stream){
  const int* uidx = (const int*)d_in[0];
  const int* iidx = (const int*)d_in[1];
  const int* eidx = (const int*)d_in[2];
  const int* src = eidx;
  const int* dst = eidx + NE;
  const float* ue  = (const float*)d_in[3];
  const float* ie  = (const float*)d_in[4];
  const float* W1  = (const float*)d_in[5];  const float* b1  = (const float*)d_in[6];
  const float* W2  = (const float*)d_in[7];  const float* b2  = (const float*)d_in[8];
  const float* Wg1 = (const float*)d_in[9];  const float* bg1 = (const float*)d_in[10];
  const float* gamma1 = (const float*)d_in[11]; const float* beta1 = (const float*)d_in[12];
  const float* Wg2 = (const float*)d_in[13]; const float* bg2 = (const float*)d_in[14];
  const float* gamma2 = (const float*)d_in[15]; const float* beta2 = (const float*)d_in[16];
  const float* Wsl = (const float*)d_in[17]; const float* bsl = (const float*)d_in[18];
  const float* Wsr = (const float*)d_in[19];
  const float* Wc0 = (const float*)d_in[20]; const float* Wc1 = (const float*)d_in[21];
  const float* bc  = (const float*)d_in[22];
  const float* Wgat1 = (const float*)d_in[23]; const float* as1 = (const float*)d_in[24];
  const float* ad1 = (const float*)d_in[25];   const float* bgat1 = (const float*)d_in[26];
  const float* Wgat2 = (const float*)d_in[27]; const float* as2 = (const float*)d_in[28];
  const float* ad2 = (const float*)d_in[29];   const float* bgat2 = (const float*)d_in[30];
  const float* Wp  = (const float*)d_in[31];   const float* bp  = (const float*)d_in[32];

  // ---- workspace: diag + int CSR region + float region (~52.6 MB) ----
  int* diag   = (int*)d_ws;                        // 4 ints
  int* ideg   = diag + 4;                          // NN
  int* rowptr = ideg + NN;                         // NN+2
  int* cursor = rowptr + NN + 2;                   // NN
  int* colsrc = cursor + NN;                       // NE
  float* dg = (float*)(colsrc + NE);               // NN
  float* dc = dg + NN;                             // NN
  float* ic = dc + NN;                             // NN
  float* al = ic + NN;                             // 2NN
  float* ar = al + 2 * NN;                         // 2NN
  float* stats = ar + 2 * NN;                      // 512
  float* S0 = stats + 512;                         // NN*256 f
  float* S1 = S0 + (size_t)NN * 256;               // NN*128 f
  float* P128 = S1 + (size_t)NN * 128;             // NN*64 f
  float* PA = P128 + (size_t)NN * 64;              // NN*128 f
  float* PB = PA + (size_t)NN * 128;               // NN*64 f

  // bf16 phase-reuse views (live ranges disjoint)
  bf16* x0b  = (bf16*)P128;   // A in   [NN,128]
  bf16* h1b  = (bf16*)S1;     // A mid  [4000,1024]
  bf16* h2b  = (bf16*)S0;     // A out  [NN,512]
  bf16* xw1b = (bf16*)S1;     // B      [NN,256]
  float* g1f = S0;            // B f32  [NN,256] (h2 dead after its GEMM)
  bf16* g1b  = (bf16*)PA;     // B out  [NN,256]
  bf16* xw2b = (bf16*)P128;   // C      [NN,128]
  float* x3f = S1;            // C f32  [NN,128]
  bf16* x3b  = (bf16*)PB;     // C out  [NN,128]
  bf16* aggb = (bf16*)P128;   // D      [NN,128]
  bf16* x4b  = (bf16*)PA;     // D out  [NN,128]
  bf16* tx1b = (bf16*)P128;   // E      [NN,128]
  bf16* x5b  = (bf16*)PB;     // E out  [NN,128]
  bf16* xpb  = (bf16*)S1;     // F/G    [NN,256]
  bf16* x6b  = (bf16*)PA;     // F out  [NN,128]
  bf16* x7b  = (bf16*)P128;   // G out  [NN,128]

  auto gemm = [&](const bf16* A1, const float* B1, int K1,
                  const bf16* A2, const float* B2, int K2,
                  const float* bias, bf16* C, int M, int Ncol, int flags){
    dim3 g(Ncol / 64, cdiv(M, 64));
    k_gemm2<<<g, 256, 0, stream>>>(A1, B1, K1, A2, B2, K2, bias, C, M, Ncol, flags);
  };
  auto chkb = [&](const void* buf, int n, int code){
    k_chk_bf<<<256, 256, 0, stream>>>((const unsigned short*)buf, n, code, diag);
  };

  // CSR build + norms
  hipMemsetAsync(diag, 0, (size_t)(4 + NN) * 4, stream);   // diag + ideg
  k_ideg<<<cdiv(NE, 256), 256, 0, stream>>>(dst, ideg);
  k_scan<<<1, 256, 0, stream>>>(ideg, rowptr, cursor);
  k_fill<<<cdiv(NE, 256), 256, 0, stream>>>(src, dst, cursor, colsrc);
  k_csrchk<<<256, 256, 0, stream>>>(rowptr, colsrc, diag);
  k_norms<<<cdiv(NN, 256), 256, 0, stream>>>(ideg, dg, dc, ic);

  k_gather<<<cdiv(NN * 128, 256), 256, 0, stream>>>(uidx, iidx, ue, ie, x0b);
  chkb(x0b, NN * 128, 1);

  // Phase A — MLP (row-chunked)
  {
    const int CH = 4000;
    for (int ofs = 0; ofs < NN; ofs += CH){
      int mc = min(CH, NN - ofs);
      gemm(x0b + (size_t)ofs * 128, W1, 128, nullptr, nullptr, 0, b1, h1b, mc, 1024, GF_BIAS | GF_RELU);
      gemm(h1b, W2, 1024, nullptr, nullptr, 0, b2, h2b + (size_t)ofs * 512, mc, 512, GF_BIAS | GF_RELU);
    }
  }
  chkb(h2b, NN * 512, 2);

  // Phase B — GCN1 (512->256) + BN + relu
  gemm(h2b, Wg1, 512, nullptr, nullptr, 0, nullptr, xw1b, NN, 256, 0);
  k_agg<<<cdiv(NN * 256, 256), 256, 0, stream>>>(rowptr, colsrc, xw1b, dg, nullptr, bg1, g1f, nullptr, 8, 0);
  hipMemsetAsync(stats, 0, 512 * 4, stream);
  k_bn_stats<<<cdiv(NN, 128), 256, 0, stream>>>(g1f, stats, 256);
  k_bn_apply<<<cdiv(NN * 256, 256), 256, 0, stream>>>(g1f, stats, gamma1, beta1, 8, NN * 256, g1b);
  chkb(g1b, NN * 256, 5);

  // Phase C — GCN2 (256->128) + BN + relu
  gemm(g1b, Wg2, 256, nullptr, nullptr, 0, nullptr, xw2b, NN, 128, 0);
  k_agg<<<cdiv(NN * 128, 256), 256, 0, stream>>>(rowptr, colsrc, xw2b, dg, nullptr, bg2, x3f, nullptr, 7, 0);
  hipMemsetAsync(stats, 0, 256 * 4, stream);
  k_bn_stats<<<cdiv(NN, 128), 256, 0, stream>>>(x3f, stats, 128);
  k_bn_apply<<<cdiv(NN * 128, 256), 256, 0, stream>>>(x3f, stats, gamma2, beta2, 7, NN * 128, x3b);
  chkb(x3b, NN * 128, 8);

  // Phase D — SAGE
  k_agg<<<cdiv(NN * 128, 256), 256, 0, stream>>>(rowptr, colsrc, x3b, nullptr, ic, nullptr, nullptr, aggb, 7, 1);
  gemm(aggb, Wsl, 128, x3b, Wsr, 128, bsl, x4b, NN, 128, GF_BIAS | GF_RELU);
  chkb(x4b, NN * 128, 11);

  // Phase E — Cheb
  k_agg<<<cdiv(NN * 128, 256), 256, 0, stream>>>(rowptr, colsrc, x4b, dc, nullptr, nullptr, nullptr, tx1b, 7, 2);
  gemm(x4b, Wc0, 128, tx1b, Wc1, 128, bc, x5b, NN, 128, GF_BIAS | GF_RELU);
  chkb(x5b, NN * 128, 13);

  // Phases F/G — GAT (atomic-free, wave-per-node)
  auto gat_layer = [&](const bf16* xin, const float* Wg, const float* vas, const float* vad,
                       const float* bg, bf16* xout){
    gemm(xin, Wg, 128, nullptr, nullptr, 0, nullptr, xpb, NN, 256, 0);
    k_gat_alar<<<cdiv(NN * 2, 256), 256, 0, stream>>>(xpb, vas, vad, al, ar);
    k_gat<<<NN, 64, 0, stream>>>(rowptr, colsrc, xpb, al, ar, bg, xout);
  };

  gat_layer(x5b, Wgat1, as1, ad1, bgat1, x6b);
  chkb(x6b, NN * 128, 16);
  gat_layer(x6b, Wgat2, as2, ad2, bgat2, x7b);
  chkb(x7b, NN * 128, 19);

  // final projection -> fp32 out [NN]
  k_final<<<NN, 64, 0, stream>>>(x7b, Wp, bp, (float*)d_out);
  k_diag_out<<<cdiv(NN, 256), 256, 0, stream>>>(diag, (float*)d_out);
}

// Round 7
// 1208.761 us; speedup vs baseline: 3.2595x; 1.2807x over previous
//
#include <hip/hip_runtime.h>
#include <hip/hip_bf16.h>

typedef __hip_bfloat16 bf16;
typedef short s8v __attribute__((ext_vector_type(8)));
typedef float f4v __attribute__((ext_vector_type(4)));

#define NN 20000
#define NE 160000
#define BN_EPS 1e-5f

#define GF_BIAS 1
#define GF_RELU 2

static __device__ __forceinline__ float b2f(const bf16 x){ return __bfloat162float(x); }
static __device__ __forceinline__ float bits2f(unsigned int u){ return __uint_as_float(u << 16); }
static __device__ __forceinline__ unsigned short f2bits(float f){
  bf16 h = __float2bfloat16(f);
  unsigned short u; __builtin_memcpy(&u, &h, 2); return u;
}
static __device__ __forceinline__ float lrelu(float v){ return (v > 0.f) ? v : 0.2f * v; }

static inline int cdiv(int a, int b){ return (a + b - 1) / b; }

// ---------------- diagnostics (2 tripwires) ----------------

__global__ void k_chk_bf(const unsigned short* __restrict__ x, int n, int code,
                         int* __restrict__ diag){
  bool bad = false;
  for (int k = blockIdx.x * 256 + threadIdx.x; k < n; k += gridDim.x * 256)
    if ((x[k] & 0x7F80u) == 0x7F80u) bad = true;
  if (bad) atomicCAS(diag, 0, code);
}

__global__ void k_diag_out(const int* __restrict__ diag, float* __restrict__ out){
  int d = *diag;
  if (d == 0) return;
  int i = blockIdx.x * 256 + threadIdx.x;
  if (i < NN) out[i] = (float)(d * 100);
}

// ---------------- CSR build ----------------

__global__ void k_ideg(const int* __restrict__ dst, int* __restrict__ ideg){
  int e = blockIdx.x * 256 + threadIdx.x;
  if (e < NE) atomicAdd(&ideg[dst[e]], 1);
}

__global__ __launch_bounds__(256) void k_scan(const int* __restrict__ ideg,
                                              int* __restrict__ rowptr,
                                              int* __restrict__ cursor){
  __shared__ int part[256];
  const int tid = threadIdx.x;
  const int STRIP = (NN + 255) / 256;
  const int lo = tid * STRIP, hi = min(NN, lo + STRIP);
  int s = 0;
  for (int i = lo; i < hi; i++) s += ideg[i];
  part[tid] = s;
  __syncthreads();
  for (int off = 1; off < 256; off <<= 1){
    int t = (tid >= off) ? part[tid - off] : 0;
    __syncthreads();
    part[tid] += t;
    __syncthreads();
  }
  int pre = part[tid] - s;
  for (int i = lo; i < hi; i++){
    rowptr[i] = pre; cursor[i] = pre; pre += ideg[i];
  }
  if (tid == 0) rowptr[NN] = NE;
}

__global__ void k_fill(const int* __restrict__ src, const int* __restrict__ dst,
                       int* __restrict__ cursor, int* __restrict__ colsrc){
  int e = blockIdx.x * 256 + threadIdx.x;
  if (e >= NE) return;
  int pos = atomicAdd(&cursor[dst[e]], 1);
  colsrc[pos] = src[e];
}

__global__ void k_norms(const int* __restrict__ ideg, float* __restrict__ dg,
                        float* __restrict__ dc, float* __restrict__ ic){
  int i = blockIdx.x * 256 + threadIdx.x;
  if (i >= NN) return;
  float d = (float)ideg[i];
  dg[i] = rsqrtf(d + 1.0f);                 // GCN: self-loops added
  dc[i] = (d > 0.f) ? rsqrtf(d) : 0.f;      // Cheb: no self-loops
  ic[i] = 1.0f / fmaxf(d, 1.0f);            // SAGE mean divisor
}

// ---- weight prep: W[K][N] fp32 -> WT_hi/WT_lo [N][K] bf16 (hi+lo ~ fp32 precision) ----

__global__ void k_wt(const float* __restrict__ W, short* __restrict__ hi,
                     short* __restrict__ lo, int K, int nshift){
  int idx = blockIdx.x * 256 + threadIdx.x;
  if (idx >= (K << nshift)) return;
  int n = idx & ((1 << nshift) - 1), k = idx >> nshift;
  float w = W[idx];
  unsigned short h = f2bits(w);
  float hf = bits2f(h);
  unsigned short l = f2bits(w - hf);
  hi[(size_t)n * K + k] = (short)h;
  lo[(size_t)n * K + k] = (short)l;
}

// ---------------- gather: fp32 embeddings -> bf16 x0 ----------------

__global__ void k_gather(const int* __restrict__ uidx, const int* __restrict__ iidx,
                         const float* __restrict__ ue, const float* __restrict__ ie,
                         bf16* __restrict__ x0){
  int idx = blockIdx.x * 256 + threadIdx.x;
  if (idx >= NN * 128) return;
  int i = idx >> 7, c = idx & 127;
  float v = (c < 64) ? ue[(size_t)uidx[i] * 64 + c] : ie[(size_t)iidx[i] * 64 + (c - 64)];
  x0[idx] = __float2bfloat16(v);
}

// ------- MFMA GEMM: C[M,N] = act( Σ_p A_p @ B_pT^T + bias ), 128x128 tile, 4 waves -------
// A bf16 row-major [M][K]; BT bf16(short) row-major [N][K]. K%32==0, N%128==0.

__global__ __launch_bounds__(256) void k_mm(
    const bf16* A0, const short* B0, int K0,
    const bf16* A1, const short* B1, int K1,
    const bf16* A2, const short* B2, int K2,
    const bf16* A3, const short* B3, int K3,
    const float* __restrict__ bias, bf16* __restrict__ C,
    int M, int Ncol, int flags, int npass){
  __shared__ short As[128][40];   // pad 32->40 (80 B row stride, <=2-way conflicts)
  __shared__ short Bs[128][40];
  const int tid = threadIdx.x;
  const int row0 = blockIdx.y * 128, col0 = blockIdx.x * 128;
  const int wid = tid >> 6, lane = tid & 63;
  const int wr = (wid >> 1) * 64, wc = (wid & 1) * 64;
  const int lr = lane & 15, lq = lane >> 4;
  const int sr = tid >> 2, sq = (tid & 3) * 8;

  f4v acc[4][4];
#pragma unroll
  for (int i = 0; i < 4; i++)
#pragma unroll
    for (int j = 0; j < 4; j++)
      acc[i][j] = f4v{0.f, 0.f, 0.f, 0.f};

  const bf16* Aarr[4] = {A0, A1, A2, A3};
  const short* Barr[4] = {B0, B1, B2, B3};
  const int Karr[4] = {K0, K1, K2, K3};

  for (int p = 0; p < npass; p++){
    const short* A = (const short*)Aarr[p];
    const short* BT = Barr[p];
    const int K = Karr[p];
    for (int k0 = 0; k0 < K; k0 += 32){
#pragma unroll
      for (int h = 0; h < 2; h++){
        int r = h * 64 + sr;
        uint4 va = make_uint4(0u, 0u, 0u, 0u);
        int grow = row0 + r;
        if (grow < M) va = *(const uint4*)(A + (size_t)grow * K + k0 + sq);
        *(uint4*)&As[r][sq] = va;
        *(uint4*)&Bs[r][sq] = *(const uint4*)(BT + (size_t)(col0 + r) * K + k0 + sq);
      }
      __syncthreads();
      s8v af[4], bg[4];
#pragma unroll
      for (int i = 0; i < 4; i++) af[i] = *(const s8v*)&As[wr + i * 16 + lr][lq * 8];
#pragma unroll
      for (int j = 0; j < 4; j++) bg[j] = *(const s8v*)&Bs[wc + j * 16 + lr][lq * 8];
#pragma unroll
      for (int i = 0; i < 4; i++)
#pragma unroll
        for (int j = 0; j < 4; j++)
          acc[i][j] = __builtin_amdgcn_mfma_f32_16x16x32_bf16(af[i], bg[j], acc[i][j], 0, 0, 0);
      __syncthreads();
    }
  }

  // epilogue: C/D layout col=lane&15, row=quad*4+reg
#pragma unroll
  for (int i = 0; i < 4; i++){
#pragma unroll
    for (int rg = 0; rg < 4; rg++){
      int row = row0 + wr + i * 16 + lq * 4 + rg;
      if (row >= M) continue;
#pragma unroll
      for (int j = 0; j < 4; j++){
        int col = col0 + wc + j * 16 + lr;
        float v = acc[i][j][rg];
        if (flags & GF_BIAS) v += bias[col];
        if (flags & GF_RELU) v = fmaxf(v, 0.f);
        C[(size_t)row * Ncol + col] = __float2bfloat16(v);
      }
    }
  }
}

// ---------------- CSR aggregation (no atomics) ----------------

__global__ void k_agg(const int* __restrict__ rowptr, const int* __restrict__ colsrc,
                      const bf16* __restrict__ x, const float* __restrict__ wn,
                      const float* __restrict__ icv, const float* __restrict__ bias,
                      float* __restrict__ outf, bf16* __restrict__ outb,
                      int fshift, int mode){
  int idx = blockIdx.x * 256 + threadIdx.x;
  int total = NN << fshift;
  if (idx >= total) return;
  int d = idx >> fshift, c = idx & ((1 << fshift) - 1);
  int F = 1 << fshift;
  int r0 = rowptr[d], r1 = rowptr[d + 1];
  float sum = 0.f;
  if (mode == 0){
    for (int r = r0; r < r1; r++){
      int s = colsrc[r];
      sum += wn[s] * b2f(x[(size_t)s * F + c]);
    }
    float w = wn[d];
    outf[idx] = w * sum + w * w * b2f(x[(size_t)d * F + c]) + bias[c];
  } else if (mode == 1){
    for (int r = r0; r < r1; r++)
      sum += b2f(x[(size_t)colsrc[r] * F + c]);
    outb[idx] = __float2bfloat16(sum * icv[d]);
  } else {
    for (int r = r0; r < r1; r++){
      int s = colsrc[r];
      sum += wn[s] * b2f(x[(size_t)s * F + c]);
    }
    outb[idx] = __float2bfloat16(-wn[d] * sum);
  }
}

// ---------------- batchnorm (training-mode, biased var) ----------------

__global__ void k_bn_stats(const float* __restrict__ x, float* __restrict__ stats, int F){
  int c = threadIdx.x & (F - 1);
  int rsub = threadIdx.x / F;
  int rpi = 256 / F;
  int r0 = blockIdx.x * 128;
  int rend = min(NN, r0 + 128);
  float s1 = 0.f, s2 = 0.f;
  for (int r = r0 + rsub; r < rend; r += rpi){
    float v = x[(size_t)r * F + c];
    s1 += v; s2 += v * v;
  }
  atomicAdd(&stats[c], s1);
  atomicAdd(&stats[F + c], s2);
}

__global__ void k_bn_apply(const float* __restrict__ x, const float* __restrict__ stats,
                           const float* __restrict__ g, const float* __restrict__ b,
                           int fshift, int total, bf16* __restrict__ out){
  int idx = blockIdx.x * 256 + threadIdx.x;
  if (idx >= total) return;
  int F = 1 << fshift;
  int c = idx & (F - 1);
  float mu = stats[c] * (1.0f / NN);
  float var = fmaxf(stats[F + c] * (1.0f / NN) - mu * mu, 0.f);
  float v = (x[idx] - mu) * rsqrtf(var + BN_EPS) * g[c] + b[c];
  out[idx] = __float2bfloat16(fmaxf(v, 0.f));
}

// ---------------- GAT ----------------

__global__ void k_gat_alar(const bf16* __restrict__ xp, const float* __restrict__ as_,
                           const float* __restrict__ ad_, float* __restrict__ al,
                           float* __restrict__ ar){
  int idx = blockIdx.x * 256 + threadIdx.x;
  if (idx >= NN * 2) return;
  int i = idx >> 1, h = idx & 1;
  const bf16* row = xp + (size_t)i * 256 + h * 128;
  const float* va = as_ + h * 128;
  const float* vd = ad_ + h * 128;
  float sa = 0.f, sd = 0.f;
  for (int c = 0; c < 128; c++){
    float v = b2f(row[c]);
    sa += v * va[c];
    sd += v * vd[c];
  }
  al[idx] = sa; ar[idx] = sd;
}

__global__ __launch_bounds__(64) void k_gat(const int* __restrict__ rowptr,
                                            const int* __restrict__ colsrc,
                                            const bf16* __restrict__ xp,
                                            const float* __restrict__ al,
                                            const float* __restrict__ ar,
                                            const float* __restrict__ bias,
                                            bf16* __restrict__ out){
  int d = blockIdx.x;
  int lane = threadIdx.x;
  int r0 = rowptr[d], r1 = rowptr[d + 1];
  float m[2], sm[2];
#pragma unroll
  for (int h = 0; h < 2; h++){
    float ard = ar[d * 2 + h];
    float eself = lrelu(al[d * 2 + h] + ard);
    float mx = eself;
    for (int r = r0 + lane; r < r1; r += 64)
      mx = fmaxf(mx, lrelu(al[colsrc[r] * 2 + h] + ard));
#pragma unroll
    for (int off = 32; off > 0; off >>= 1) mx = fmaxf(mx, __shfl_xor(mx, off));
    float ps = (lane == 0) ? expf(eself - mx) : 0.f;
    for (int r = r0 + lane; r < r1; r += 64)
      ps += expf(lrelu(al[colsrc[r] * 2 + h] + ard) - mx);
#pragma unroll
    for (int off = 32; off > 0; off >>= 1) ps += __shfl_xor(ps, off);
    m[h] = mx; sm[h] = ps;
  }
#pragma unroll
  for (int chunk = 0; chunk < 2; chunk++){
    int c = chunk * 64 + lane;
    float o[2];
#pragma unroll
    for (int h = 0; h < 2; h++){
      float ard = ar[d * 2 + h];
      float acc = expf(lrelu(al[d * 2 + h] + ard) - m[h]) * b2f(xp[(size_t)d * 256 + h * 128 + c]);
      for (int r = r0; r < r1; r++){
        int s = colsrc[r];
        float w = expf(lrelu(al[s * 2 + h] + ard) - m[h]);
        acc += w * b2f(xp[(size_t)s * 256 + h * 128 + c]);
      }
      o[h] = acc / sm[h];
    }
    float v = 0.5f * (o[0] + o[1]) + bias[c];
    out[(size_t)d * 128 + c] = __float2bfloat16((v > 0.f) ? v : expm1f(v));
  }
}

// ---------------- final projection ----------------

__global__ void k_final(const bf16* __restrict__ x, const float* __restrict__ wp,
                        const float* __restrict__ bp, float* __restrict__ out){
  int i = blockIdx.x;
  int t = threadIdx.x;
  float v = b2f(x[(size_t)i * 128 + t]) * wp[t]
          + b2f(x[(size_t)i * 128 + 64 + t]) * wp[64 + t];
#pragma unroll
  for (int off = 32; off > 0; off >>= 1) v += __shfl_down(v, off, 64);
  if (t == 0) out[i] = v + bp[0];
}

// ---------------- host ----------------

extern "C" void kernel_launch(void* const* d_in, const int* in_sizes, int n_in,
                              void* d_out, int out_size, void* d_ws, size_t ws_size,
                              hipStream_t stream){
  const int* uidx = (const int*)d_in[0];
  const int* iidx = (const int*)d_in[1];
  const int* eidx = (const int*)d_in[2];
  const int* src = eidx;
  const int* dst = eidx + NE;
  const float* ue  = (const float*)d_in[3];
  const float* ie  = (const float*)d_in[4];
  const float* W1  = (const float*)d_in[5];  const float* b1  = (const float*)d_in[6];
  const float* W2  = (const float*)d_in[7];  const float* b2  = (const float*)d_in[8];
  const float* Wg1 = (const float*)d_in[9];  const float* bg1 = (const float*)d_in[10];
  const float* gamma1 = (const float*)d_in[11]; const float* beta1 = (const float*)d_in[12];
  const float* Wg2 = (const float*)d_in[13]; const float* bg2 = (const float*)d_in[14];
  const float* gamma2 = (const float*)d_in[15]; const float* beta2 = (const float*)d_in[16];
  const float* Wsl = (const float*)d_in[17]; const float* bsl = (const float*)d_in[18];
  const float* Wsr = (const float*)d_in[19];
  const float* Wc0 = (const float*)d_in[20]; const float* Wc1 = (const float*)d_in[21];
  const float* bc  = (const float*)d_in[22];
  const float* Wgat1 = (const float*)d_in[23]; const float* as1 = (const float*)d_in[24];
  const float* ad1 = (const float*)d_in[25];   const float* bgat1 = (const float*)d_in[26];
  const float* Wgat2 = (const float*)d_in[27]; const float* as2 = (const float*)d_in[28];
  const float* ad2 = (const float*)d_in[29];   const float* bgat2 = (const float*)d_in[30];
  const float* Wp  = (const float*)d_in[31];   const float* bp  = (const float*)d_in[32];

  // ---- workspace (52.98 MB total; proven floor >= 53.2 MB) ----
  int* diag   = (int*)d_ws;                        // 4
  int* ideg   = diag + 4;                          // NN   (dead after norms -> hosts WslT)
  int* rowptr = ideg + NN;                         // NN+4
  int* cursor = rowptr + NN + 4;                   // NN   (dead after fill -> hosts WsrT)
  int* colsrc = cursor + NN;                       // NE
  float* dg = (float*)(colsrc + NE);               // NN
  float* dc = dg + NN;                             // NN
  float* ic = dc + NN;                             // NN
  float* stats = ic + NN;                          // 512
  short* wg1h = (short*)(stats + 512);             // 131072 (persistent weights)
  short* wg1l = wg1h + 131072;
  short* wg2h = wg1l + 131072;                     // 32768
  short* wg2l = wg2h + 32768;
  float* S0 = (float*)(wg2l + 32768);              // NN*256 f
  float* S1 = S0 + (size_t)NN * 256;               // NN*128 f
  float* P128 = S1 + (size_t)NN * 128;             // NN*64 f
  float* PA = P128 + (size_t)NN * 64;              // NN*128 f
  float* PB = PA + (size_t)NN * 128;               // NN*64 f

  // phase-local weight slots (time-disjoint with hosting regions)
  short* wslh = (short*)ideg;       short* wsll = wslh + 16384;   // after k_norms
  short* wsrh = (short*)cursor;     short* wsrl = wsrh + 16384;   // after k_fill
  short* w1h  = (short*)PA;         short* w1l  = w1h + 131072;   // phase A only
  short* w2h  = w1l + 131072;       short* w2l  = w2h + 524288;
  short* wc0h = (short*)(S0 + 80000); short* wc0l = wc0h + 16384; // before E (S0 free)
  short* wc1h = wc0l + 16384;       short* wc1l = wc1h + 16384;
  short* wgat1h = (short*)P128;     short* wgat1l = wgat1h + 32768; // after E (P128 free)
  short* wgat2h = (short*)PB;       short* wgat2l = wgat2h + 32768; // after F (PB free)

  // activation views (live ranges disjoint)
  bf16* x0b  = (bf16*)P128;   // A in   [NN,128]
  bf16* h1b  = (bf16*)S1;     // A mid  [5000,1024]
  bf16* h2b  = (bf16*)S0;     // A out  [NN,512]
  bf16* xw1b = (bf16*)S1;     // B      [NN,256]
  float* g1f = S0;            // B f32  [NN,256]
  bf16* g1b  = (bf16*)PA;     // B out  [NN,256]
  bf16* xw2b = (bf16*)P128;   // C      [NN,128]
  float* x3f = S1;            // C f32  [NN,128]
  bf16* x3b  = (bf16*)PB;     // C out  [NN,128]
  bf16* aggb = (bf16*)P128;   // D      [NN,128]
  bf16* x4b  = (bf16*)PA;     // D out  [NN,128]
  bf16* tx1b = (bf16*)P128;   // E      [NN,128]
  bf16* x5b  = (bf16*)PB;     // E out  [NN,128]
  bf16* xpb  = (bf16*)S1;     // F/G    [NN,256]
  bf16* x6b  = (bf16*)PA;     // F out  [NN,128]
  bf16* x7b  = (bf16*)P128;   // G out  [NN,128]
  float* al = S0;             // F/G [NN,2]
  float* ar = al + 2 * NN;    // F/G [NN,2]

  auto mm = [&](const bf16* A1, const short* B1h, const short* B1l, int K1,
                const bf16* A2, const short* B2h, const short* B2l, int K2,
                const float* bias, bf16* C, int M, int N, int flags){
    dim3 g(N / 128, cdiv(M, 128));
    if (A2)
      k_mm<<<g, 256, 0, stream>>>(A1, B1h, K1, A1, B1l, K1, A2, B2h, K2, A2, B2l, K2,
                                  bias, C, M, N, flags, 4);
    else
      k_mm<<<g, 256, 0, stream>>>(A1, B1h, K1, A1, B1l, K1, nullptr, nullptr, 0,
                                  nullptr, nullptr, 0, bias, C, M, N, flags, 2);
  };
  auto wt = [&](const float* W, short* hi, short* lo, int K, int nshift){
    k_wt<<<cdiv(K << nshift, 256), 256, 0, stream>>>(W, hi, lo, K, nshift);
  };
  auto chkb = [&](const void* buf, int n, int code){
    k_chk_bf<<<256, 256, 0, stream>>>((const unsigned short*)buf, n, code, diag);
  };

  // CSR build + norms
  hipMemsetAsync(diag, 0, (size_t)(4 + NN) * 4, stream);   // diag + ideg
  k_ideg<<<cdiv(NE, 256), 256, 0, stream>>>(dst, ideg);
  k_scan<<<1, 256, 0, stream>>>(ideg, rowptr, cursor);
  k_fill<<<cdiv(NE, 256), 256, 0, stream>>>(src, dst, cursor, colsrc);
  k_norms<<<cdiv(NN, 256), 256, 0, stream>>>(ideg, dg, dc, ic);

  // weight prep (ideg/cursor now dead; PA free until phase B)
  wt(W1, w1h, w1l, 128, 10);
  wt(W2, w2h, w2l, 1024, 9);
  wt(Wg1, wg1h, wg1l, 512, 8);
  wt(Wg2, wg2h, wg2l, 256, 7);
  wt(Wsl, wslh, wsll, 128, 7);
  wt(Wsr, wsrh, wsrl, 128, 7);

  k_gather<<<cdiv(NN * 128, 256), 256, 0, stream>>>(uidx, iidx, ue, ie, x0b);

  // Phase A — MLP (row-chunked, CH=5000: h1b fills S1 exactly)
  for (int ofs = 0; ofs < NN; ofs += 5000){
    mm(x0b + (size_t)ofs * 128, w1h, w1l, 128, nullptr, nullptr, nullptr, 0,
       b1, h1b, 5000, 1024, GF_BIAS | GF_RELU);
    mm(h1b, w2h, w2l, 1024, nullptr, nullptr, nullptr, 0,
       b2, h2b + (size_t)ofs * 512, 5000, 512, GF_BIAS | GF_RELU);
  }
  chkb(h2b, NN * 512, 2);

  // Phase B — GCN1 (512->256) + BN + relu
  mm(h2b, wg1h, wg1l, 512, nullptr, nullptr, nullptr, 0, nullptr, xw1b, NN, 256, 0);
  k_agg<<<cdiv(NN * 256, 256), 256, 0, stream>>>(rowptr, colsrc, xw1b, dg, nullptr, bg1, g1f, nullptr, 8, 0);
  hipMemsetAsync(stats, 0, 512 * 4, stream);
  k_bn_stats<<<cdiv(NN, 128), 256, 0, stream>>>(g1f, stats, 256);
  k_bn_apply<<<cdiv(NN * 256, 256), 256, 0, stream>>>(g1f, stats, gamma1, beta1, 8, NN * 256, g1b);

  // Phase C — GCN2 (256->128) + BN + relu
  mm(g1b, wg2h, wg2l, 256, nullptr, nullptr, nullptr, 0, nullptr, xw2b, NN, 128, 0);
  k_agg<<<cdiv(NN * 128, 256), 256, 0, stream>>>(rowptr, colsrc, xw2b, dg, nullptr, bg2, x3f, nullptr, 7, 0);
  hipMemsetAsync(stats, 0, 256 * 4, stream);
  k_bn_stats<<<cdiv(NN, 128), 256, 0, stream>>>(x3f, stats, 128);
  k_bn_apply<<<cdiv(NN * 128, 256), 256, 0, stream>>>(x3f, stats, gamma2, beta2, 7, NN * 128, x3b);

  // Phase D — SAGE
  k_agg<<<cdiv(NN * 128, 256), 256, 0, stream>>>(rowptr, colsrc, x3b, nullptr, ic, nullptr, nullptr, aggb, 7, 1);
  mm(aggb, wslh, wsll, 128, x3b, wsrh, wsrl, 128, bsl, x4b, NN, 128, GF_BIAS | GF_RELU);

  // Phase E — Cheb (Wc weights staged into free S0 tail)
  wt(Wc0, wc0h, wc0l, 128, 7);
  wt(Wc1, wc1h, wc1l, 128, 7);
  k_agg<<<cdiv(NN * 128, 256), 256, 0, stream>>>(rowptr, colsrc, x4b, dc, nullptr, nullptr, nullptr, tx1b, 7, 2);
  mm(x4b, wc0h, wc0l, 128, tx1b, wc1h, wc1l, 128, bc, x5b, NN, 128, GF_BIAS | GF_RELU);

  // Phase F — GAT1 (Wgat1 into P128, free after E)
  wt(Wgat1, wgat1h, wgat1l, 128, 8);
  mm(x5b, wgat1h, wgat1l, 128, nullptr, nullptr, nullptr, 0, nullptr, xpb, NN, 256, 0);
  k_gat_alar<<<cdiv(NN * 2, 256), 256, 0, stream>>>(xpb, as1, ad1, al, ar);
  k_gat<<<NN, 64, 0, stream>>>(rowptr, colsrc, xpb, al, ar, bgat1, x6b);

  // Phase G — GAT2 (Wgat2 into PB, free after F)
  wt(Wgat2, wgat2h, wgat2l, 128, 8);
  mm(x6b, wgat2h, wgat2l, 128, nullptr, nullptr, nullptr, 0, nullptr, xpb, NN, 256, 0);
  k_gat_alar<<<cdiv(NN * 2, 256), 256, 0, stream>>>(xpb, as2, ad2, al, ar);
  k_gat<<<NN, 64, 0, stream>>>(rowptr, colsrc, xpb, al, ar, bgat2, x7b);
  chkb(x7b, NN * 128, 19);

  // final projection -> fp32 out [NN]
  k_final<<<NN, 64, 0, stream>>>(x7b, Wp, bp, (float*)d_out);
  k_diag_out<<<cdiv(NN, 256), 256, 0, stream>>>(diag, (float*)d_out);
}

// Round 8
// 895.049 us; speedup vs baseline: 4.4020x; 1.3505x over previous
//
#include <hip/hip_runtime.h>
#include <hip/hip_bf16.h>

typedef __hip_bfloat16 bf16;
typedef short s8v __attribute__((ext_vector_type(8)));
typedef float f4v __attribute__((ext_vector_type(4)));

#define NN 20000
#define NE 160000
#define BN_EPS 1e-5f

#define GF_BIAS 1
#define GF_RELU 2

static __device__ __forceinline__ float b2f(const bf16 x){ return __bfloat162float(x); }
static __device__ __forceinline__ float bits2f(unsigned int u){ return __uint_as_float(u << 16); }
static __device__ __forceinline__ unsigned short f2bits(float f){
  bf16 h = __float2bfloat16(f);
  unsigned short u; __builtin_memcpy(&u, &h, 2); return u;
}
static __device__ __forceinline__ float lrelu(float v){ return (v > 0.f) ? v : 0.2f * v; }

static inline int cdiv(int a, int b){ return (a + b - 1) / b; }

// ---------------- diagnostics (1 tripwire) ----------------

__global__ void k_chk_bf(const unsigned short* __restrict__ x, int n, int code,
                         int* __restrict__ diag){
  bool bad = false;
  for (int k = blockIdx.x * 256 + threadIdx.x; k < n; k += gridDim.x * 256)
    if ((x[k] & 0x7F80u) == 0x7F80u) bad = true;
  if (bad) atomicCAS(diag, 0, code);
}

__global__ void k_diag_out(const int* __restrict__ diag, float* __restrict__ out){
  int d = *diag;
  if (d == 0) return;
  int i = blockIdx.x * 256 + threadIdx.x;
  if (i < NN) out[i] = (float)(d * 100);
}

// ---------------- CSR build ----------------

__global__ void k_ideg(const int* __restrict__ dst, int* __restrict__ ideg){
  int e = blockIdx.x * 256 + threadIdx.x;
  if (e < NE) atomicAdd(&ideg[dst[e]], 1);
}

__global__ __launch_bounds__(256) void k_scan(const int* __restrict__ ideg,
                                              int* __restrict__ rowptr,
                                              int* __restrict__ cursor){
  __shared__ int part[256];
  const int tid = threadIdx.x;
  const int STRIP = (NN + 255) / 256;
  const int lo = tid * STRIP, hi = min(NN, lo + STRIP);
  int s = 0;
  for (int i = lo; i < hi; i++) s += ideg[i];
  part[tid] = s;
  __syncthreads();
  for (int off = 1; off < 256; off <<= 1){
    int t = (tid >= off) ? part[tid - off] : 0;
    __syncthreads();
    part[tid] += t;
    __syncthreads();
  }
  int pre = part[tid] - s;
  for (int i = lo; i < hi; i++){
    rowptr[i] = pre; cursor[i] = pre; pre += ideg[i];
  }
  if (tid == 0) rowptr[NN] = NE;
}

__global__ void k_fill(const int* __restrict__ src, const int* __restrict__ dst,
                       int* __restrict__ cursor, int* __restrict__ colsrc){
  int e = blockIdx.x * 256 + threadIdx.x;
  if (e >= NE) return;
  int pos = atomicAdd(&cursor[dst[e]], 1);
  colsrc[pos] = src[e];
}

__global__ void k_norms(const int* __restrict__ ideg, float* __restrict__ dg,
                        float* __restrict__ dc, float* __restrict__ ic){
  int i = blockIdx.x * 256 + threadIdx.x;
  if (i >= NN) return;
  float d = (float)ideg[i];
  dg[i] = rsqrtf(d + 1.0f);                 // GCN: self-loops added
  dc[i] = (d > 0.f) ? rsqrtf(d) : 0.f;      // Cheb: no self-loops
  ic[i] = 1.0f / fmaxf(d, 1.0f);            // SAGE mean divisor
}

// ---- weight prep: W[K][N] fp32 -> WT_hi/WT_lo [N][K] bf16 (hi+lo ~ fp32 precision) ----

__global__ void k_wt(const float* __restrict__ W, short* __restrict__ hi,
                     short* __restrict__ lo, int K, int nshift){
  int idx = blockIdx.x * 256 + threadIdx.x;
  if (idx >= (K << nshift)) return;
  int n = idx & ((1 << nshift) - 1), k = idx >> nshift;
  float w = W[idx];
  unsigned short h = f2bits(w);
  float hf = bits2f(h);
  unsigned short l = f2bits(w - hf);
  hi[(size_t)n * K + k] = (short)h;
  lo[(size_t)n * K + k] = (short)l;
}

// ---------------- gather: fp32 embeddings -> bf16 x0 ----------------

__global__ void k_gather(const int* __restrict__ uidx, const int* __restrict__ iidx,
                         const float* __restrict__ ue, const float* __restrict__ ie,
                         bf16* __restrict__ x0){
  int idx = blockIdx.x * 256 + threadIdx.x;
  if (idx >= NN * 128) return;
  int i = idx >> 7, c = idx & 127;
  float v = (c < 64) ? ue[(size_t)uidx[i] * 64 + c] : ie[(size_t)iidx[i] * 64 + (c - 64)];
  x0[idx] = __float2bfloat16(v);
}

// ------- MFMA GEMM, 64x64 tile, 4 waves, hi/lo fused in one K-sweep -------
// C[M,N] = act( Σ_p A_p @ (B_ph + B_pl)^T + bias ). A bf16 [M][K]; B*T short [N][K].
// K%32==0, N%64==0.

__global__ __launch_bounds__(256) void k_mm64(
    const bf16* A0, const short* B0h, const short* B0l, int K0,
    const bf16* A1, const short* B1h, const short* B1l, int K1,
    const float* __restrict__ bias, bf16* __restrict__ C,
    int M, int Ncol, int flags, int npass){
  __shared__ short As[64][40];    // stride 80 B: 16B-aligned vec ops, <=2-way conflicts
  __shared__ short Bhs[64][40];
  __shared__ short Bls[64][40];
  const int tid = threadIdx.x;
  const int row0 = blockIdx.y * 64, col0 = blockIdx.x * 64;
  const int wid = tid >> 6, lane = tid & 63;
  const int wr = (wid >> 1) * 32, wc = (wid & 1) * 32;
  const int lr = lane & 15, lq = lane >> 4;
  const int sr = tid >> 2, sq = (tid & 3) * 8;

  f4v acc[2][2];
#pragma unroll
  for (int i = 0; i < 2; i++)
#pragma unroll
    for (int j = 0; j < 2; j++)
      acc[i][j] = f4v{0.f, 0.f, 0.f, 0.f};

  const bf16* Aarr[2] = {A0, A1};
  const short* Bharr[2] = {B0h, B1h};
  const short* Blarr[2] = {B0l, B1l};
  const int Karr[2] = {K0, K1};

  for (int p = 0; p < npass; p++){
    const short* A = (const short*)Aarr[p];
    const short* Bh = Bharr[p];
    const short* Bl = Blarr[p];
    const int K = Karr[p];
    for (int k0 = 0; k0 < K; k0 += 32){
      uint4 va = make_uint4(0u, 0u, 0u, 0u);
      int grow = row0 + sr;
      if (grow < M) va = *(const uint4*)(A + (size_t)grow * K + k0 + sq);
      *(uint4*)&As[sr][sq] = va;
      size_t boff = (size_t)(col0 + sr) * K + k0 + sq;
      *(uint4*)&Bhs[sr][sq] = *(const uint4*)(Bh + boff);
      *(uint4*)&Bls[sr][sq] = *(const uint4*)(Bl + boff);
      __syncthreads();
      s8v a[2], bh[2], bl[2];
#pragma unroll
      for (int i = 0; i < 2; i++) a[i] = *(const s8v*)&As[wr + i * 16 + lr][lq * 8];
#pragma unroll
      for (int j = 0; j < 2; j++){
        bh[j] = *(const s8v*)&Bhs[wc + j * 16 + lr][lq * 8];
        bl[j] = *(const s8v*)&Bls[wc + j * 16 + lr][lq * 8];
      }
#pragma unroll
      for (int i = 0; i < 2; i++)
#pragma unroll
        for (int j = 0; j < 2; j++){
          acc[i][j] = __builtin_amdgcn_mfma_f32_16x16x32_bf16(a[i], bh[j], acc[i][j], 0, 0, 0);
          acc[i][j] = __builtin_amdgcn_mfma_f32_16x16x32_bf16(a[i], bl[j], acc[i][j], 0, 0, 0);
        }
      __syncthreads();
    }
  }

  // epilogue: C/D layout col=lane&15, row=quad*4+reg (verified round 7)
#pragma unroll
  for (int i = 0; i < 2; i++){
#pragma unroll
    for (int rg = 0; rg < 4; rg++){
      int row = row0 + wr + i * 16 + lq * 4 + rg;
      if (row >= M) continue;
#pragma unroll
      for (int j = 0; j < 2; j++){
        int col = col0 + wc + j * 16 + lr;
        float v = acc[i][j][rg];
        if (flags & GF_BIAS) v += bias[col];
        if (flags & GF_RELU) v = fmaxf(v, 0.f);
        C[(size_t)row * Ncol + col] = __float2bfloat16(v);
      }
    }
  }
}

// ---------------- CSR aggregation (no atomics) ----------------
// mode 0 (GCN):  outf = dg[d]*Σ dg[s]x[s][c] + dg[d]^2 x[d][c] + bias[c]
// mode 1 (SAGE): outb = (Σ x[s][c]) * ic[d]
// mode 2 (Cheb): outb = -dc[d] * Σ dc[s] x[s][c]

__global__ void k_agg(const int* __restrict__ rowptr, const int* __restrict__ colsrc,
                      const bf16* __restrict__ x, const float* __restrict__ wn,
                      const float* __restrict__ icv, const float* __restrict__ bias,
                      float* __restrict__ outf, bf16* __restrict__ outb,
                      int fshift, int mode){
  int idx = blockIdx.x * 256 + threadIdx.x;
  int total = NN << fshift;
  if (idx >= total) return;
  int d = idx >> fshift, c = idx & ((1 << fshift) - 1);
  int F = 1 << fshift;
  int r0 = rowptr[d], r1 = rowptr[d + 1];
  float sum = 0.f;
  if (mode == 0){
    for (int r = r0; r < r1; r++){
      int s = colsrc[r];
      sum += wn[s] * b2f(x[(size_t)s * F + c]);
    }
    float w = wn[d];
    outf[idx] = w * sum + w * w * b2f(x[(size_t)d * F + c]) + bias[c];
  } else if (mode == 1){
    for (int r = r0; r < r1; r++)
      sum += b2f(x[(size_t)colsrc[r] * F + c]);
    outb[idx] = __float2bfloat16(sum * icv[d]);
  } else {
    for (int r = r0; r < r1; r++){
      int s = colsrc[r];
      sum += wn[s] * b2f(x[(size_t)s * F + c]);
    }
    outb[idx] = __float2bfloat16(-wn[d] * sum);
  }
}

// ---------------- batchnorm (training-mode, biased var) ----------------

__global__ void k_bn_stats(const float* __restrict__ x, float* __restrict__ stats, int F){
  int c = threadIdx.x & (F - 1);
  int rsub = threadIdx.x / F;
  int rpi = 256 / F;
  int r0 = blockIdx.x * 128;
  int rend = min(NN, r0 + 128);
  float s1 = 0.f, s2 = 0.f;
  for (int r = r0 + rsub; r < rend; r += rpi){
    float v = x[(size_t)r * F + c];
    s1 += v; s2 += v * v;
  }
  atomicAdd(&stats[c], s1);
  atomicAdd(&stats[F + c], s2);
}

__global__ void k_bn_apply(const float* __restrict__ x, const float* __restrict__ stats,
                           const float* __restrict__ g, const float* __restrict__ b,
                           int fshift, int total, bf16* __restrict__ out){
  int idx = blockIdx.x * 256 + threadIdx.x;
  if (idx >= total) return;
  int F = 1 << fshift;
  int c = idx & (F - 1);
  float mu = stats[c] * (1.0f / NN);
  float var = fmaxf(stats[F + c] * (1.0f / NN) - mu * mu, 0.f);
  float v = (x[idx] - mu) * rsqrtf(var + BN_EPS) * g[c] + b[c];
  out[idx] = __float2bfloat16(fmaxf(v, 0.f));
}

// ---------------- GAT ----------------

__global__ void k_gat_alar(const bf16* __restrict__ xp, const float* __restrict__ as_,
                           const float* __restrict__ ad_, float* __restrict__ al,
                           float* __restrict__ ar){
  int idx = blockIdx.x * 256 + threadIdx.x;
  if (idx >= NN * 2) return;
  int i = idx >> 1, h = idx & 1;
  const bf16* row = xp + (size_t)i * 256 + h * 128;
  const float* va = as_ + h * 128;
  const float* vd = ad_ + h * 128;
  float sa = 0.f, sd = 0.f;
  for (int c = 0; c < 128; c++){
    float v = b2f(row[c]);
    sa += v * va[c];
    sd += v * vd[c];
  }
  al[idx] = sa; ar[idx] = sd;
}

__global__ __launch_bounds__(64) void k_gat(const int* __restrict__ rowptr,
                                            const int* __restrict__ colsrc,
                                            const bf16* __restrict__ xp,
                                            const float* __restrict__ al,
                                            const float* __restrict__ ar,
                                            const float* __restrict__ bias,
                                            bf16* __restrict__ out){
  int d = blockIdx.x;
  int lane = threadIdx.x;
  int r0 = rowptr[d], r1 = rowptr[d + 1];
  float m[2], sm[2];
#pragma unroll
  for (int h = 0; h < 2; h++){
    float ard = ar[d * 2 + h];
    float eself = lrelu(al[d * 2 + h] + ard);
    float mx = eself;
    for (int r = r0 + lane; r < r1; r += 64)
      mx = fmaxf(mx, lrelu(al[colsrc[r] * 2 + h] + ard));
#pragma unroll
    for (int off = 32; off > 0; off >>= 1) mx = fmaxf(mx, __shfl_xor(mx, off));
    float ps = (lane == 0) ? expf(eself - mx) : 0.f;
    for (int r = r0 + lane; r < r1; r += 64)
      ps += expf(lrelu(al[colsrc[r] * 2 + h] + ard) - mx);
#pragma unroll
    for (int off = 32; off > 0; off >>= 1) ps += __shfl_xor(ps, off);
    m[h] = mx; sm[h] = ps;
  }
#pragma unroll
  for (int chunk = 0; chunk < 2; chunk++){
    int c = chunk * 64 + lane;
    float o[2];
#pragma unroll
    for (int h = 0; h < 2; h++){
      float ard = ar[d * 2 + h];
      float acc = expf(lrelu(al[d * 2 + h] + ard) - m[h]) * b2f(xp[(size_t)d * 256 + h * 128 + c]);
      for (int r = r0; r < r1; r++){
        int s = colsrc[r];
        float w = expf(lrelu(al[s * 2 + h] + ard) - m[h]);
        acc += w * b2f(xp[(size_t)s * 256 + h * 128 + c]);
      }
      o[h] = acc / sm[h];
    }
    float v = 0.5f * (o[0] + o[1]) + bias[c];
    out[(size_t)d * 128 + c] = __float2bfloat16((v > 0.f) ? v : expm1f(v));
  }
}

// ---------------- final projection ----------------

__global__ void k_final(const bf16* __restrict__ x, const float* __restrict__ wp,
                        const float* __restrict__ bp, float* __restrict__ out){
  int i = blockIdx.x;
  int t = threadIdx.x;
  float v = b2f(x[(size_t)i * 128 + t]) * wp[t]
          + b2f(x[(size_t)i * 128 + 64 + t]) * wp[64 + t];
#pragma unroll
  for (int off = 32; off > 0; off >>= 1) v += __shfl_down(v, off, 64);
  if (t == 0) out[i] = v + bp[0];
}

// ---------------- host ----------------

extern "C" void kernel_launch(void* const* d_in, const int* in_sizes, int n_in,
                              void* d_out, int out_size, void* d_ws, size_t ws_size,
                              hipStream_t stream){
  const int* uidx = (const int*)d_in[0];
  const int* iidx = (const int*)d_in[1];
  const int* eidx = (const int*)d_in[2];
  const int* src = eidx;
  const int* dst = eidx + NE;
  const float* ue  = (const float*)d_in[3];
  const float* ie  = (const float*)d_in[4];
  const float* W1  = (const float*)d_in[5];  const float* b1  = (const float*)d_in[6];
  const float* W2  = (const float*)d_in[7];  const float* b2  = (const float*)d_in[8];
  const float* Wg1 = (const float*)d_in[9];  const float* bg1 = (const float*)d_in[10];
  const float* gamma1 = (const float*)d_in[11]; const float* beta1 = (const float*)d_in[12];
  const float* Wg2 = (const float*)d_in[13]; const float* bg2 = (const float*)d_in[14];
  const float* gamma2 = (const float*)d_in[15]; const float* beta2 = (const float*)d_in[16];
  const float* Wsl = (const float*)d_in[17]; const float* bsl = (const float*)d_in[18];
  const float* Wsr = (const float*)d_in[19];
  const float* Wc0 = (const float*)d_in[20]; const float* Wc1 = (const float*)d_in[21];
  const float* bc  = (const float*)d_in[22];
  const float* Wgat1 = (const float*)d_in[23]; const float* as1 = (const float*)d_in[24];
  const float* ad1 = (const float*)d_in[25];   const float* bgat1 = (const float*)d_in[26];
  const float* Wgat2 = (const float*)d_in[27]; const float* as2 = (const float*)d_in[28];
  const float* ad2 = (const float*)d_in[29];   const float* bgat2 = (const float*)d_in[30];
  const float* Wp  = (const float*)d_in[31];   const float* bp  = (const float*)d_in[32];

  // ---- workspace, 51.3 MB total (proven ws_size >= 53.2 MB) ----
  int* diag   = (int*)d_ws;                        // 4
  int* ideg   = diag + 4;                          // NN
  int* rowptr = ideg + NN;                         // NN+4
  int* cursor = rowptr + NN + 4;                   // NN
  int* colsrc = cursor + NN;                       // NE
  float* dg = (float*)(colsrc + NE);               // NN
  float* dc = dg + NN;                             // NN
  float* ic = dc + NN;                             // NN
  float* stats = ic + NN;                          // 512
  float* al = stats + 512;                         // 2NN
  float* ar = al + 2 * NN;                         // 2NN
  // persistent hi/lo weights (shorts)
  short* w1h = (short*)(ar + 2 * NN);              // 131072 (128x1024)
  short* w1l = w1h + 131072;
  short* w2h = w1l + 131072;                       // 524288 (1024x512)
  short* w2l = w2h + 524288;
  short* wg1h = w2l + 524288;                      // 131072 (512x256)
  short* wg1l = wg1h + 131072;
  short* wg2h = wg1l + 131072;                     // 32768 (256x128)
  short* wg2l = wg2h + 32768;
  short* wslh = wg2l + 32768;                      // 16384 (128x128)
  short* wsll = wslh + 16384;
  short* wsrh = wsll + 16384;
  short* wsrl = wsrh + 16384;
  short* wc0h = wsrl + 16384;
  short* wc0l = wc0h + 16384;
  short* wc1h = wc0l + 16384;
  short* wc1l = wc1h + 16384;
  short* wgat1h = wc1l + 16384;                    // 32768 (128x256)
  short* wgat1l = wgat1h + 32768;
  short* wgat2h = wgat1l + 32768;
  short* wgat2l = wgat2h + 32768;
  // activation slots (shorts/bf16 elements)
  short* X0 = wgat2l + 32768;                      // NN*128   (5.12 MB)
  short* H1 = X0 + (size_t)NN * 128;               // 10000*1024 (20.48 MB)
  short* H2 = H1 + (size_t)10000 * 1024;           // NN*512   (20.48 MB)

  // activation views (live ranges verified disjoint)
  bf16* x0b  = (bf16*)X0;                          // phase A in
  bf16* h1b  = (bf16*)H1;                          // phase A mid (per 10000-chunk)
  bf16* h2b  = (bf16*)H2;                          // phase A out [NN,512]
  bf16* xw1b = (bf16*)H1;                          // B: [NN,256] (first half of H1)
  float* g1f = (float*)H2;                         // B: f32 [NN,256] (h2b dead)
  bf16* g1b  = (bf16*)(H1 + (size_t)NN * 256);     // B out [NN,256] (second half of H1)
  bf16* xw2b = (bf16*)X0;                          // C: [NN,128] (x0b dead)
  float* x3f = (float*)H1;                         // C: f32 [NN,128] (xw1b dead)
  bf16* x3b  = (bf16*)H2;                          // C out [NN,128] (g1f dead)
  bf16* aggb = (bf16*)X0;                          // D: [NN,128] (xw2b dead)
  bf16* x4b  = (bf16*)(H2 + (size_t)NN * 128);     // D out [NN,128]
  bf16* tx1b = (bf16*)X0;                          // E: [NN,128] (aggb dead)
  bf16* x5b  = (bf16*)(H2 + (size_t)NN * 256);     // E out [NN,128]
  bf16* xpb  = (bf16*)H1;                          // F/G: [NN,256] (x3f dead)
  bf16* x6b  = (bf16*)X0;                          // F out [NN,128] (tx1b dead)
  bf16* x7b  = (bf16*)H2;                          // G out [NN,128] (x3b dead)

  auto mm = [&](const bf16* A1, const short* B1h, const short* B1l, int K1,
                const bf16* A2, const short* B2h, const short* B2l, int K2,
                const float* bias, bf16* C, int M, int N, int flags){
    dim3 g(N / 64, cdiv(M, 64));
    int np = A2 ? 2 : 1;
    k_mm64<<<g, 256, 0, stream>>>(A1, B1h, B1l, K1, A2, B2h, B2l, K2,
                                  bias, C, M, N, flags, np);
  };
  auto wt = [&](const float* W, short* hi, short* lo, int K, int nshift){
    k_wt<<<cdiv(K << nshift, 256), 256, 0, stream>>>(W, hi, lo, K, nshift);
  };

  // CSR build + norms
  hipMemsetAsync(diag, 0, (size_t)(4 + NN) * 4, stream);   // diag + ideg
  k_ideg<<<cdiv(NE, 256), 256, 0, stream>>>(dst, ideg);
  k_scan<<<1, 256, 0, stream>>>(ideg, rowptr, cursor);
  k_fill<<<cdiv(NE, 256), 256, 0, stream>>>(src, dst, cursor, colsrc);
  k_norms<<<cdiv(NN, 256), 256, 0, stream>>>(ideg, dg, dc, ic);

  // weight prep (all persistent)
  wt(W1, w1h, w1l, 128, 10);
  wt(W2, w2h, w2l, 1024, 9);
  wt(Wg1, wg1h, wg1l, 512, 8);
  wt(Wg2, wg2h, wg2l, 256, 7);
  wt(Wsl, wslh, wsll, 128, 7);
  wt(Wsr, wsrh, wsrl, 128, 7);
  wt(Wc0, wc0h, wc0l, 128, 7);
  wt(Wc1, wc1h, wc1l, 128, 7);
  wt(Wgat1, wgat1h, wgat1l, 128, 8);
  wt(Wgat2, wgat2h, wgat2l, 128, 8);

  k_gather<<<cdiv(NN * 128, 256), 256, 0, stream>>>(uidx, iidx, ue, ie, x0b);

  // Phase A — MLP (two 10000-row chunks; h1b reused)
  for (int ofs = 0; ofs < NN; ofs += 10000){
    mm(x0b + (size_t)ofs * 128, w1h, w1l, 128, nullptr, nullptr, nullptr, 0,
       b1, h1b, 10000, 1024, GF_BIAS | GF_RELU);
    mm(h1b, w2h, w2l, 1024, nullptr, nullptr, nullptr, 0,
       b2, h2b + (size_t)ofs * 512, 10000, 512, GF_BIAS | GF_RELU);
  }

  // Phase B — GCN1 (512->256) + BN + relu
  mm(h2b, wg1h, wg1l, 512, nullptr, nullptr, nullptr, 0, nullptr, xw1b, NN, 256, 0);
  k_agg<<<cdiv(NN * 256, 256), 256, 0, stream>>>(rowptr, colsrc, xw1b, dg, nullptr, bg1, g1f, nullptr, 8, 0);
  hipMemsetAsync(stats, 0, 512 * 4, stream);
  k_bn_stats<<<cdiv(NN, 128), 256, 0, stream>>>(g1f, stats, 256);
  k_bn_apply<<<cdiv(NN * 256, 256), 256, 0, stream>>>(g1f, stats, gamma1, beta1, 8, NN * 256, g1b);

  // Phase C — GCN2 (256->128) + BN + relu
  mm(g1b, wg2h, wg2l, 256, nullptr, nullptr, nullptr, 0, nullptr, xw2b, NN, 128, 0);
  k_agg<<<cdiv(NN * 128, 256), 256, 0, stream>>>(rowptr, colsrc, xw2b, dg, nullptr, bg2, x3f, nullptr, 7, 0);
  hipMemsetAsync(stats, 0, 256 * 4, stream);
  k_bn_stats<<<cdiv(NN, 128), 256, 0, stream>>>(x3f, stats, 128);
  k_bn_apply<<<cdiv(NN * 128, 256), 256, 0, stream>>>(x3f, stats, gamma2, beta2, 7, NN * 128, x3b);

  // Phase D — SAGE
  k_agg<<<cdiv(NN * 128, 256), 256, 0, stream>>>(rowptr, colsrc, x3b, nullptr, ic, nullptr, nullptr, aggb, 7, 1);
  mm(aggb, wslh, wsll, 128, x3b, wsrh, wsrl, 128, bsl, x4b, NN, 128, GF_BIAS | GF_RELU);

  // Phase E — Cheb
  k_agg<<<cdiv(NN * 128, 256), 256, 0, stream>>>(rowptr, colsrc, x4b, dc, nullptr, nullptr, nullptr, tx1b, 7, 2);
  mm(x4b, wc0h, wc0l, 128, tx1b, wc1h, wc1l, 128, bc, x5b, NN, 128, GF_BIAS | GF_RELU);

  // Phase F — GAT1
  mm(x5b, wgat1h, wgat1l, 128, nullptr, nullptr, nullptr, 0, nullptr, xpb, NN, 256, 0);
  k_gat_alar<<<cdiv(NN * 2, 256), 256, 0, stream>>>(xpb, as1, ad1, al, ar);
  k_gat<<<NN, 64, 0, stream>>>(rowptr, colsrc, xpb, al, ar, bgat1, x6b);

  // Phase G — GAT2
  mm(x6b, wgat2h, wgat2l, 128, nullptr, nullptr, nullptr, 0, nullptr, xpb, NN, 256, 0);
  k_gat_alar<<<cdiv(NN * 2, 256), 256, 0, stream>>>(xpb, as2, ad2, al, ar);
  k_gat<<<NN, 64, 0, stream>>>(rowptr, colsrc, xpb, al, ar, bgat2, x7b);
  k_chk_bf<<<256, 256, 0, stream>>>((const unsigned short*)x7b, NN * 128, 19, diag);

  // final projection -> fp32 out [NN]
  k_final<<<NN, 64, 0, stream>>>(x7b, Wp, bp, (float*)d_out);
  k_diag_out<<<cdiv(NN, 256), 256, 0, stream>>>(diag, (float*)d_out);
}

// Round 9
// 814.972 us; speedup vs baseline: 4.8345x; 1.0983x over previous
//
#include <hip/hip_runtime.h>
#include <hip/hip_bf16.h>

typedef __hip_bfloat16 bf16;
typedef short s8v __attribute__((ext_vector_type(8)));
typedef float f4v __attribute__((ext_vector_type(4)));

#define NN 20000
#define NE 160000
#define BN_EPS 1e-5f

#define GF_BIAS 1
#define GF_RELU 2

static __device__ __forceinline__ float b2f(const bf16 x){ return __bfloat162float(x); }
static __device__ __forceinline__ float bits2f(unsigned int u){ return __uint_as_float(u << 16); }
static __device__ __forceinline__ unsigned short f2bits(float f){
  bf16 h = __float2bfloat16(f);
  unsigned short u; __builtin_memcpy(&u, &h, 2); return u;
}
static __device__ __forceinline__ float lrelu(float v){ return (v > 0.f) ? v : 0.2f * v; }

static inline int cdiv(int a, int b){ return (a + b - 1) / b; }

// ---------------- diagnostics ----------------

__global__ void k_chk_bf(const unsigned short* __restrict__ x, int n, int code,
                         int* __restrict__ diag){
  bool bad = false;
  for (int k = blockIdx.x * 256 + threadIdx.x; k < n; k += gridDim.x * 256)
    if ((x[k] & 0x7F80u) == 0x7F80u) bad = true;
  if (bad) atomicCAS(diag, 0, code);
}

__global__ void k_diag_out(const int* __restrict__ diag, float* __restrict__ out){
  int d = *diag;
  if (d == 0) return;
  int i = blockIdx.x * 256 + threadIdx.x;
  if (i < NN) out[i] = (float)(d * 100);
}

// ---------------- CSR build ----------------

__global__ void k_ideg(const int* __restrict__ dst, int* __restrict__ ideg){
  int e = blockIdx.x * 256 + threadIdx.x;
  if (e < NE) atomicAdd(&ideg[dst[e]], 1);
}

// scan + cursor init + degree norms in one launch
__global__ __launch_bounds__(256) void k_scan(const int* __restrict__ ideg,
                                              int* __restrict__ rowptr,
                                              int* __restrict__ cursor,
                                              float* __restrict__ dg,
                                              float* __restrict__ dc,
                                              float* __restrict__ ic){
  __shared__ int part[256];
  const int tid = threadIdx.x;
  const int STRIP = (NN + 255) / 256;
  const int lo = tid * STRIP, hi = min(NN, lo + STRIP);
  int s = 0;
  for (int i = lo; i < hi; i++) s += ideg[i];
  part[tid] = s;
  __syncthreads();
  for (int off = 1; off < 256; off <<= 1){
    int t = (tid >= off) ? part[tid - off] : 0;
    __syncthreads();
    part[tid] += t;
    __syncthreads();
  }
  int pre = part[tid] - s;
  for (int i = lo; i < hi; i++){
    int dv = ideg[i];
    rowptr[i] = pre; cursor[i] = pre; pre += dv;
    float d = (float)dv;
    dg[i] = rsqrtf(d + 1.0f);
    dc[i] = (d > 0.f) ? rsqrtf(d) : 0.f;
    ic[i] = 1.0f / fmaxf(d, 1.0f);
  }
  if (tid == 0) rowptr[NN] = NE;
}

__global__ void k_fill(const int* __restrict__ src, const int* __restrict__ dst,
                       int* __restrict__ cursor, int* __restrict__ colsrc){
  int e = blockIdx.x * 256 + threadIdx.x;
  if (e >= NE) return;
  int pos = atomicAdd(&cursor[dst[e]], 1);
  colsrc[pos] = src[e];
}

// ---- batched weight prep: all W[K][N] fp32 -> WT_hi/WT_lo [N][K] bf16, one launch ----

struct WtPack {
  const float* W[10]; short* hi[10]; short* lo[10];
  int K[10]; int nshift[10]; int base[11];
};

__global__ __launch_bounds__(256) void k_wtall(WtPack p){
  int idx = blockIdx.x * 256 + threadIdx.x;
  if (idx >= p.base[10]) return;
  int seg = 0;
#pragma unroll
  for (int i = 1; i < 10; i++) seg += (idx >= p.base[i]) ? 1 : 0;
  int local = idx - p.base[seg];
  int K = p.K[seg], ns = p.nshift[seg];
  int n = local & ((1 << ns) - 1), k = local >> ns;
  float w = p.W[seg][local];
  unsigned short h = f2bits(w);
  unsigned short l = f2bits(w - bits2f(h));
  p.hi[seg][(size_t)n * K + k] = (short)h;
  p.lo[seg][(size_t)n * K + k] = (short)l;
}

// ---------------- gather: fp32 embeddings -> bf16 x0 ----------------

__global__ void k_gather(const int* __restrict__ uidx, const int* __restrict__ iidx,
                         const float* __restrict__ ue, const float* __restrict__ ie,
                         bf16* __restrict__ x0){
  int idx = blockIdx.x * 256 + threadIdx.x;
  if (idx >= NN * 128) return;
  int i = idx >> 7, c = idx & 127;
  float v = (c < 64) ? ue[(size_t)uidx[i] * 64 + c] : ie[(size_t)iidx[i] * 64 + (c - 64)];
  x0[idx] = __float2bfloat16(v);
}

// ------- MFMA GEMM, 64x64 tile, 4 waves, hi/lo fused in one K-sweep -------

__global__ __launch_bounds__(256) void k_mm64(
    const bf16* A0, const short* B0h, const short* B0l, int K0,
    const bf16* A1, const short* B1h, const short* B1l, int K1,
    const float* __restrict__ bias, bf16* __restrict__ C,
    int M, int Ncol, int flags, int npass){
  __shared__ short As[64][40];
  __shared__ short Bhs[64][40];
  __shared__ short Bls[64][40];
  const int tid = threadIdx.x;
  const int row0 = blockIdx.y * 64, col0 = blockIdx.x * 64;
  const int wid = tid >> 6, lane = tid & 63;
  const int wr = (wid >> 1) * 32, wc = (wid & 1) * 32;
  const int lr = lane & 15, lq = lane >> 4;
  const int sr = tid >> 2, sq = (tid & 3) * 8;

  f4v acc[2][2];
#pragma unroll
  for (int i = 0; i < 2; i++)
#pragma unroll
    for (int j = 0; j < 2; j++)
      acc[i][j] = f4v{0.f, 0.f, 0.f, 0.f};

  const bf16* Aarr[2] = {A0, A1};
  const short* Bharr[2] = {B0h, B1h};
  const short* Blarr[2] = {B0l, B1l};
  const int Karr[2] = {K0, K1};

  for (int p = 0; p < npass; p++){
    const short* A = (const short*)Aarr[p];
    const short* Bh = Bharr[p];
    const short* Bl = Blarr[p];
    const int K = Karr[p];
    for (int k0 = 0; k0 < K; k0 += 32){
      uint4 va = make_uint4(0u, 0u, 0u, 0u);
      int grow = row0 + sr;
      if (grow < M) va = *(const uint4*)(A + (size_t)grow * K + k0 + sq);
      *(uint4*)&As[sr][sq] = va;
      size_t boff = (size_t)(col0 + sr) * K + k0 + sq;
      *(uint4*)&Bhs[sr][sq] = *(const uint4*)(Bh + boff);
      *(uint4*)&Bls[sr][sq] = *(const uint4*)(Bl + boff);
      __syncthreads();
      s8v a[2], bh[2], bl[2];
#pragma unroll
      for (int i = 0; i < 2; i++) a[i] = *(const s8v*)&As[wr + i * 16 + lr][lq * 8];
#pragma unroll
      for (int j = 0; j < 2; j++){
        bh[j] = *(const s8v*)&Bhs[wc + j * 16 + lr][lq * 8];
        bl[j] = *(const s8v*)&Bls[wc + j * 16 + lr][lq * 8];
      }
#pragma unroll
      for (int i = 0; i < 2; i++)
#pragma unroll
        for (int j = 0; j < 2; j++){
          acc[i][j] = __builtin_amdgcn_mfma_f32_16x16x32_bf16(a[i], bh[j], acc[i][j], 0, 0, 0);
          acc[i][j] = __builtin_amdgcn_mfma_f32_16x16x32_bf16(a[i], bl[j], acc[i][j], 0, 0, 0);
        }
      __syncthreads();
    }
  }

#pragma unroll
  for (int i = 0; i < 2; i++){
#pragma unroll
    for (int rg = 0; rg < 4; rg++){
      int row = row0 + wr + i * 16 + lq * 4 + rg;
      if (row >= M) continue;
#pragma unroll
      for (int j = 0; j < 2; j++){
        int col = col0 + wc + j * 16 + lr;
        float v = acc[i][j][rg];
        if (flags & GF_BIAS) v += bias[col];
        if (flags & GF_RELU) v = fmaxf(v, 0.f);
        C[(size_t)row * Ncol + col] = __float2bfloat16(v);
      }
    }
  }
}

// ---------------- CSR aggregation (no atomics) ----------------

__global__ void k_agg(const int* __restrict__ rowptr, const int* __restrict__ colsrc,
                      const bf16* __restrict__ x, const float* __restrict__ wn,
                      const float* __restrict__ icv, const float* __restrict__ bias,
                      float* __restrict__ outf, bf16* __restrict__ outb,
                      int fshift, int mode){
  int idx = blockIdx.x * 256 + threadIdx.x;
  int total = NN << fshift;
  if (idx >= total) return;
  int d = idx >> fshift, c = idx & ((1 << fshift) - 1);
  int F = 1 << fshift;
  int r0 = rowptr[d], r1 = rowptr[d + 1];
  float sum = 0.f;
  if (mode == 0){
    for (int r = r0; r < r1; r++){
      int s = colsrc[r];
      sum += wn[s] * b2f(x[(size_t)s * F + c]);
    }
    float w = wn[d];
    outf[idx] = w * sum + w * w * b2f(x[(size_t)d * F + c]) + bias[c];
  } else if (mode == 1){
    for (int r = r0; r < r1; r++)
      sum += b2f(x[(size_t)colsrc[r] * F + c]);
    outb[idx] = __float2bfloat16(sum * icv[d]);
  } else {
    for (int r = r0; r < r1; r++){
      int s = colsrc[r];
      sum += wn[s] * b2f(x[(size_t)s * F + c]);
    }
    outb[idx] = __float2bfloat16(-wn[d] * sum);
  }
}

// ---------------- batchnorm (training-mode, biased var) ----------------

__global__ void k_bn_stats(const float* __restrict__ x, float* __restrict__ stats, int F){
  int c = threadIdx.x & (F - 1);
  int rsub = threadIdx.x / F;
  int rpi = 256 / F;
  int r0 = blockIdx.x * 128;
  int rend = min(NN, r0 + 128);
  float s1 = 0.f, s2 = 0.f;
  for (int r = r0 + rsub; r < rend; r += rpi){
    float v = x[(size_t)r * F + c];
    s1 += v; s2 += v * v;
  }
  atomicAdd(&stats[c], s1);
  atomicAdd(&stats[F + c], s2);
}

__global__ void k_bn_apply(const float* __restrict__ x, const float* __restrict__ stats,
                           const float* __restrict__ g, const float* __restrict__ b,
                           int fshift, int total, bf16* __restrict__ out){
  int idx = blockIdx.x * 256 + threadIdx.x;
  if (idx >= total) return;
  int F = 1 << fshift;
  int c = idx & (F - 1);
  float mu = stats[c] * (1.0f / NN);
  float var = fmaxf(stats[F + c] * (1.0f / NN) - mu * mu, 0.f);
  float v = (x[idx] - mu) * rsqrtf(var + BN_EPS) * g[c] + b[c];
  out[idx] = __float2bfloat16(fmaxf(v, 0.f));
}

// ---------------- GAT ----------------

// wave-per-node attention logits (4 nodes per 256-thread block)
__global__ __launch_bounds__(256) void k_gat_alar(const bf16* __restrict__ xp,
                                                  const float* __restrict__ as_,
                                                  const float* __restrict__ ad_,
                                                  float* __restrict__ al,
                                                  float* __restrict__ ar){
  int d = blockIdx.x * 4 + (threadIdx.x >> 6);
  int lane = threadIdx.x & 63;
  if (d >= NN) return;
  int c0 = lane * 2;
  unsigned int p0 = *(const unsigned int*)((const short*)xp + (size_t)d * 256 + c0);
  unsigned int p1 = *(const unsigned int*)((const short*)xp + (size_t)d * 256 + 128 + c0);
  float x00 = bits2f(p0 & 0xffffu), x01 = bits2f(p0 >> 16);
  float x10 = bits2f(p1 & 0xffffu), x11 = bits2f(p1 >> 16);
  float sa0 = x00 * as_[c0] + x01 * as_[c0 + 1];
  float sd0 = x00 * ad_[c0] + x01 * ad_[c0 + 1];
  float sa1 = x10 * as_[128 + c0] + x11 * as_[128 + c0 + 1];
  float sd1 = x10 * ad_[128 + c0] + x11 * ad_[128 + c0 + 1];
#pragma unroll
  for (int off = 32; off > 0; off >>= 1){
    sa0 += __shfl_xor(sa0, off); sd0 += __shfl_xor(sd0, off);
    sa1 += __shfl_xor(sa1, off); sd1 += __shfl_xor(sd1, off);
  }
  if (lane == 0){
    al[d * 2] = sa0;     ar[d * 2] = sd0;
    al[d * 2 + 1] = sa1; ar[d * 2 + 1] = sd1;
  }
}

// wave-per-node GAT: softmax stats, then edge tiles with LDS-staged weights
// (each per-edge expf computed ONCE, not per-lane). If wp!=null, fuse the
// final [128]->1 projection and write fp32 out; else write bf16 features.
__global__ __launch_bounds__(64) void k_gat(const int* __restrict__ rowptr,
                                            const int* __restrict__ colsrc,
                                            const bf16* __restrict__ xp,
                                            const float* __restrict__ al,
                                            const float* __restrict__ ar,
                                            const float* __restrict__ bias,
                                            bf16* __restrict__ outb,
                                            const float* __restrict__ wp,
                                            const float* __restrict__ bp,
                                            float* __restrict__ outf){
  __shared__ float w0s[64], w1s[64];
  __shared__ int ss[64];
  int d = blockIdx.x;
  int lane = threadIdx.x;
  int r0 = rowptr[d], r1 = rowptr[d + 1];
  float ard0 = ar[d * 2], ard1 = ar[d * 2 + 1];
  float e0 = lrelu(al[d * 2] + ard0);
  float e1 = lrelu(al[d * 2 + 1] + ard1);
  // max
  float mx0 = e0, mx1 = e1;
  for (int r = r0 + lane; r < r1; r += 64){
    int s = colsrc[r];
    mx0 = fmaxf(mx0, lrelu(al[s * 2] + ard0));
    mx1 = fmaxf(mx1, lrelu(al[s * 2 + 1] + ard1));
  }
#pragma unroll
  for (int off = 32; off > 0; off >>= 1){
    mx0 = fmaxf(mx0, __shfl_xor(mx0, off));
    mx1 = fmaxf(mx1, __shfl_xor(mx1, off));
  }
  // sum
  float ps0 = (lane == 0) ? expf(e0 - mx0) : 0.f;
  float ps1 = (lane == 0) ? expf(e1 - mx1) : 0.f;
  for (int r = r0 + lane; r < r1; r += 64){
    int s = colsrc[r];
    ps0 += expf(lrelu(al[s * 2] + ard0) - mx0);
    ps1 += expf(lrelu(al[s * 2 + 1] + ard1) - mx1);
  }
#pragma unroll
  for (int off = 32; off > 0; off >>= 1){
    ps0 += __shfl_xor(ps0, off);
    ps1 += __shfl_xor(ps1, off);
  }
  // features: lane owns columns c0, c0+1 of both heads
  int c0 = lane * 2;
  float a00, a01, a10, a11;
  {
    float w0 = expf(e0 - mx0), w1 = expf(e1 - mx1);
    unsigned int p0 = *(const unsigned int*)((const short*)xp + (size_t)d * 256 + c0);
    unsigned int p1 = *(const unsigned int*)((const short*)xp + (size_t)d * 256 + 128 + c0);
    a00 = w0 * bits2f(p0 & 0xffffu); a01 = w0 * bits2f(p0 >> 16);
    a10 = w1 * bits2f(p1 & 0xffffu); a11 = w1 * bits2f(p1 >> 16);
  }
  for (int t0 = r0; t0 < r1; t0 += 64){
    int nt = min(64, r1 - t0);
    __syncthreads();
    if (lane < nt){
      int s = colsrc[t0 + lane];
      ss[lane] = s;
      w0s[lane] = expf(lrelu(al[s * 2] + ard0) - mx0);
      w1s[lane] = expf(lrelu(al[s * 2 + 1] + ard1) - mx1);
    }
    __syncthreads();
    for (int r = 0; r < nt; r++){
      int s = ss[r];
      float w0 = w0s[r], w1 = w1s[r];
      unsigned int p0 = *(const unsigned int*)((const short*)xp + (size_t)s * 256 + c0);
      unsigned int p1 = *(const unsigned int*)((const short*)xp + (size_t)s * 256 + 128 + c0);
      a00 += w0 * bits2f(p0 & 0xffffu); a01 += w0 * bits2f(p0 >> 16);
      a10 += w1 * bits2f(p1 & 0xffffu); a11 += w1 * bits2f(p1 >> 16);
    }
  }
  float v0 = 0.5f * (a00 / ps0 + a10 / ps1) + bias[c0];
  float v1 = 0.5f * (a01 / ps0 + a11 / ps1) + bias[c0 + 1];
  v0 = (v0 > 0.f) ? v0 : expm1f(v0);
  v1 = (v1 > 0.f) ? v1 : expm1f(v1);
  if (wp == nullptr){
    unsigned int packed = (unsigned int)f2bits(v0) | ((unsigned int)f2bits(v1) << 16);
    *(unsigned int*)((short*)outb + (size_t)d * 128 + c0) = packed;
  } else {
    float pv = v0 * wp[c0] + v1 * wp[c0 + 1];
#pragma unroll
    for (int off = 32; off > 0; off >>= 1) pv += __shfl_down(pv, off);
    if (lane == 0) outf[d] = pv + bp[0];
  }
}

// ---------------- host ----------------

extern "C" void kernel_launch(void* const* d_in, const int* in_sizes, int n_in,
                              void* d_out, int out_size, void* d_ws, size_t ws_size,
                              hipStream_t stream){
  const int* uidx = (const int*)d_in[0];
  const int* iidx = (const int*)d_in[1];
  const int* eidx = (const int*)d_in[2];
  const int* src = eidx;
  const int* dst = eidx + NE;
  const float* ue  = (const float*)d_in[3];
  const float* ie  = (const float*)d_in[4];
  const float* W1  = (const float*)d_in[5];  const float* b1  = (const float*)d_in[6];
  const float* W2  = (const float*)d_in[7];  const float* b2  = (const float*)d_in[8];
  const float* Wg1 = (const float*)d_in[9];  const float* bg1 = (const float*)d_in[10];
  const float* gamma1 = (const float*)d_in[11]; const float* beta1 = (const float*)d_in[12];
  const float* Wg2 = (const float*)d_in[13]; const float* bg2 = (const float*)d_in[14];
  const float* gamma2 = (const float*)d_in[15]; const float* beta2 = (const float*)d_in[16];
  const float* Wsl = (const float*)d_in[17]; const float* bsl = (const float*)d_in[18];
  const float* Wsr = (const float*)d_in[19];
  const float* Wc0 = (const float*)d_in[20]; const float* Wc1 = (const float*)d_in[21];
  const float* bc  = (const float*)d_in[22];
  const float* Wgat1 = (const float*)d_in[23]; const float* as1 = (const float*)d_in[24];
  const float* ad1 = (const float*)d_in[25];   const float* bgat1 = (const float*)d_in[26];
  const float* Wgat2 = (const float*)d_in[27]; const float* as2 = (const float*)d_in[28];
  const float* ad2 = (const float*)d_in[29];   const float* bgat2 = (const float*)d_in[30];
  const float* Wp  = (const float*)d_in[31];   const float* bp  = (const float*)d_in[32];

  // ---- workspace, 51.3 MB total ----
  int* diag   = (int*)d_ws;
  int* ideg   = diag + 4;
  int* rowptr = ideg + NN;
  int* cursor = rowptr + NN + 4;
  int* colsrc = cursor + NN;
  float* dg = (float*)(colsrc + NE);
  float* dc = dg + NN;
  float* ic = dc + NN;
  float* stats = ic + NN;
  float* al = stats + 512;
  float* ar = al + 2 * NN;
  short* w1h = (short*)(ar + 2 * NN);
  short* w1l = w1h + 131072;
  short* w2h = w1l + 131072;
  short* w2l = w2h + 524288;
  short* wg1h = w2l + 524288;
  short* wg1l = wg1h + 131072;
  short* wg2h = wg1l + 131072;
  short* wg2l = wg2h + 32768;
  short* wslh = wg2l + 32768;
  short* wsll = wslh + 16384;
  short* wsrh = wsll + 16384;
  short* wsrl = wsrh + 16384;
  short* wc0h = wsrl + 16384;
  short* wc0l = wc0h + 16384;
  short* wc1h = wc0l + 16384;
  short* wc1l = wc1h + 16384;
  short* wgat1h = wc1l + 16384;
  short* wgat1l = wgat1h + 32768;
  short* wgat2h = wgat1l + 32768;
  short* wgat2l = wgat2h + 32768;
  short* X0 = wgat2l + 32768;                      // NN*128
  short* H1 = X0 + (size_t)NN * 128;               // 10000*1024
  short* H2 = H1 + (size_t)10000 * 1024;           // NN*512

  bf16* x0b  = (bf16*)X0;
  bf16* h1b  = (bf16*)H1;
  bf16* h2b  = (bf16*)H2;
  bf16* xw1b = (bf16*)H1;
  float* g1f = (float*)H2;
  bf16* g1b  = (bf16*)(H1 + (size_t)NN * 256);
  bf16* xw2b = (bf16*)X0;
  float* x3f = (float*)H1;
  bf16* x3b  = (bf16*)H2;
  bf16* aggb = (bf16*)X0;
  bf16* x4b  = (bf16*)(H2 + (size_t)NN * 128);
  bf16* tx1b = (bf16*)X0;
  bf16* x5b  = (bf16*)(H2 + (size_t)NN * 256);
  bf16* xpb  = (bf16*)H1;
  bf16* x6b  = (bf16*)X0;

  auto mm = [&](const bf16* A1, const short* B1h, const short* B1l, int K1,
                const bf16* A2, const short* B2h, const short* B2l, int K2,
                const float* bias, bf16* C, int M, int N, int flags){
    dim3 g(N / 64, cdiv(M, 64));
    int np = A2 ? 2 : 1;
    k_mm64<<<g, 256, 0, stream>>>(A1, B1h, B1l, K1, A2, B2h, B2l, K2,
                                  bias, C, M, N, flags, np);
  };

  // CSR build + norms
  hipMemsetAsync(diag, 0, (size_t)(4 + NN) * 4, stream);
  k_ideg<<<cdiv(NE, 256), 256, 0, stream>>>(dst, ideg);
  k_scan<<<1, 256, 0, stream>>>(ideg, rowptr, cursor, dg, dc, ic);
  k_fill<<<cdiv(NE, 256), 256, 0, stream>>>(src, dst, cursor, colsrc);

  // batched weight prep (single launch)
  {
    WtPack p;
    const float* Ws[10] = {W1, W2, Wg1, Wg2, Wsl, Wsr, Wc0, Wc1, Wgat1, Wgat2};
    short* his[10] = {w1h, w2h, wg1h, wg2h, wslh, wsrh, wc0h, wc1h, wgat1h, wgat2h};
    short* los[10] = {w1l, w2l, wg1l, wg2l, wsll, wsrl, wc0l, wc1l, wgat1l, wgat2l};
    int Ks[10] = {128, 1024, 512, 256, 128, 128, 128, 128, 128, 128};
    int nss[10] = {10, 9, 8, 7, 7, 7, 7, 7, 8, 8};
    int off = 0;
    for (int i = 0; i < 10; i++){
      p.W[i] = Ws[i]; p.hi[i] = his[i]; p.lo[i] = los[i];
      p.K[i] = Ks[i]; p.nshift[i] = nss[i]; p.base[i] = off;
      off += Ks[i] << nss[i];
    }
    p.base[10] = off;
    k_wtall<<<cdiv(off, 256), 256, 0, stream>>>(p);
  }

  k_gather<<<cdiv(NN * 128, 256), 256, 0, stream>>>(uidx, iidx, ue, ie, x0b);

  // Phase A — MLP (two 10000-row chunks)
  for (int ofs = 0; ofs < NN; ofs += 10000){
    mm(x0b + (size_t)ofs * 128, w1h, w1l, 128, nullptr, nullptr, nullptr, 0,
       b1, h1b, 10000, 1024, GF_BIAS | GF_RELU);
    mm(h1b, w2h, w2l, 1024, nullptr, nullptr, nullptr, 0,
       b2, h2b + (size_t)ofs * 512, 10000, 512, GF_BIAS | GF_RELU);
  }

  // Phase B — GCN1 (512->256) + BN + relu
  mm(h2b, wg1h, wg1l, 512, nullptr, nullptr, nullptr, 0, nullptr, xw1b, NN, 256, 0);
  k_agg<<<cdiv(NN * 256, 256), 256, 0, stream>>>(rowptr, colsrc, xw1b, dg, nullptr, bg1, g1f, nullptr, 8, 0);
  hipMemsetAsync(stats, 0, 512 * 4, stream);
  k_bn_stats<<<cdiv(NN, 128), 256, 0, stream>>>(g1f, stats, 256);
  k_bn_apply<<<cdiv(NN * 256, 256), 256, 0, stream>>>(g1f, stats, gamma1, beta1, 8, NN * 256, g1b);

  // Phase C — GCN2 (256->128) + BN + relu
  mm(g1b, wg2h, wg2l, 256, nullptr, nullptr, nullptr, 0, nullptr, xw2b, NN, 128, 0);
  k_agg<<<cdiv(NN * 128, 256), 256, 0, stream>>>(rowptr, colsrc, xw2b, dg, nullptr, bg2, x3f, nullptr, 7, 0);
  hipMemsetAsync(stats, 0, 256 * 4, stream);
  k_bn_stats<<<cdiv(NN, 128), 256, 0, stream>>>(x3f, stats, 128);
  k_bn_apply<<<cdiv(NN * 128, 256), 256, 0, stream>>>(x3f, stats, gamma2, beta2, 7, NN * 128, x3b);

  // Phase D — SAGE
  k_agg<<<cdiv(NN * 128, 256), 256, 0, stream>>>(rowptr, colsrc, x3b, nullptr, ic, nullptr, nullptr, aggb, 7, 1);
  mm(aggb, wslh, wsll, 128, x3b, wsrh, wsrl, 128, bsl, x4b, NN, 128, GF_BIAS | GF_RELU);

  // Phase E — Cheb
  k_agg<<<cdiv(NN * 128, 256), 256, 0, stream>>>(rowptr, colsrc, x4b, dc, nullptr, nullptr, nullptr, tx1b, 7, 2);
  mm(x4b, wc0h, wc0l, 128, tx1b, wc1h, wc1l, 128, bc, x5b, NN, 128, GF_BIAS | GF_RELU);

  // Phase F — GAT1
  mm(x5b, wgat1h, wgat1l, 128, nullptr, nullptr, nullptr, 0, nullptr, xpb, NN, 256, 0);
  k_gat_alar<<<cdiv(NN, 4), 256, 0, stream>>>(xpb, as1, ad1, al, ar);
  k_gat<<<NN, 64, 0, stream>>>(rowptr, colsrc, xpb, al, ar, bgat1, x6b,
                               nullptr, nullptr, nullptr);
  k_chk_bf<<<256, 256, 0, stream>>>((const unsigned short*)x6b, NN * 128, 16, diag);

  // Phase G — GAT2 (final projection fused -> fp32 out)
  mm(x6b, wgat2h, wgat2l, 128, nullptr, nullptr, nullptr, 0, nullptr, xpb, NN, 256, 0);
  k_gat_alar<<<cdiv(NN, 4), 256, 0, stream>>>(xpb, as2, ad2, al, ar);
  k_gat<<<NN, 64, 0, stream>>>(rowptr, colsrc, xpb, al, ar, bgat2, nullptr,
                               Wp, bp, (float*)d_out);
  k_diag_out<<<cdiv(NN, 256), 256, 0, stream>>>(diag, (float*)d_out);
}

// Round 10
// 751.470 us; speedup vs baseline: 5.2430x; 1.0845x over previous
//
#include <hip/hip_runtime.h>
#include <hip/hip_bf16.h>

typedef __hip_bfloat16 bf16;
typedef short s8v __attribute__((ext_vector_type(8)));
typedef float f4v __attribute__((ext_vector_type(4)));

#define NN 20000
#define NE 160000
#define BN_EPS 1e-5f
#define NB 79   // cdiv(NN,256)

#define GF_BIAS 1
#define GF_RELU 2

static __device__ __forceinline__ float b2f(const bf16 x){ return __bfloat162float(x); }
static __device__ __forceinline__ float bits2f(unsigned int u){ return __uint_as_float(u << 16); }
static __device__ __forceinline__ unsigned short f2bits(float f){
  bf16 h = __float2bfloat16(f);
  unsigned short u; __builtin_memcpy(&u, &h, 2); return u;
}
static __device__ __forceinline__ float lrelu(float v){ return (v > 0.f) ? v : 0.2f * v; }

static inline int cdiv(int a, int b){ return (a + b - 1) / b; }

// ---------------- diagnostics ----------------

__global__ void k_chk_bf(const unsigned short* __restrict__ x, int n, int code,
                         int* __restrict__ diag){
  bool bad = false;
  for (int k = blockIdx.x * 256 + threadIdx.x; k < n; k += gridDim.x * 256)
    if ((x[k] & 0x7F80u) == 0x7F80u) bad = true;
  if (bad) atomicCAS(diag, 0, code);
}

__global__ void k_diag_out(const int* __restrict__ diag, float* __restrict__ out){
  int d = *diag;
  if (d == 0) return;
  int i = blockIdx.x * 256 + threadIdx.x;
  if (i < NN) out[i] = (float)(d * 100);
}

// ---------------- CSR build (hierarchical, coalesced) ----------------

__global__ void k_ideg(const int* __restrict__ dst, int* __restrict__ ideg){
  int e = blockIdx.x * 256 + threadIdx.x;
  if (e < NE) atomicAdd(&ideg[dst[e]], 1);
}

// phase 1: per-block inclusive scan (into tmp=cursor) + block sums
__global__ __launch_bounds__(256) void k_scan1(const int* __restrict__ ideg,
                                               int* __restrict__ tmp,
                                               int* __restrict__ bsum){
  __shared__ int lds[256];
  int tid = threadIdx.x;
  int i = blockIdx.x * 256 + tid;
  int v = (i < NN) ? ideg[i] : 0;
  lds[tid] = v;
  __syncthreads();
  for (int off = 1; off < 256; off <<= 1){
    int t = (tid >= off) ? lds[tid - off] : 0;
    __syncthreads();
    lds[tid] += t;
    __syncthreads();
  }
  if (i < NN) tmp[i] = lds[tid];
  if (tid == 255) bsum[blockIdx.x] = lds[255];
}

// phase 2: exclusive scan of NB block sums (one tiny block)
__global__ __launch_bounds__(128) void k_scan2(const int* __restrict__ bsum,
                                               int* __restrict__ boff){
  __shared__ int lds[128];
  int tid = threadIdx.x;
  int v = (tid < NB) ? bsum[tid] : 0;
  lds[tid] = v;
  __syncthreads();
  for (int off = 1; off < 128; off <<= 1){
    int t = (tid >= off) ? lds[tid - off] : 0;
    __syncthreads();
    lds[tid] += t;
    __syncthreads();
  }
  if (tid < NB) boff[tid] = lds[tid] - v;
}

// phase 3: finalize rowptr/cursor + degree norms, coalesced
__global__ __launch_bounds__(256) void k_scan3(const int* __restrict__ ideg,
                                               const int* __restrict__ boff,
                                               int* __restrict__ rowptr,
                                               int* __restrict__ cursor,  // holds tmp
                                               float* __restrict__ dg,
                                               float* __restrict__ dc,
                                               float* __restrict__ ic){
  int i = blockIdx.x * 256 + threadIdx.x;
  if (i == 0) rowptr[NN] = NE;
  if (i >= NN) return;
  int v = ideg[i];
  int excl = cursor[i] - v + boff[blockIdx.x];
  rowptr[i] = excl;
  cursor[i] = excl;
  float d = (float)v;
  dg[i] = rsqrtf(d + 1.0f);
  dc[i] = (d > 0.f) ? rsqrtf(d) : 0.f;
  ic[i] = 1.0f / fmaxf(d, 1.0f);
}

__global__ void k_fill(const int* __restrict__ src, const int* __restrict__ dst,
                       int* __restrict__ cursor, int* __restrict__ colsrc){
  int e = blockIdx.x * 256 + threadIdx.x;
  if (e >= NE) return;
  int pos = atomicAdd(&cursor[dst[e]], 1);
  colsrc[pos] = src[e];
}

// ---- batched weight prep: all W[K][N] fp32 -> WT_hi/WT_lo [N][K] bf16, one launch ----

struct WtPack {
  const float* W[10]; short* hi[10]; short* lo[10];
  int K[10]; int nshift[10]; int base[11];
};

__global__ __launch_bounds__(256) void k_wtall(WtPack p){
  int idx = blockIdx.x * 256 + threadIdx.x;
  if (idx >= p.base[10]) return;
  int seg = 0;
#pragma unroll
  for (int i = 1; i < 10; i++) seg += (idx >= p.base[i]) ? 1 : 0;
  int local = idx - p.base[seg];
  int K = p.K[seg], ns = p.nshift[seg];
  int n = local & ((1 << ns) - 1), k = local >> ns;
  float w = p.W[seg][local];
  unsigned short h = f2bits(w);
  unsigned short l = f2bits(w - bits2f(h));
  p.hi[seg][(size_t)n * K + k] = (short)h;
  p.lo[seg][(size_t)n * K + k] = (short)l;
}

// ---------------- gather: fp32 embeddings -> bf16 x0 ----------------

__global__ void k_gather(const int* __restrict__ uidx, const int* __restrict__ iidx,
                         const float* __restrict__ ue, const float* __restrict__ ie,
                         bf16* __restrict__ x0){
  int idx = blockIdx.x * 256 + threadIdx.x;
  if (idx >= NN * 128) return;
  int i = idx >> 7, c = idx & 127;
  float v = (c < 64) ? ue[(size_t)uidx[i] * 64 + c] : ie[(size_t)iidx[i] * 64 + (c - 64)];
  x0[idx] = __float2bfloat16(v);
}

// ------- MFMA GEMM, 64x64 tile, 4 waves, hi/lo fused in one K-sweep -------

__global__ __launch_bounds__(256) void k_mm64(
    const bf16* A0, const short* B0h, const short* B0l, int K0,
    const bf16* A1, const short* B1h, const short* B1l, int K1,
    const float* __restrict__ bias, bf16* __restrict__ C,
    int M, int Ncol, int flags, int npass){
  __shared__ short As[64][40];
  __shared__ short Bhs[64][40];
  __shared__ short Bls[64][40];
  const int tid = threadIdx.x;
  const int row0 = blockIdx.y * 64, col0 = blockIdx.x * 64;
  const int wid = tid >> 6, lane = tid & 63;
  const int wr = (wid >> 1) * 32, wc = (wid & 1) * 32;
  const int lr = lane & 15, lq = lane >> 4;
  const int sr = tid >> 2, sq = (tid & 3) * 8;

  f4v acc[2][2];
#pragma unroll
  for (int i = 0; i < 2; i++)
#pragma unroll
    for (int j = 0; j < 2; j++)
      acc[i][j] = f4v{0.f, 0.f, 0.f, 0.f};

  const bf16* Aarr[2] = {A0, A1};
  const short* Bharr[2] = {B0h, B1h};
  const short* Blarr[2] = {B0l, B1l};
  const int Karr[2] = {K0, K1};

  for (int p = 0; p < npass; p++){
    const short* A = (const short*)Aarr[p];
    const short* Bh = Bharr[p];
    const short* Bl = Blarr[p];
    const int K = Karr[p];
    for (int k0 = 0; k0 < K; k0 += 32){
      uint4 va = make_uint4(0u, 0u, 0u, 0u);
      int grow = row0 + sr;
      if (grow < M) va = *(const uint4*)(A + (size_t)grow * K + k0 + sq);
      *(uint4*)&As[sr][sq] = va;
      size_t boff = (size_t)(col0 + sr) * K + k0 + sq;
      *(uint4*)&Bhs[sr][sq] = *(const uint4*)(Bh + boff);
      *(uint4*)&Bls[sr][sq] = *(const uint4*)(Bl + boff);
      __syncthreads();
      s8v a[2], bh[2], bl[2];
#pragma unroll
      for (int i = 0; i < 2; i++) a[i] = *(const s8v*)&As[wr + i * 16 + lr][lq * 8];
#pragma unroll
      for (int j = 0; j < 2; j++){
        bh[j] = *(const s8v*)&Bhs[wc + j * 16 + lr][lq * 8];
        bl[j] = *(const s8v*)&Bls[wc + j * 16 + lr][lq * 8];
      }
#pragma unroll
      for (int i = 0; i < 2; i++)
#pragma unroll
        for (int j = 0; j < 2; j++){
          acc[i][j] = __builtin_amdgcn_mfma_f32_16x16x32_bf16(a[i], bh[j], acc[i][j], 0, 0, 0);
          acc[i][j] = __builtin_amdgcn_mfma_f32_16x16x32_bf16(a[i], bl[j], acc[i][j], 0, 0, 0);
        }
      __syncthreads();
    }
  }

#pragma unroll
  for (int i = 0; i < 2; i++){
#pragma unroll
    for (int rg = 0; rg < 4; rg++){
      int row = row0 + wr + i * 16 + lq * 4 + rg;
      if (row >= M) continue;
#pragma unroll
      for (int j = 0; j < 2; j++){
        int col = col0 + wc + j * 16 + lr;
        float v = acc[i][j][rg];
        if (flags & GF_BIAS) v += bias[col];
        if (flags & GF_RELU) v = fmaxf(v, 0.f);
        C[(size_t)row * Ncol + col] = __float2bfloat16(v);
      }
    }
  }
}

// ---------------- CSR aggregation (no atomics) ----------------

__global__ void k_agg(const int* __restrict__ rowptr, const int* __restrict__ colsrc,
                      const bf16* __restrict__ x, const float* __restrict__ wn,
                      const float* __restrict__ icv, const float* __restrict__ bias,
                      float* __restrict__ outf, bf16* __restrict__ outb,
                      int fshift, int mode){
  int idx = blockIdx.x * 256 + threadIdx.x;
  int total = NN << fshift;
  if (idx >= total) return;
  int d = idx >> fshift, c = idx & ((1 << fshift) - 1);
  int F = 1 << fshift;
  int r0 = rowptr[d], r1 = rowptr[d + 1];
  float sum = 0.f;
  if (mode == 0){
    for (int r = r0; r < r1; r++){
      int s = colsrc[r];
      sum += wn[s] * b2f(x[(size_t)s * F + c]);
    }
    float w = wn[d];
    outf[idx] = w * sum + w * w * b2f(x[(size_t)d * F + c]) + bias[c];
  } else if (mode == 1){
    for (int r = r0; r < r1; r++)
      sum += b2f(x[(size_t)colsrc[r] * F + c]);
    outb[idx] = __float2bfloat16(sum * icv[d]);
  } else {
    for (int r = r0; r < r1; r++){
      int s = colsrc[r];
      sum += wn[s] * b2f(x[(size_t)s * F + c]);
    }
    outb[idx] = __float2bfloat16(-wn[d] * sum);
  }
}

// ---------------- batchnorm (training-mode, biased var) ----------------

__global__ void k_bn_stats(const float* __restrict__ x, float* __restrict__ stats, int F){
  int c = threadIdx.x & (F - 1);
  int rsub = threadIdx.x / F;
  int rpi = 256 / F;
  int r0 = blockIdx.x * 128;
  int rend = min(NN, r0 + 128);
  float s1 = 0.f, s2 = 0.f;
  for (int r = r0 + rsub; r < rend; r += rpi){
    float v = x[(size_t)r * F + c];
    s1 += v; s2 += v * v;
  }
  atomicAdd(&stats[c], s1);
  atomicAdd(&stats[F + c], s2);
}

__global__ void k_bn_apply(const float* __restrict__ x, const float* __restrict__ stats,
                           const float* __restrict__ g, const float* __restrict__ b,
                           int fshift, int total, bf16* __restrict__ out){
  int idx = blockIdx.x * 256 + threadIdx.x;
  if (idx >= total) return;
  int F = 1 << fshift;
  int c = idx & (F - 1);
  float mu = stats[c] * (1.0f / NN);
  float var = fmaxf(stats[F + c] * (1.0f / NN) - mu * mu, 0.f);
  float v = (x[idx] - mu) * rsqrtf(var + BN_EPS) * g[c] + b[c];
  out[idx] = __float2bfloat16(fmaxf(v, 0.f));
}

// ---------------- GAT ----------------

__global__ __launch_bounds__(256) void k_gat_alar(const bf16* __restrict__ xp,
                                                  const float* __restrict__ as_,
                                                  const float* __restrict__ ad_,
                                                  float* __restrict__ al,
                                                  float* __restrict__ ar){
  int d = blockIdx.x * 4 + (threadIdx.x >> 6);
  int lane = threadIdx.x & 63;
  if (d >= NN) return;
  int c0 = lane * 2;
  unsigned int p0 = *(const unsigned int*)((const short*)xp + (size_t)d * 256 + c0);
  unsigned int p1 = *(const unsigned int*)((const short*)xp + (size_t)d * 256 + 128 + c0);
  float x00 = bits2f(p0 & 0xffffu), x01 = bits2f(p0 >> 16);
  float x10 = bits2f(p1 & 0xffffu), x11 = bits2f(p1 >> 16);
  float sa0 = x00 * as_[c0] + x01 * as_[c0 + 1];
  float sd0 = x00 * ad_[c0] + x01 * ad_[c0 + 1];
  float sa1 = x10 * as_[128 + c0] + x11 * as_[128 + c0 + 1];
  float sd1 = x10 * ad_[128 + c0] + x11 * ad_[128 + c0 + 1];
#pragma unroll
  for (int off = 32; off > 0; off >>= 1){
    sa0 += __shfl_xor(sa0, off); sd0 += __shfl_xor(sd0, off);
    sa1 += __shfl_xor(sa1, off); sd1 += __shfl_xor(sd1, off);
  }
  if (lane == 0){
    al[d * 2] = sa0;     ar[d * 2] = sd0;
    al[d * 2 + 1] = sa1; ar[d * 2 + 1] = sd1;
  }
}

__global__ __launch_bounds__(64) void k_gat(const int* __restrict__ rowptr,
                                            const int* __restrict__ colsrc,
                                            const bf16* __restrict__ xp,
                                            const float* __restrict__ al,
                                            const float* __restrict__ ar,
                                            const float* __restrict__ bias,
                                            bf16* __restrict__ outb,
                                            const float* __restrict__ wp,
                                            const float* __restrict__ bp,
                                            float* __restrict__ outf){
  __shared__ float w0s[64], w1s[64];
  __shared__ int ss[64];
  int d = blockIdx.x;
  int lane = threadIdx.x;
  int r0 = rowptr[d], r1 = rowptr[d + 1];
  float ard0 = ar[d * 2], ard1 = ar[d * 2 + 1];
  float e0 = lrelu(al[d * 2] + ard0);
  float e1 = lrelu(al[d * 2 + 1] + ard1);
  float mx0 = e0, mx1 = e1;
  for (int r = r0 + lane; r < r1; r += 64){
    int s = colsrc[r];
    mx0 = fmaxf(mx0, lrelu(al[s * 2] + ard0));
    mx1 = fmaxf(mx1, lrelu(al[s * 2 + 1] + ard1));
  }
#pragma unroll
  for (int off = 32; off > 0; off >>= 1){
    mx0 = fmaxf(mx0, __shfl_xor(mx0, off));
    mx1 = fmaxf(mx1, __shfl_xor(mx1, off));
  }
  float ps0 = (lane == 0) ? expf(e0 - mx0) : 0.f;
  float ps1 = (lane == 0) ? expf(e1 - mx1) : 0.f;
  for (int r = r0 + lane; r < r1; r += 64){
    int s = colsrc[r];
    ps0 += expf(lrelu(al[s * 2] + ard0) - mx0);
    ps1 += expf(lrelu(al[s * 2 + 1] + ard1) - mx1);
  }
#pragma unroll
  for (int off = 32; off > 0; off >>= 1){
    ps0 += __shfl_xor(ps0, off);
    ps1 += __shfl_xor(ps1, off);
  }
  int c0 = lane * 2;
  float a00, a01, a10, a11;
  {
    float w0 = expf(e0 - mx0), w1 = expf(e1 - mx1);
    unsigned int p0 = *(const unsigned int*)((const short*)xp + (size_t)d * 256 + c0);
    unsigned int p1 = *(const unsigned int*)((const short*)xp + (size_t)d * 256 + 128 + c0);
    a00 = w0 * bits2f(p0 & 0xffffu); a01 = w0 * bits2f(p0 >> 16);
    a10 = w1 * bits2f(p1 & 0xffffu); a11 = w1 * bits2f(p1 >> 16);
  }
  for (int t0 = r0; t0 < r1; t0 += 64){
    int nt = min(64, r1 - t0);
    __syncthreads();
    if (lane < nt){
      int s = colsrc[t0 + lane];
      ss[lane] = s;
      w0s[lane] = expf(lrelu(al[s * 2] + ard0) - mx0);
      w1s[lane] = expf(lrelu(al[s * 2 + 1] + ard1) - mx1);
    }
    __syncthreads();
    for (int r = 0; r < nt; r++){
      int s = ss[r];
      float w0 = w0s[r], w1 = w1s[r];
      unsigned int p0 = *(const unsigned int*)((const short*)xp + (size_t)s * 256 + c0);
      unsigned int p1 = *(const unsigned int*)((const short*)xp + (size_t)s * 256 + 128 + c0);
      a00 += w0 * bits2f(p0 & 0xffffu); a01 += w0 * bits2f(p0 >> 16);
      a10 += w1 * bits2f(p1 & 0xffffu); a11 += w1 * bits2f(p1 >> 16);
    }
  }
  float v0 = 0.5f * (a00 / ps0 + a10 / ps1) + bias[c0];
  float v1 = 0.5f * (a01 / ps0 + a11 / ps1) + bias[c0 + 1];
  v0 = (v0 > 0.f) ? v0 : expm1f(v0);
  v1 = (v1 > 0.f) ? v1 : expm1f(v1);
  if (wp == nullptr){
    unsigned int packed = (unsigned int)f2bits(v0) | ((unsigned int)f2bits(v1) << 16);
    *(unsigned int*)((short*)outb + (size_t)d * 128 + c0) = packed;
  } else {
    float pv = v0 * wp[c0] + v1 * wp[c0 + 1];
#pragma unroll
    for (int off = 32; off > 0; off >>= 1) pv += __shfl_down(pv, off);
    if (lane == 0) outf[d] = pv + bp[0];
  }
}

// ---------------- host ----------------

extern "C" void kernel_launch(void* const* d_in, const int* in_sizes, int n_in,
                              void* d_out, int out_size, void* d_ws, size_t ws_size,
                              hipStream_t stream){
  const int* uidx = (const int*)d_in[0];
  const int* iidx = (const int*)d_in[1];
  const int* eidx = (const int*)d_in[2];
  const int* src = eidx;
  const int* dst = eidx + NE;
  const float* ue  = (const float*)d_in[3];
  const float* ie  = (const float*)d_in[4];
  const float* W1  = (const float*)d_in[5];  const float* b1  = (const float*)d_in[6];
  const float* W2  = (const float*)d_in[7];  const float* b2  = (const float*)d_in[8];
  const float* Wg1 = (const float*)d_in[9];  const float* bg1 = (const float*)d_in[10];
  const float* gamma1 = (const float*)d_in[11]; const float* beta1 = (const float*)d_in[12];
  const float* Wg2 = (const float*)d_in[13]; const float* bg2 = (const float*)d_in[14];
  const float* gamma2 = (const float*)d_in[15]; const float* beta2 = (const float*)d_in[16];
  const float* Wsl = (const float*)d_in[17]; const float* bsl = (const float*)d_in[18];
  const float* Wsr = (const float*)d_in[19];
  const float* Wc0 = (const float*)d_in[20]; const float* Wc1 = (const float*)d_in[21];
  const float* bc  = (const float*)d_in[22];
  const float* Wgat1 = (const float*)d_in[23]; const float* as1 = (const float*)d_in[24];
  const float* ad1 = (const float*)d_in[25];   const float* bgat1 = (const float*)d_in[26];
  const float* Wgat2 = (const float*)d_in[27]; const float* as2 = (const float*)d_in[28];
  const float* ad2 = (const float*)d_in[29];   const float* bgat2 = (const float*)d_in[30];
  const float* Wp  = (const float*)d_in[31];   const float* bp  = (const float*)d_in[32];

  // ---- workspace (~51.3 MB) ----
  // [zeroed in ONE memset: diag, ideg, stats1, stats2]
  int* diag   = (int*)d_ws;                        // 4
  int* ideg   = diag + 4;                          // NN
  float* stats1 = (float*)(ideg + NN);             // 512
  float* stats2 = stats1 + 512;                    // 256
  int* bsum   = (int*)(stats2 + 256);              // 128
  int* boff   = bsum + 128;                        // 128
  int* rowptr = boff + 128;                        // NN+4
  int* cursor = rowptr + NN + 4;                   // NN
  int* colsrc = cursor + NN;                       // NE
  float* dg = (float*)(colsrc + NE);               // NN
  float* dc = dg + NN;                             // NN
  float* ic = dc + NN;                             // NN
  float* al = ic + NN;                             // 2NN
  float* ar = al + 2 * NN;                         // 2NN
  short* w1h = (short*)(ar + 2 * NN);
  short* w1l = w1h + 131072;
  short* w2h = w1l + 131072;
  short* w2l = w2h + 524288;
  short* wg1h = w2l + 524288;
  short* wg1l = wg1h + 131072;
  short* wg2h = wg1l + 131072;
  short* wg2l = wg2h + 32768;
  short* wslh = wg2l + 32768;
  short* wsll = wslh + 16384;
  short* wsrh = wsll + 16384;
  short* wsrl = wsrh + 16384;
  short* wc0h = wsrl + 16384;
  short* wc0l = wc0h + 16384;
  short* wc1h = wc0l + 16384;
  short* wc1l = wc1h + 16384;
  short* wgat1h = wc1l + 16384;
  short* wgat1l = wgat1h + 32768;
  short* wgat2h = wgat1l + 32768;
  short* wgat2l = wgat2h + 32768;
  short* X0 = wgat2l + 32768;                      // NN*128
  short* H1 = X0 + (size_t)NN * 128;               // 10000*1024
  short* H2 = H1 + (size_t)10000 * 1024;           // NN*512

  bf16* x0b  = (bf16*)X0;
  bf16* h1b  = (bf16*)H1;
  bf16* h2b  = (bf16*)H2;
  bf16* xw1b = (bf16*)H1;
  float* g1f = (float*)H2;
  bf16* g1b  = (bf16*)(H1 + (size_t)NN * 256);
  bf16* xw2b = (bf16*)X0;
  float* x3f = (float*)H1;
  bf16* x3b  = (bf16*)H2;
  bf16* aggb = (bf16*)X0;
  bf16* x4b  = (bf16*)(H2 + (size_t)NN * 128);
  bf16* tx1b = (bf16*)X0;
  bf16* x5b  = (bf16*)(H2 + (size_t)NN * 256);
  bf16* xpb  = (bf16*)H1;
  bf16* x6b  = (bf16*)X0;

  auto mm = [&](const bf16* A1, const short* B1h, const short* B1l, int K1,
                const bf16* A2, const short* B2h, const short* B2l, int K2,
                const float* bias, bf16* C, int M, int N, int flags){
    dim3 g(N / 64, cdiv(M, 64));
    int np = A2 ? 2 : 1;
    k_mm64<<<g, 256, 0, stream>>>(A1, B1h, B1l, K1, A2, B2h, B2l, K2,
                                  bias, C, M, N, flags, np);
  };

  // single memset zeroes diag + ideg + stats1 + stats2 (contiguous)
  hipMemsetAsync(diag, 0, (size_t)(4 + NN + 768) * 4, stream);

  // CSR build + norms (hierarchical coalesced scan)
  k_ideg<<<cdiv(NE, 256), 256, 0, stream>>>(dst, ideg);
  k_scan1<<<NB, 256, 0, stream>>>(ideg, cursor, bsum);
  k_scan2<<<1, 128, 0, stream>>>(bsum, boff);
  k_scan3<<<NB, 256, 0, stream>>>(ideg, boff, rowptr, cursor, dg, dc, ic);
  k_fill<<<cdiv(NE, 256), 256, 0, stream>>>(src, dst, cursor, colsrc);

  // batched weight prep (single launch)
  {
    WtPack p;
    const float* Ws[10] = {W1, W2, Wg1, Wg2, Wsl, Wsr, Wc0, Wc1, Wgat1, Wgat2};
    short* his[10] = {w1h, w2h, wg1h, wg2h, wslh, wsrh, wc0h, wc1h, wgat1h, wgat2h};
    short* los[10] = {w1l, w2l, wg1l, wg2l, wsll, wsrl, wc0l, wc1l, wgat1l, wgat2l};
    int Ks[10] = {128, 1024, 512, 256, 128, 128, 128, 128, 128, 128};
    int nss[10] = {10, 9, 8, 7, 7, 7, 7, 7, 8, 8};
    int off = 0;
    for (int i = 0; i < 10; i++){
      p.W[i] = Ws[i]; p.hi[i] = his[i]; p.lo[i] = los[i];
      p.K[i] = Ks[i]; p.nshift[i] = nss[i]; p.base[i] = off;
      off += Ks[i] << nss[i];
    }
    p.base[10] = off;
    k_wtall<<<cdiv(off, 256), 256, 0, stream>>>(p);
  }

  k_gather<<<cdiv(NN * 128, 256), 256, 0, stream>>>(uidx, iidx, ue, ie, x0b);

  // Phase A — MLP (two 10000-row chunks)
  for (int ofs = 0; ofs < NN; ofs += 10000){
    mm(x0b + (size_t)ofs * 128, w1h, w1l, 128, nullptr, nullptr, nullptr, 0,
       b1, h1b, 10000, 1024, GF_BIAS | GF_RELU);
    mm(h1b, w2h, w2l, 1024, nullptr, nullptr, nullptr, 0,
       b2, h2b + (size_t)ofs * 512, 10000, 512, GF_BIAS | GF_RELU);
  }

  // Phase B — GCN1 (512->256) + BN + relu
  mm(h2b, wg1h, wg1l, 512, nullptr, nullptr, nullptr, 0, nullptr, xw1b, NN, 256, 0);
  k_agg<<<cdiv(NN * 256, 256), 256, 0, stream>>>(rowptr, colsrc, xw1b, dg, nullptr, bg1, g1f, nullptr, 8, 0);
  k_bn_stats<<<cdiv(NN, 128), 256, 0, stream>>>(g1f, stats1, 256);
  k_bn_apply<<<cdiv(NN * 256, 256), 256, 0, stream>>>(g1f, stats1, gamma1, beta1, 8, NN * 256, g1b);

  // Phase C — GCN2 (256->128) + BN + relu
  mm(g1b, wg2h, wg2l, 256, nullptr, nullptr, nullptr, 0, nullptr, xw2b, NN, 128, 0);
  k_agg<<<cdiv(NN * 128, 256), 256, 0, stream>>>(rowptr, colsrc, xw2b, dg, nullptr, bg2, x3f, nullptr, 7, 0);
  k_bn_stats<<<cdiv(NN, 128), 256, 0, stream>>>(x3f, stats2, 128);
  k_bn_apply<<<cdiv(NN * 128, 256), 256, 0, stream>>>(x3f, stats2, gamma2, beta2, 7, NN * 128, x3b);

  // Phase D — SAGE
  k_agg<<<cdiv(NN * 128, 256), 256, 0, stream>>>(rowptr, colsrc, x3b, nullptr, ic, nullptr, nullptr, aggb, 7, 1);
  mm(aggb, wslh, wsll, 128, x3b, wsrh, wsrl, 128, bsl, x4b, NN, 128, GF_BIAS | GF_RELU);

  // Phase E — Cheb
  k_agg<<<cdiv(NN * 128, 256), 256, 0, stream>>>(rowptr, colsrc, x4b, dc, nullptr, nullptr, nullptr, tx1b, 7, 2);
  mm(x4b, wc0h, wc0l, 128, tx1b, wc1h, wc1l, 128, bc, x5b, NN, 128, GF_BIAS | GF_RELU);

  // Phase F — GAT1
  mm(x5b, wgat1h, wgat1l, 128, nullptr, nullptr, nullptr, 0, nullptr, xpb, NN, 256, 0);
  k_gat_alar<<<cdiv(NN, 4), 256, 0, stream>>>(xpb, as1, ad1, al, ar);
  k_gat<<<NN, 64, 0, stream>>>(rowptr, colsrc, xpb, al, ar, bgat1, x6b,
                               nullptr, nullptr, nullptr);
  k_chk_bf<<<256, 256, 0, stream>>>((const unsigned short*)x6b, NN * 128, 16, diag);

  // Phase G — GAT2 (final projection fused -> fp32 out)
  mm(x6b, wgat2h, wgat2l, 128, nullptr, nullptr, nullptr, 0, nullptr, xpb, NN, 256, 0);
  k_gat_alar<<<cdiv(NN, 4), 256, 0, stream>>>(xpb, as2, ad2, al, ar);
  k_gat<<<NN, 64, 0, stream>>>(rowptr, colsrc, xpb, al, ar, bgat2, nullptr,
                               Wp, bp, (float*)d_out);
  k_diag_out<<<cdiv(NN, 256), 256, 0, stream>>>(diag, (float*)d_out);
}

// Round 11
// 731.020 us; speedup vs baseline: 5.3897x; 1.0280x over previous
//
#include <hip/hip_runtime.h>
#include <hip/hip_bf16.h>

typedef __hip_bfloat16 bf16;
typedef short s8v __attribute__((ext_vector_type(8)));
typedef float f4v __attribute__((ext_vector_type(4)));

#define NN 20000
#define NE 160000
#define BN_EPS 1e-5f
#define NB 79   // cdiv(NN,256)

#define GF_BIAS 1
#define GF_RELU 2

static __device__ __forceinline__ float b2f(const bf16 x){ return __bfloat162float(x); }
static __device__ __forceinline__ float bits2f(unsigned int u){ return __uint_as_float(u << 16); }
static __device__ __forceinline__ unsigned short f2bits(float f){
  bf16 h = __float2bfloat16(f);
  unsigned short u; __builtin_memcpy(&u, &h, 2); return u;
}
static __device__ __forceinline__ float lrelu(float v){ return (v > 0.f) ? v : 0.2f * v; }

static inline int cdiv(int a, int b){ return (a + b - 1) / b; }

// ---------------- diagnostics ----------------

__global__ void k_chk_bf(const unsigned short* __restrict__ x, int n, int code,
                         int* __restrict__ diag){
  bool bad = false;
  for (int k = blockIdx.x * 256 + threadIdx.x; k < n; k += gridDim.x * 256)
    if ((x[k] & 0x7F80u) == 0x7F80u) bad = true;
  if (bad) atomicCAS(diag, 0, code);
}

__global__ void k_diag_out(const int* __restrict__ diag, float* __restrict__ out){
  int d = *diag;
  if (d == 0) return;
  int i = blockIdx.x * 256 + threadIdx.x;
  if (i < NN) out[i] = (float)(d * 100);
}

// ---------------- CSR build (hierarchical, coalesced) ----------------

__global__ void k_ideg(const int* __restrict__ dst, int* __restrict__ ideg){
  int e = blockIdx.x * 256 + threadIdx.x;
  if (e < NE) atomicAdd(&ideg[dst[e]], 1);
}

__global__ __launch_bounds__(256) void k_scan1(const int* __restrict__ ideg,
                                               int* __restrict__ tmp,
                                               int* __restrict__ bsum){
  __shared__ int lds[256];
  int tid = threadIdx.x;
  int i = blockIdx.x * 256 + tid;
  int v = (i < NN) ? ideg[i] : 0;
  lds[tid] = v;
  __syncthreads();
  for (int off = 1; off < 256; off <<= 1){
    int t = (tid >= off) ? lds[tid - off] : 0;
    __syncthreads();
    lds[tid] += t;
    __syncthreads();
  }
  if (i < NN) tmp[i] = lds[tid];
  if (tid == 255) bsum[blockIdx.x] = lds[255];
}

__global__ __launch_bounds__(128) void k_scan2(const int* __restrict__ bsum,
                                               int* __restrict__ boff){
  __shared__ int lds[128];
  int tid = threadIdx.x;
  int v = (tid < NB) ? bsum[tid] : 0;
  lds[tid] = v;
  __syncthreads();
  for (int off = 1; off < 128; off <<= 1){
    int t = (tid >= off) ? lds[tid - off] : 0;
    __syncthreads();
    lds[tid] += t;
    __syncthreads();
  }
  if (tid < NB) boff[tid] = lds[tid] - v;
}

__global__ __launch_bounds__(256) void k_scan3(const int* __restrict__ ideg,
                                               const int* __restrict__ boff,
                                               int* __restrict__ rowptr,
                                               int* __restrict__ cursor,
                                               float* __restrict__ dg,
                                               float* __restrict__ dc,
                                               float* __restrict__ ic){
  int i = blockIdx.x * 256 + threadIdx.x;
  if (i == 0) rowptr[NN] = NE;
  if (i >= NN) return;
  int v = ideg[i];
  int excl = cursor[i] - v + boff[blockIdx.x];
  rowptr[i] = excl;
  cursor[i] = excl;
  float d = (float)v;
  dg[i] = rsqrtf(d + 1.0f);
  dc[i] = (d > 0.f) ? rsqrtf(d) : 0.f;
  ic[i] = 1.0f / fmaxf(d, 1.0f);
}

__global__ void k_fill(const int* __restrict__ src, const int* __restrict__ dst,
                       int* __restrict__ cursor, int* __restrict__ colsrc){
  int e = blockIdx.x * 256 + threadIdx.x;
  if (e >= NE) return;
  int pos = atomicAdd(&cursor[dst[e]], 1);
  colsrc[pos] = src[e];
}

// ---- batched weight prep ----

struct WtPack {
  const float* W[10]; short* hi[10]; short* lo[10];
  int K[10]; int nshift[10]; int base[11];
};

__global__ __launch_bounds__(256) void k_wtall(WtPack p){
  int idx = blockIdx.x * 256 + threadIdx.x;
  if (idx >= p.base[10]) return;
  int seg = 0;
#pragma unroll
  for (int i = 1; i < 10; i++) seg += (idx >= p.base[i]) ? 1 : 0;
  int local = idx - p.base[seg];
  int K = p.K[seg], ns = p.nshift[seg];
  int n = local & ((1 << ns) - 1), k = local >> ns;
  float w = p.W[seg][local];
  unsigned short h = f2bits(w);
  unsigned short l = f2bits(w - bits2f(h));
  p.hi[seg][(size_t)n * K + k] = (short)h;
  p.lo[seg][(size_t)n * K + k] = (short)l;
}

// ---------------- gather ----------------

__global__ void k_gather(const int* __restrict__ uidx, const int* __restrict__ iidx,
                         const float* __restrict__ ue, const float* __restrict__ ie,
                         bf16* __restrict__ x0){
  int idx = blockIdx.x * 256 + threadIdx.x;
  if (idx >= NN * 128) return;
  int i = idx >> 7, c = idx & 127;
  float v = (c < 64) ? ue[(size_t)uidx[i] * 64 + c] : ie[(size_t)iidx[i] * 64 + (c - 64)];
  x0[idx] = __float2bfloat16(v);
}

// ------- MFMA GEMM, 64x64 tile, hi/lo fused, XCD-aware block swizzle -------
// Host guarantees gridDim.x*gridDim.y % 8 == 0. XCD = bid%8 (MI355X heuristic)
// gets a CONTIGUOUS logical tile range -> A row-bands stay in one XCD's L2.

__global__ __launch_bounds__(256) void k_mm64(
    const bf16* A0, const short* B0h, const short* B0l, int K0,
    const bf16* A1, const short* B1h, const short* B1l, int K1,
    const float* __restrict__ bias, bf16* __restrict__ C,
    int M, int Ncol, int flags, int npass){
  __shared__ short As[64][40];
  __shared__ short Bhs[64][40];
  __shared__ short Bls[64][40];
  const int tid = threadIdx.x;
  const int bid = blockIdx.y * gridDim.x + blockIdx.x;
  const int total = gridDim.x * gridDim.y;
  const int L = (bid & 7) * (total >> 3) + (bid >> 3);
  const int row0 = (L / gridDim.x) * 64, col0 = (L % gridDim.x) * 64;
  if (row0 >= M) return;                     // grid padding blocks exit pre-barrier
  const int wid = tid >> 6, lane = tid & 63;
  const int wr = (wid >> 1) * 32, wc = (wid & 1) * 32;
  const int lr = lane & 15, lq = lane >> 4;
  const int sr = tid >> 2, sq = (tid & 3) * 8;

  f4v acc[2][2];
#pragma unroll
  for (int i = 0; i < 2; i++)
#pragma unroll
    for (int j = 0; j < 2; j++)
      acc[i][j] = f4v{0.f, 0.f, 0.f, 0.f};

  const bf16* Aarr[2] = {A0, A1};
  const short* Bharr[2] = {B0h, B1h};
  const short* Blarr[2] = {B0l, B1l};
  const int Karr[2] = {K0, K1};

  for (int p = 0; p < npass; p++){
    const short* A = (const short*)Aarr[p];
    const short* Bh = Bharr[p];
    const short* Bl = Blarr[p];
    const int K = Karr[p];
    for (int k0 = 0; k0 < K; k0 += 32){
      uint4 va = make_uint4(0u, 0u, 0u, 0u);
      int grow = row0 + sr;
      if (grow < M) va = *(const uint4*)(A + (size_t)grow * K + k0 + sq);
      *(uint4*)&As[sr][sq] = va;
      size_t boff = (size_t)(col0 + sr) * K + k0 + sq;
      *(uint4*)&Bhs[sr][sq] = *(const uint4*)(Bh + boff);
      *(uint4*)&Bls[sr][sq] = *(const uint4*)(Bl + boff);
      __syncthreads();
      s8v a[2], bh[2], bl[2];
#pragma unroll
      for (int i = 0; i < 2; i++) a[i] = *(const s8v*)&As[wr + i * 16 + lr][lq * 8];
#pragma unroll
      for (int j = 0; j < 2; j++){
        bh[j] = *(const s8v*)&Bhs[wc + j * 16 + lr][lq * 8];
        bl[j] = *(const s8v*)&Bls[wc + j * 16 + lr][lq * 8];
      }
#pragma unroll
      for (int i = 0; i < 2; i++)
#pragma unroll
        for (int j = 0; j < 2; j++){
          acc[i][j] = __builtin_amdgcn_mfma_f32_16x16x32_bf16(a[i], bh[j], acc[i][j], 0, 0, 0);
          acc[i][j] = __builtin_amdgcn_mfma_f32_16x16x32_bf16(a[i], bl[j], acc[i][j], 0, 0, 0);
        }
      __syncthreads();
    }
  }

#pragma unroll
  for (int i = 0; i < 2; i++){
#pragma unroll
    for (int rg = 0; rg < 4; rg++){
      int row = row0 + wr + i * 16 + lq * 4 + rg;
      if (row >= M) continue;
#pragma unroll
      for (int j = 0; j < 2; j++){
        int col = col0 + wc + j * 16 + lr;
        float v = acc[i][j][rg];
        if (flags & GF_BIAS) v += bias[col];
        if (flags & GF_RELU) v = fmaxf(v, 0.f);
        C[(size_t)row * Ncol + col] = __float2bfloat16(v);
      }
    }
  }
}

// ---------------- CSR aggregation ----------------

__global__ void k_agg(const int* __restrict__ rowptr, const int* __restrict__ colsrc,
                      const bf16* __restrict__ x, const float* __restrict__ wn,
                      const float* __restrict__ icv, const float* __restrict__ bias,
                      float* __restrict__ outf, bf16* __restrict__ outb,
                      int fshift, int mode){
  int idx = blockIdx.x * 256 + threadIdx.x;
  int total = NN << fshift;
  if (idx >= total) return;
  int d = idx >> fshift, c = idx & ((1 << fshift) - 1);
  int F = 1 << fshift;
  int r0 = rowptr[d], r1 = rowptr[d + 1];
  float sum = 0.f;
  if (mode == 0){
    for (int r = r0; r < r1; r++){
      int s = colsrc[r];
      sum += wn[s] * b2f(x[(size_t)s * F + c]);
    }
    float w = wn[d];
    outf[idx] = w * sum + w * w * b2f(x[(size_t)d * F + c]) + bias[c];
  } else if (mode == 1){
    for (int r = r0; r < r1; r++)
      sum += b2f(x[(size_t)colsrc[r] * F + c]);
    outb[idx] = __float2bfloat16(sum * icv[d]);
  } else {
    for (int r = r0; r < r1; r++){
      int s = colsrc[r];
      sum += wn[s] * b2f(x[(size_t)s * F + c]);
    }
    outb[idx] = __float2bfloat16(-wn[d] * sum);
  }
}

// ---------------- batchnorm ----------------

__global__ void k_bn_stats(const float* __restrict__ x, float* __restrict__ stats, int F){
  int c = threadIdx.x & (F - 1);
  int rsub = threadIdx.x / F;
  int rpi = 256 / F;
  int r0 = blockIdx.x * 128;
  int rend = min(NN, r0 + 128);
  float s1 = 0.f, s2 = 0.f;
  for (int r = r0 + rsub; r < rend; r += rpi){
    float v = x[(size_t)r * F + c];
    s1 += v; s2 += v * v;
  }
  atomicAdd(&stats[c], s1);
  atomicAdd(&stats[F + c], s2);
}

__global__ void k_bn_apply(const float* __restrict__ x, const float* __restrict__ stats,
                           const float* __restrict__ g, const float* __restrict__ b,
                           int fshift, int total, bf16* __restrict__ out){
  int idx = blockIdx.x * 256 + threadIdx.x;
  if (idx >= total) return;
  int F = 1 << fshift;
  int c = idx & (F - 1);
  float mu = stats[c] * (1.0f / NN);
  float var = fmaxf(stats[F + c] * (1.0f / NN) - mu * mu, 0.f);
  float v = (x[idx] - mu) * rsqrtf(var + BN_EPS) * g[c] + b[c];
  out[idx] = __float2bfloat16(fmaxf(v, 0.f));
}

// ---------------- GAT ----------------

__global__ __launch_bounds__(256) void k_gat_alar(const bf16* __restrict__ xp,
                                                  const float* __restrict__ as_,
                                                  const float* __restrict__ ad_,
                                                  float* __restrict__ al,
                                                  float* __restrict__ ar){
  int d = blockIdx.x * 4 + (threadIdx.x >> 6);
  int lane = threadIdx.x & 63;
  if (d >= NN) return;
  int c0 = lane * 2;
  unsigned int p0 = *(const unsigned int*)((const short*)xp + (size_t)d * 256 + c0);
  unsigned int p1 = *(const unsigned int*)((const short*)xp + (size_t)d * 256 + 128 + c0);
  float x00 = bits2f(p0 & 0xffffu), x01 = bits2f(p0 >> 16);
  float x10 = bits2f(p1 & 0xffffu), x11 = bits2f(p1 >> 16);
  float sa0 = x00 * as_[c0] + x01 * as_[c0 + 1];
  float sd0 = x00 * ad_[c0] + x01 * ad_[c0 + 1];
  float sa1 = x10 * as_[128 + c0] + x11 * as_[128 + c0 + 1];
  float sd1 = x10 * ad_[128 + c0] + x11 * ad_[128 + c0 + 1];
#pragma unroll
  for (int off = 32; off > 0; off >>= 1){
    sa0 += __shfl_xor(sa0, off); sd0 += __shfl_xor(sd0, off);
    sa1 += __shfl_xor(sa1, off); sd1 += __shfl_xor(sd1, off);
  }
  if (lane == 0){
    al[d * 2] = sa0;     ar[d * 2] = sd0;
    al[d * 2 + 1] = sa1; ar[d * 2 + 1] = sd1;
  }
}

__global__ __launch_bounds__(64) void k_gat(const int* __restrict__ rowptr,
                                            const int* __restrict__ colsrc,
                                            const bf16* __restrict__ xp,
                                            const float* __restrict__ al,
                                            const float* __restrict__ ar,
                                            const float* __restrict__ bias,
                                            bf16* __restrict__ outb,
                                            const float* __restrict__ wp,
                                            const float* __restrict__ bp,
                                            float* __restrict__ outf){
  __shared__ float w0s[64], w1s[64];
  __shared__ int ss[64];
  int d = blockIdx.x;
  int lane = threadIdx.x;
  int r0 = rowptr[d], r1 = rowptr[d + 1];
  float ard0 = ar[d * 2], ard1 = ar[d * 2 + 1];
  float e0 = lrelu(al[d * 2] + ard0);
  float e1 = lrelu(al[d * 2 + 1] + ard1);
  float mx0 = e0, mx1 = e1;
  for (int r = r0 + lane; r < r1; r += 64){
    int s = colsrc[r];
    mx0 = fmaxf(mx0, lrelu(al[s * 2] + ard0));
    mx1 = fmaxf(mx1, lrelu(al[s * 2 + 1] + ard1));
  }
#pragma unroll
  for (int off = 32; off > 0; off >>= 1){
    mx0 = fmaxf(mx0, __shfl_xor(mx0, off));
    mx1 = fmaxf(mx1, __shfl_xor(mx1, off));
  }
  float ps0 = (lane == 0) ? expf(e0 - mx0) : 0.f;
  float ps1 = (lane == 0) ? expf(e1 - mx1) : 0.f;
  for (int r = r0 + lane; r < r1; r += 64){
    int s = colsrc[r];
    ps0 += expf(lrelu(al[s * 2] + ard0) - mx0);
    ps1 += expf(lrelu(al[s * 2 + 1] + ard1) - mx1);
  }
#pragma unroll
  for (int off = 32; off > 0; off >>= 1){
    ps0 += __shfl_xor(ps0, off);
    ps1 += __shfl_xor(ps1, off);
  }
  int c0 = lane * 2;
  float a00, a01, a10, a11;
  {
    float w0 = expf(e0 - mx0), w1 = expf(e1 - mx1);
    unsigned int p0 = *(const unsigned int*)((const short*)xp + (size_t)d * 256 + c0);
    unsigned int p1 = *(const unsigned int*)((const short*)xp + (size_t)d * 256 + 128 + c0);
    a00 = w0 * bits2f(p0 & 0xffffu); a01 = w0 * bits2f(p0 >> 16);
    a10 = w1 * bits2f(p1 & 0xffffu); a11 = w1 * bits2f(p1 >> 16);
  }
  for (int t0 = r0; t0 < r1; t0 += 64){
    int nt = min(64, r1 - t0);
    __syncthreads();
    if (lane < nt){
      int s = colsrc[t0 + lane];
      ss[lane] = s;
      w0s[lane] = expf(lrelu(al[s * 2] + ard0) - mx0);
      w1s[lane] = expf(lrelu(al[s * 2 + 1] + ard1) - mx1);
    }
    __syncthreads();
    for (int r = 0; r < nt; r++){
      int s = ss[r];
      float w0 = w0s[r], w1 = w1s[r];
      unsigned int p0 = *(const unsigned int*)((const short*)xp + (size_t)s * 256 + c0);
      unsigned int p1 = *(const unsigned int*)((const short*)xp + (size_t)s * 256 + 128 + c0);
      a00 += w0 * bits2f(p0 & 0xffffu); a01 += w0 * bits2f(p0 >> 16);
      a10 += w1 * bits2f(p1 & 0xffffu); a11 += w1 * bits2f(p1 >> 16);
    }
  }
  float v0 = 0.5f * (a00 / ps0 + a10 / ps1) + bias[c0];
  float v1 = 0.5f * (a01 / ps0 + a11 / ps1) + bias[c0 + 1];
  v0 = (v0 > 0.f) ? v0 : expm1f(v0);
  v1 = (v1 > 0.f) ? v1 : expm1f(v1);
  if (wp == nullptr){
    unsigned int packed = (unsigned int)f2bits(v0) | ((unsigned int)f2bits(v1) << 16);
    *(unsigned int*)((short*)outb + (size_t)d * 128 + c0) = packed;
  } else {
    float pv = v0 * wp[c0] + v1 * wp[c0 + 1];
#pragma unroll
    for (int off = 32; off > 0; off >>= 1) pv += __shfl_down(pv, off);
    if (lane == 0) outf[d] = pv + bp[0];
  }
}

// ---------------- host ----------------

extern "C" void kernel_launch(void* const* d_in, const int* in_sizes, int n_in,
                              void* d_out, int out_size, void* d_ws, size_t ws_size,
                              hipStream_t stream){
  const int* uidx = (const int*)d_in[0];
  const int* iidx = (const int*)d_in[1];
  const int* eidx = (const int*)d_in[2];
  const int* src = eidx;
  const int* dst = eidx + NE;
  const float* ue  = (const float*)d_in[3];
  const float* ie  = (const float*)d_in[4];
  const float* W1  = (const float*)d_in[5];  const float* b1  = (const float*)d_in[6];
  const float* W2  = (const float*)d_in[7];  const float* b2  = (const float*)d_in[8];
  const float* Wg1 = (const float*)d_in[9];  const float* bg1 = (const float*)d_in[10];
  const float* gamma1 = (const float*)d_in[11]; const float* beta1 = (const float*)d_in[12];
  const float* Wg2 = (const float*)d_in[13]; const float* bg2 = (const float*)d_in[14];
  const float* gamma2 = (const float*)d_in[15]; const float* beta2 = (const float*)d_in[16];
  const float* Wsl = (const float*)d_in[17]; const float* bsl = (const float*)d_in[18];
  const float* Wsr = (const float*)d_in[19];
  const float* Wc0 = (const float*)d_in[20]; const float* Wc1 = (const float*)d_in[21];
  const float* bc  = (const float*)d_in[22];
  const float* Wgat1 = (const float*)d_in[23]; const float* as1 = (const float*)d_in[24];
  const float* ad1 = (const float*)d_in[25];   const float* bgat1 = (const float*)d_in[26];
  const float* Wgat2 = (const float*)d_in[27]; const float* as2 = (const float*)d_in[28];
  const float* ad2 = (const float*)d_in[29];   const float* bgat2 = (const float*)d_in[30];
  const float* Wp  = (const float*)d_in[31];   const float* bp  = (const float*)d_in[32];

  // ---- workspace (~51.3 MB) ----
  int* diag   = (int*)d_ws;
  int* ideg   = diag + 4;
  float* stats1 = (float*)(ideg + NN);
  float* stats2 = stats1 + 512;
  int* bsum   = (int*)(stats2 + 256);
  int* boff   = bsum + 128;
  int* rowptr = boff + 128;
  int* cursor = rowptr + NN + 4;
  int* colsrc = cursor + NN;
  float* dg = (float*)(colsrc + NE);
  float* dc = dg + NN;
  float* ic = dc + NN;
  float* al = ic + NN;
  float* ar = al + 2 * NN;
  short* w1h = (short*)(ar + 2 * NN);
  short* w1l = w1h + 131072;
  short* w2h = w1l + 131072;
  short* w2l = w2h + 524288;
  short* wg1h = w2l + 524288;
  short* wg1l = wg1h + 131072;
  short* wg2h = wg1l + 131072;
  short* wg2l = wg2h + 32768;
  short* wslh = wg2l + 32768;
  short* wsll = wslh + 16384;
  short* wsrh = wsll + 16384;
  short* wsrl = wsrh + 16384;
  short* wc0h = wsrl + 16384;
  short* wc0l = wc0h + 16384;
  short* wc1h = wc0l + 16384;
  short* wc1l = wc1h + 16384;
  short* wgat1h = wc1l + 16384;
  short* wgat1l = wgat1h + 32768;
  short* wgat2h = wgat1l + 32768;
  short* wgat2l = wgat2h + 32768;
  short* X0 = wgat2l + 32768;
  short* H1 = X0 + (size_t)NN * 128;
  short* H2 = H1 + (size_t)10000 * 1024;

  bf16* x0b  = (bf16*)X0;
  bf16* h1b  = (bf16*)H1;
  bf16* h2b  = (bf16*)H2;
  bf16* xw1b = (bf16*)H1;
  float* g1f = (float*)H2;
  bf16* g1b  = (bf16*)(H1 + (size_t)NN * 256);
  bf16* xw2b = (bf16*)X0;
  float* x3f = (float*)H1;
  bf16* x3b  = (bf16*)H2;
  bf16* aggb = (bf16*)X0;
  bf16* x4b  = (bf16*)(H2 + (size_t)NN * 128);
  bf16* tx1b = (bf16*)X0;
  bf16* x5b  = (bf16*)(H2 + (size_t)NN * 256);
  bf16* xpb  = (bf16*)H1;
  bf16* x6b  = (bf16*)X0;

  auto mm = [&](const bf16* A1, const short* B1h, const short* B1l, int K1,
                const bf16* A2, const short* B2h, const short* B2l, int K2,
                const float* bias, bf16* C, int M, int N, int flags){
    int nx = N / 64;
    int ny = cdiv(M, 64);
    while ((nx * ny) & 7) ny++;          // pad so total blocks % 8 == 0 (swizzle)
    dim3 g(nx, ny);
    int np = A2 ? 2 : 1;
    k_mm64<<<g, 256, 0, stream>>>(A1, B1h, B1l, K1, A2, B2h, B2l, K2,
                                  bias, C, M, N, flags, np);
  };

  hipMemsetAsync(diag, 0, (size_t)(4 + NN + 768) * 4, stream);

  // CSR build + norms
  k_ideg<<<cdiv(NE, 256), 256, 0, stream>>>(dst, ideg);
  k_scan1<<<NB, 256, 0, stream>>>(ideg, cursor, bsum);
  k_scan2<<<1, 128, 0, stream>>>(bsum, boff);
  k_scan3<<<NB, 256, 0, stream>>>(ideg, boff, rowptr, cursor, dg, dc, ic);
  k_fill<<<cdiv(NE, 256), 256, 0, stream>>>(src, dst, cursor, colsrc);

  // batched weight prep
  {
    WtPack p;
    const float* Ws[10] = {W1, W2, Wg1, Wg2, Wsl, Wsr, Wc0, Wc1, Wgat1, Wgat2};
    short* his[10] = {w1h, w2h, wg1h, wg2h, wslh, wsrh, wc0h, wc1h, wgat1h, wgat2h};
    short* los[10] = {w1l, w2l, wg1l, wg2l, wsll, wsrl, wc0l, wc1l, wgat1l, wgat2l};
    int Ks[10] = {128, 1024, 512, 256, 128, 128, 128, 128, 128, 128};
    int nss[10] = {10, 9, 8, 7, 7, 7, 7, 7, 8, 8};
    int off = 0;
    for (int i = 0; i < 10; i++){
      p.W[i] = Ws[i]; p.hi[i] = his[i]; p.lo[i] = los[i];
      p.K[i] = Ks[i]; p.nshift[i] = nss[i]; p.base[i] = off;
      off += Ks[i] << nss[i];
    }
    p.base[10] = off;
    k_wtall<<<cdiv(off, 256), 256, 0, stream>>>(p);
  }

  k_gather<<<cdiv(NN * 128, 256), 256, 0, stream>>>(uidx, iidx, ue, ie, x0b);

  // Phase A — MLP (two 10000-row chunks)
  for (int ofs = 0; ofs < NN; ofs += 10000){
    mm(x0b + (size_t)ofs * 128, w1h, w1l, 128, nullptr, nullptr, nullptr, 0,
       b1, h1b, 10000, 1024, GF_BIAS | GF_RELU);
    mm(h1b, w2h, w2l, 1024, nullptr, nullptr, nullptr, 0,
       b2, h2b + (size_t)ofs * 512, 10000, 512, GF_BIAS | GF_RELU);
  }

  // Phase B — GCN1 (512->256) + BN + relu
  mm(h2b, wg1h, wg1l, 512, nullptr, nullptr, nullptr, 0, nullptr, xw1b, NN, 256, 0);
  k_agg<<<cdiv(NN * 256, 256), 256, 0, stream>>>(rowptr, colsrc, xw1b, dg, nullptr, bg1, g1f, nullptr, 8, 0);
  k_bn_stats<<<cdiv(NN, 128), 256, 0, stream>>>(g1f, stats1, 256);
  k_bn_apply<<<cdiv(NN * 256, 256), 256, 0, stream>>>(g1f, stats1, gamma1, beta1, 8, NN * 256, g1b);

  // Phase C — GCN2 (256->128) + BN + relu
  mm(g1b, wg2h, wg2l, 256, nullptr, nullptr, nullptr, 0, nullptr, xw2b, NN, 128, 0);
  k_agg<<<cdiv(NN * 128, 256), 256, 0, stream>>>(rowptr, colsrc, xw2b, dg, nullptr, bg2, x3f, nullptr, 7, 0);
  k_bn_stats<<<cdiv(NN, 128), 256, 0, stream>>>(x3f, stats2, 128);
  k_bn_apply<<<cdiv(NN * 128, 256), 256, 0, stream>>>(x3f, stats2, gamma2, beta2, 7, NN * 128, x3b);

  // Phase D — SAGE
  k_agg<<<cdiv(NN * 128, 256), 256, 0, stream>>>(rowptr, colsrc, x3b, nullptr, ic, nullptr, nullptr, aggb, 7, 1);
  mm(aggb, wslh, wsll, 128, x3b, wsrh, wsrl, 128, bsl, x4b, NN, 128, GF_BIAS | GF_RELU);

  // Phase E — Cheb
  k_agg<<<cdiv(NN * 128, 256), 256, 0, stream>>>(rowptr, colsrc, x4b, dc, nullptr, nullptr, nullptr, tx1b, 7, 2);
  mm(x4b, wc0h, wc0l, 128, tx1b, wc1h, wc1l, 128, bc, x5b, NN, 128, GF_BIAS | GF_RELU);

  // Phase F — GAT1
  mm(x5b, wgat1h, wgat1l, 128, nullptr, nullptr, nullptr, 0, nullptr, xpb, NN, 256, 0);
  k_gat_alar<<<cdiv(NN, 4), 256, 0, stream>>>(xpb, as1, ad1, al, ar);
  k_gat<<<NN, 64, 0, stream>>>(rowptr, colsrc, xpb, al, ar, bgat1, x6b,
                               nullptr, nullptr, nullptr);
  k_chk_bf<<<256, 256, 0, stream>>>((const unsigned short*)x6b, NN * 128, 16, diag);

  // Phase G — GAT2 (final projection fused -> fp32 out)
  mm(x6b, wgat2h, wgat2l, 128, nullptr, nullptr, nullptr, 0, nullptr, xpb, NN, 256, 0);
  k_gat_alar<<<cdiv(NN, 4), 256, 0, stream>>>(xpb, as2, ad2, al, ar);
  k_gat<<<NN, 64, 0, stream>>>(rowptr, colsrc, xpb, al, ar, bgat2, nullptr,
                               Wp, bp, (float*)d_out);
  k_diag_out<<<cdiv(NN, 256), 256, 0, stream>>>(diag, (float*)d_out);
}

// Round 12
// 635.483 us; speedup vs baseline: 6.2000x; 1.1503x over previous
//
#include <hip/hip_runtime.h>
#include <hip/hip_bf16.h>

typedef __hip_bfloat16 bf16;
typedef short s8v __attribute__((ext_vector_type(8)));
typedef float f4v __attribute__((ext_vector_type(4)));

#define NN 20000
#define NE 160000
#define BN_EPS 1e-5f
#define NB 79   // cdiv(NN,256)

#define GF_BIAS 1
#define GF_RELU 2

static __device__ __forceinline__ float b2f(const bf16 x){ return __bfloat162float(x); }
static __device__ __forceinline__ float bits2f(unsigned int u){ return __uint_as_float(u << 16); }
static __device__ __forceinline__ unsigned short f2bits(float f){
  bf16 h = __float2bfloat16(f);
  unsigned short u; __builtin_memcpy(&u, &h, 2); return u;
}
static __device__ __forceinline__ float lrelu(float v){ return (v > 0.f) ? v : 0.2f * v; }

static inline int cdiv(int a, int b){ return (a + b - 1) / b; }

// ---------------- diagnostics ----------------

__global__ void k_chk_bf(const unsigned short* __restrict__ x, int n, int code,
                         int* __restrict__ diag){
  bool bad = false;
  for (int k = blockIdx.x * 256 + threadIdx.x; k < n; k += gridDim.x * 256)
    if ((x[k] & 0x7F80u) == 0x7F80u) bad = true;
  if (bad) atomicCAS(diag, 0, code);
}

__global__ void k_diag_out(const int* __restrict__ diag, float* __restrict__ out){
  int d = *diag;
  if (d == 0) return;
  int i = blockIdx.x * 256 + threadIdx.x;
  if (i < NN) out[i] = (float)(d * 100);
}

// ---------------- CSR build (hierarchical, coalesced) ----------------

__global__ void k_ideg(const int* __restrict__ dst, int* __restrict__ ideg){
  int e = blockIdx.x * 256 + threadIdx.x;
  if (e < NE) atomicAdd(&ideg[dst[e]], 1);
}

__global__ __launch_bounds__(256) void k_scan1(const int* __restrict__ ideg,
                                               int* __restrict__ tmp,
                                               int* __restrict__ bsum){
  __shared__ int lds[256];
  int tid = threadIdx.x;
  int i = blockIdx.x * 256 + tid;
  int v = (i < NN) ? ideg[i] : 0;
  lds[tid] = v;
  __syncthreads();
  for (int off = 1; off < 256; off <<= 1){
    int t = (tid >= off) ? lds[tid - off] : 0;
    __syncthreads();
    lds[tid] += t;
    __syncthreads();
  }
  if (i < NN) tmp[i] = lds[tid];
  if (tid == 255) bsum[blockIdx.x] = lds[255];
}

__global__ __launch_bounds__(128) void k_scan2(const int* __restrict__ bsum,
                                               int* __restrict__ boff){
  __shared__ int lds[128];
  int tid = threadIdx.x;
  int v = (tid < NB) ? bsum[tid] : 0;
  lds[tid] = v;
  __syncthreads();
  for (int off = 1; off < 128; off <<= 1){
    int t = (tid >= off) ? lds[tid - off] : 0;
    __syncthreads();
    lds[tid] += t;
    __syncthreads();
  }
  if (tid < NB) boff[tid] = lds[tid] - v;
}

__global__ __launch_bounds__(256) void k_scan3(const int* __restrict__ ideg,
                                               const int* __restrict__ boff,
                                               int* __restrict__ rowptr,
                                               int* __restrict__ cursor,
                                               float* __restrict__ dg,
                                               float* __restrict__ dc,
                                               float* __restrict__ ic){
  int i = blockIdx.x * 256 + threadIdx.x;
  if (i == 0) rowptr[NN] = NE;
  if (i >= NN) return;
  int v = ideg[i];
  int excl = cursor[i] - v + boff[blockIdx.x];
  rowptr[i] = excl;
  cursor[i] = excl;
  float d = (float)v;
  dg[i] = rsqrtf(d + 1.0f);
  dc[i] = (d > 0.f) ? rsqrtf(d) : 0.f;
  ic[i] = 1.0f / fmaxf(d, 1.0f);
}

__global__ void k_fill(const int* __restrict__ src, const int* __restrict__ dst,
                       int* __restrict__ cursor, int* __restrict__ colsrc){
  int e = blockIdx.x * 256 + threadIdx.x;
  if (e >= NE) return;
  int pos = atomicAdd(&cursor[dst[e]], 1);
  colsrc[pos] = src[e];
}

// ---- batched weight prep ----

struct WtPack {
  const float* W[10]; short* hi[10]; short* lo[10];
  int K[10]; int nshift[10]; int base[11];
};

__global__ __launch_bounds__(256) void k_wtall(WtPack p){
  int idx = blockIdx.x * 256 + threadIdx.x;
  if (idx >= p.base[10]) return;
  int seg = 0;
#pragma unroll
  for (int i = 1; i < 10; i++) seg += (idx >= p.base[i]) ? 1 : 0;
  int local = idx - p.base[seg];
  int K = p.K[seg], ns = p.nshift[seg];
  int n = local & ((1 << ns) - 1), k = local >> ns;
  float w = p.W[seg][local];
  unsigned short h = f2bits(w);
  unsigned short l = f2bits(w - bits2f(h));
  p.hi[seg][(size_t)n * K + k] = (short)h;
  p.lo[seg][(size_t)n * K + k] = (short)l;
}

// ---------------- gather ----------------

__global__ void k_gather(const int* __restrict__ uidx, const int* __restrict__ iidx,
                         const float* __restrict__ ue, const float* __restrict__ ie,
                         bf16* __restrict__ x0){
  int idx = blockIdx.x * 256 + threadIdx.x;
  if (idx >= NN * 128) return;
  int i = idx >> 7, c = idx & 127;
  float v = (c < 64) ? ue[(size_t)uidx[i] * 64 + c] : ie[(size_t)iidx[i] * 64 + (c - 64)];
  x0[idx] = __float2bfloat16(v);
}

// ------- MFMA GEMM, 64x64 tile, hi/lo fused, XCD-aware block swizzle -------

__global__ __launch_bounds__(256) void k_mm64(
    const bf16* A0, const short* B0h, const short* B0l, int K0,
    const bf16* A1, const short* B1h, const short* B1l, int K1,
    const float* __restrict__ bias, bf16* __restrict__ C,
    int M, int Ncol, int flags, int npass){
  __shared__ short As[64][40];
  __shared__ short Bhs[64][40];
  __shared__ short Bls[64][40];
  const int tid = threadIdx.x;
  const int bid = blockIdx.y * gridDim.x + blockIdx.x;
  const int total = gridDim.x * gridDim.y;
  const int L = (bid & 7) * (total >> 3) + (bid >> 3);
  const int row0 = (L / gridDim.x) * 64, col0 = (L % gridDim.x) * 64;
  if (row0 >= M) return;
  const int wid = tid >> 6, lane = tid & 63;
  const int wr = (wid >> 1) * 32, wc = (wid & 1) * 32;
  const int lr = lane & 15, lq = lane >> 4;
  const int sr = tid >> 2, sq = (tid & 3) * 8;

  f4v acc[2][2];
#pragma unroll
  for (int i = 0; i < 2; i++)
#pragma unroll
    for (int j = 0; j < 2; j++)
      acc[i][j] = f4v{0.f, 0.f, 0.f, 0.f};

  const bf16* Aarr[2] = {A0, A1};
  const short* Bharr[2] = {B0h, B1h};
  const short* Blarr[2] = {B0l, B1l};
  const int Karr[2] = {K0, K1};

  for (int p = 0; p < npass; p++){
    const short* A = (const short*)Aarr[p];
    const short* Bh = Bharr[p];
    const short* Bl = Blarr[p];
    const int K = Karr[p];
    for (int k0 = 0; k0 < K; k0 += 32){
      uint4 va = make_uint4(0u, 0u, 0u, 0u);
      int grow = row0 + sr;
      if (grow < M) va = *(const uint4*)(A + (size_t)grow * K + k0 + sq);
      *(uint4*)&As[sr][sq] = va;
      size_t boff = (size_t)(col0 + sr) * K + k0 + sq;
      *(uint4*)&Bhs[sr][sq] = *(const uint4*)(Bh + boff);
      *(uint4*)&Bls[sr][sq] = *(const uint4*)(Bl + boff);
      __syncthreads();
      s8v a[2], bh[2], bl[2];
#pragma unroll
      for (int i = 0; i < 2; i++) a[i] = *(const s8v*)&As[wr + i * 16 + lr][lq * 8];
#pragma unroll
      for (int j = 0; j < 2; j++){
        bh[j] = *(const s8v*)&Bhs[wc + j * 16 + lr][lq * 8];
        bl[j] = *(const s8v*)&Bls[wc + j * 16 + lr][lq * 8];
      }
#pragma unroll
      for (int i = 0; i < 2; i++)
#pragma unroll
        for (int j = 0; j < 2; j++){
          acc[i][j] = __builtin_amdgcn_mfma_f32_16x16x32_bf16(a[i], bh[j], acc[i][j], 0, 0, 0);
          acc[i][j] = __builtin_amdgcn_mfma_f32_16x16x32_bf16(a[i], bl[j], acc[i][j], 0, 0, 0);
        }
      __syncthreads();
    }
  }

#pragma unroll
  for (int i = 0; i < 2; i++){
#pragma unroll
    for (int rg = 0; rg < 4; rg++){
      int row = row0 + wr + i * 16 + lq * 4 + rg;
      if (row >= M) continue;
#pragma unroll
      for (int j = 0; j < 2; j++){
        int col = col0 + wc + j * 16 + lr;
        float v = acc[i][j][rg];
        if (flags & GF_BIAS) v += bias[col];
        if (flags & GF_RELU) v = fmaxf(v, 0.f);
        C[(size_t)row * Ncol + col] = __float2bfloat16(v);
      }
    }
  }
}

// ------- CSR aggregation: 4 cols/thread, 4-edge batched (independent loads) -------
// F = 4<<qshift. mode 0 GCN -> outf f32; mode 1 SAGE, mode 2 Cheb -> outb bf16.

__global__ __launch_bounds__(256) void k_agg(
    const int* __restrict__ rowptr, const int* __restrict__ colsrc,
    const bf16* __restrict__ x, const float* __restrict__ wn,
    const float* __restrict__ icv, const float* __restrict__ bias,
    float* __restrict__ outf, bf16* __restrict__ outb,
    int qshift, int mode){
  int idx = blockIdx.x * 256 + threadIdx.x;
  int total = NN << qshift;
  if (idx >= total) return;
  int d = idx >> qshift, q = idx & ((1 << qshift) - 1);
  int F = 4 << qshift;
  int c = q * 4;
  int r0 = rowptr[d], r1 = rowptr[d + 1];
  float s0 = 0.f, s1 = 0.f, s2 = 0.f, s3 = 0.f;
  const short* xs = (const short*)x;
  for (int r = r0; r < r1; r += 4){
    int n = r1 - r;
    int i0 = colsrc[r];
    int i1 = (n > 1) ? colsrc[r + 1] : 0;
    int i2 = (n > 2) ? colsrc[r + 2] : 0;
    int i3 = (n > 3) ? colsrc[r + 3] : 0;
    float w0 = (mode == 1) ? 1.f : wn[i0];
    float w1 = (n > 1) ? ((mode == 1) ? 1.f : wn[i1]) : 0.f;
    float w2 = (n > 2) ? ((mode == 1) ? 1.f : wn[i2]) : 0.f;
    float w3 = (n > 3) ? ((mode == 1) ? 1.f : wn[i3]) : 0.f;
    uint2 v0 = *(const uint2*)(xs + (size_t)i0 * F + c);
    uint2 v1 = *(const uint2*)(xs + (size_t)i1 * F + c);
    uint2 v2 = *(const uint2*)(xs + (size_t)i2 * F + c);
    uint2 v3 = *(const uint2*)(xs + (size_t)i3 * F + c);
    s0 += w0 * bits2f(v0.x & 0xffffu) + w1 * bits2f(v1.x & 0xffffu)
        + w2 * bits2f(v2.x & 0xffffu) + w3 * bits2f(v3.x & 0xffffu);
    s1 += w0 * bits2f(v0.x >> 16) + w1 * bits2f(v1.x >> 16)
        + w2 * bits2f(v2.x >> 16) + w3 * bits2f(v3.x >> 16);
    s2 += w0 * bits2f(v0.y & 0xffffu) + w1 * bits2f(v1.y & 0xffffu)
        + w2 * bits2f(v2.y & 0xffffu) + w3 * bits2f(v3.y & 0xffffu);
    s3 += w0 * bits2f(v0.y >> 16) + w1 * bits2f(v1.y >> 16)
        + w2 * bits2f(v2.y >> 16) + w3 * bits2f(v3.y >> 16);
  }
  if (mode == 0){
    float w = wn[d], w2 = w * w;
    uint2 vd = *(const uint2*)(xs + (size_t)d * F + c);
    float4 o;
    o.x = w * s0 + w2 * bits2f(vd.x & 0xffffu) + bias[c + 0];
    o.y = w * s1 + w2 * bits2f(vd.x >> 16)     + bias[c + 1];
    o.z = w * s2 + w2 * bits2f(vd.y & 0xffffu) + bias[c + 2];
    o.w = w * s3 + w2 * bits2f(vd.y >> 16)     + bias[c + 3];
    *(float4*)(outf + (size_t)d * F + c) = o;
  } else {
    float m = (mode == 1) ? icv[d] : -wn[d];
    unsigned int lo = (unsigned int)f2bits(s0 * m) | ((unsigned int)f2bits(s1 * m) << 16);
    unsigned int hi = (unsigned int)f2bits(s2 * m) | ((unsigned int)f2bits(s3 * m) << 16);
    *(uint2*)((short*)outb + (size_t)d * F + c) = make_uint2(lo, hi);
  }
}

// ---------------- batchnorm ----------------

__global__ void k_bn_stats(const float* __restrict__ x, float* __restrict__ stats, int F){
  int c = threadIdx.x & (F - 1);
  int rsub = threadIdx.x / F;
  int rpi = 256 / F;
  int r0 = blockIdx.x * 128;
  int rend = min(NN, r0 + 128);
  float s1 = 0.f, s2 = 0.f;
  for (int r = r0 + rsub; r < rend; r += rpi){
    float v = x[(size_t)r * F + c];
    s1 += v; s2 += v * v;
  }
  atomicAdd(&stats[c], s1);
  atomicAdd(&stats[F + c], s2);
}

__global__ void k_bn_apply(const float* __restrict__ x, const float* __restrict__ stats,
                           const float* __restrict__ g, const float* __restrict__ b,
                           int fshift, int total, bf16* __restrict__ out){
  int idx = blockIdx.x * 256 + threadIdx.x;
  if (idx >= total) return;
  int F = 1 << fshift;
  int c = idx & (F - 1);
  float mu = stats[c] * (1.0f / NN);
  float var = fmaxf(stats[F + c] * (1.0f / NN) - mu * mu, 0.f);
  float v = (x[idx] - mu) * rsqrtf(var + BN_EPS) * g[c] + b[c];
  out[idx] = __float2bfloat16(fmaxf(v, 0.f));
}

// ---------------- GAT ----------------

__global__ __launch_bounds__(256) void k_gat_alar(const bf16* __restrict__ xp,
                                                  const float* __restrict__ as_,
                                                  const float* __restrict__ ad_,
                                                  float* __restrict__ al,
                                                  float* __restrict__ ar){
  int d = blockIdx.x * 4 + (threadIdx.x >> 6);
  int lane = threadIdx.x & 63;
  if (d >= NN) return;
  int c0 = lane * 2;
  unsigned int p0 = *(const unsigned int*)((const short*)xp + (size_t)d * 256 + c0);
  unsigned int p1 = *(const unsigned int*)((const short*)xp + (size_t)d * 256 + 128 + c0);
  float x00 = bits2f(p0 & 0xffffu), x01 = bits2f(p0 >> 16);
  float x10 = bits2f(p1 & 0xffffu), x11 = bits2f(p1 >> 16);
  float sa0 = x00 * as_[c0] + x01 * as_[c0 + 1];
  float sd0 = x00 * ad_[c0] + x01 * ad_[c0 + 1];
  float sa1 = x10 * as_[128 + c0] + x11 * as_[128 + c0 + 1];
  float sd1 = x10 * ad_[128 + c0] + x11 * ad_[128 + c0 + 1];
#pragma unroll
  for (int off = 32; off > 0; off >>= 1){
    sa0 += __shfl_xor(sa0, off); sd0 += __shfl_xor(sd0, off);
    sa1 += __shfl_xor(sa1, off); sd1 += __shfl_xor(sd1, off);
  }
  if (lane == 0){
    al[d * 2] = sa0;     ar[d * 2] = sd0;
    al[d * 2 + 1] = sa1; ar[d * 2 + 1] = sd1;
  }
}

__global__ __launch_bounds__(64) void k_gat(const int* __restrict__ rowptr,
                                            const int* __restrict__ colsrc,
                                            const bf16* __restrict__ xp,
                                            const float* __restrict__ al,
                                            const float* __restrict__ ar,
                                            const float* __restrict__ bias,
                                            bf16* __restrict__ outb,
                                            const float* __restrict__ wp,
                                            const float* __restrict__ bp,
                                            float* __restrict__ outf){
  __shared__ float w0s[64], w1s[64];
  __shared__ int ss[64];
  int d = blockIdx.x;
  int lane = threadIdx.x;
  int r0 = rowptr[d], r1 = rowptr[d + 1];
  float ard0 = ar[d * 2], ard1 = ar[d * 2 + 1];
  float e0 = lrelu(al[d * 2] + ard0);
  float e1 = lrelu(al[d * 2 + 1] + ard1);
  float mx0 = e0, mx1 = e1;
  for (int r = r0 + lane; r < r1; r += 64){
    int s = colsrc[r];
    mx0 = fmaxf(mx0, lrelu(al[s * 2] + ard0));
    mx1 = fmaxf(mx1, lrelu(al[s * 2 + 1] + ard1));
  }
#pragma unroll
  for (int off = 32; off > 0; off >>= 1){
    mx0 = fmaxf(mx0, __shfl_xor(mx0, off));
    mx1 = fmaxf(mx1, __shfl_xor(mx1, off));
  }
  float ps0 = (lane == 0) ? expf(e0 - mx0) : 0.f;
  float ps1 = (lane == 0) ? expf(e1 - mx1) : 0.f;
  for (int r = r0 + lane; r < r1; r += 64){
    int s = colsrc[r];
    ps0 += expf(lrelu(al[s * 2] + ard0) - mx0);
    ps1 += expf(lrelu(al[s * 2 + 1] + ard1) - mx1);
  }
#pragma unroll
  for (int off = 32; off > 0; off >>= 1){
    ps0 += __shfl_xor(ps0, off);
    ps1 += __shfl_xor(ps1, off);
  }
  int c0 = lane * 2;
  float a00, a01, a10, a11;
  {
    float w0 = expf(e0 - mx0), w1 = expf(e1 - mx1);
    unsigned int p0 = *(const unsigned int*)((const short*)xp + (size_t)d * 256 + c0);
    unsigned int p1 = *(const unsigned int*)((const short*)xp + (size_t)d * 256 + 128 + c0);
    a00 = w0 * bits2f(p0 & 0xffffu); a01 = w0 * bits2f(p0 >> 16);
    a10 = w1 * bits2f(p1 & 0xffffu); a11 = w1 * bits2f(p1 >> 16);
  }
  for (int t0 = r0; t0 < r1; t0 += 64){
    int nt = min(64, r1 - t0);
    __syncthreads();
    if (lane < nt){
      int s = colsrc[t0 + lane];
      ss[lane] = s;
      w0s[lane] = expf(lrelu(al[s * 2] + ard0) - mx0);
      w1s[lane] = expf(lrelu(al[s * 2 + 1] + ard1) - mx1);
    }
    __syncthreads();
    for (int r = 0; r < nt; r++){
      int s = ss[r];
      float w0 = w0s[r], w1 = w1s[r];
      unsigned int p0 = *(const unsigned int*)((const short*)xp + (size_t)s * 256 + c0);
      unsigned int p1 = *(const unsigned int*)((const short*)xp + (size_t)s * 256 + 128 + c0);
      a00 += w0 * bits2f(p0 & 0xffffu); a01 += w0 * bits2f(p0 >> 16);
      a10 += w1 * bits2f(p1 & 0xffffu); a11 += w1 * bits2f(p1 >> 16);
    }
  }
  float v0 = 0.5f * (a00 / ps0 + a10 / ps1) + bias[c0];
  float v1 = 0.5f * (a01 / ps0 + a11 / ps1) + bias[c0 + 1];
  v0 = (v0 > 0.f) ? v0 : expm1f(v0);
  v1 = (v1 > 0.f) ? v1 : expm1f(v1);
  if (wp == nullptr){
    unsigned int packed = (unsigned int)f2bits(v0) | ((unsigned int)f2bits(v1) << 16);
    *(unsigned int*)((short*)outb + (size_t)d * 128 + c0) = packed;
  } else {
    float pv = v0 * wp[c0] + v1 * wp[c0 + 1];
#pragma unroll
    for (int off = 32; off > 0; off >>= 1) pv += __shfl_down(pv, off);
    if (lane == 0) outf[d] = pv + bp[0];
  }
}

// ---------------- host ----------------

extern "C" void kernel_launch(void* const* d_in, const int* in_sizes, int n_in,
                              void* d_out, int out_size, void* d_ws, size_t ws_size,
                              hipStream_t stream){
  const int* uidx = (const int*)d_in[0];
  const int* iidx = (const int*)d_in[1];
  const int* eidx = (const int*)d_in[2];
  const int* src = eidx;
  const int* dst = eidx + NE;
  const float* ue  = (const float*)d_in[3];
  const float* ie  = (const float*)d_in[4];
  const float* W1  = (const float*)d_in[5];  const float* b1  = (const float*)d_in[6];
  const float* W2  = (const float*)d_in[7];  const float* b2  = (const float*)d_in[8];
  const float* Wg1 = (const float*)d_in[9];  const float* bg1 = (const float*)d_in[10];
  const float* gamma1 = (const float*)d_in[11]; const float* beta1 = (const float*)d_in[12];
  const float* Wg2 = (const float*)d_in[13]; const float* bg2 = (const float*)d_in[14];
  const float* gamma2 = (const float*)d_in[15]; const float* beta2 = (const float*)d_in[16];
  const float* Wsl = (const float*)d_in[17]; const float* bsl = (const float*)d_in[18];
  const float* Wsr = (const float*)d_in[19];
  const float* Wc0 = (const float*)d_in[20]; const float* Wc1 = (const float*)d_in[21];
  const float* bc  = (const float*)d_in[22];
  const float* Wgat1 = (const float*)d_in[23]; const float* as1 = (const float*)d_in[24];
  const float* ad1 = (const float*)d_in[25];   const float* bgat1 = (const float*)d_in[26];
  const float* Wgat2 = (const float*)d_in[27]; const float* as2 = (const float*)d_in[28];
  const float* ad2 = (const float*)d_in[29];   const float* bgat2 = (const float*)d_in[30];
  const float* Wp  = (const float*)d_in[31];   const float* bp  = (const float*)d_in[32];

  // ---- workspace (~51.3 MB) ----
  int* diag   = (int*)d_ws;
  int* ideg   = diag + 4;
  float* stats1 = (float*)(ideg + NN);
  float* stats2 = stats1 + 512;
  int* bsum   = (int*)(stats2 + 256);
  int* boff   = bsum + 128;
  int* rowptr = boff + 128;
  int* cursor = rowptr + NN + 4;
  int* colsrc = cursor + NN;
  float* dg = (float*)(colsrc + NE);
  float* dc = dg + NN;
  float* ic = dc + NN;
  float* al = ic + NN;
  float* ar = al + 2 * NN;
  short* w1h = (short*)(ar + 2 * NN);
  short* w1l = w1h + 131072;
  short* w2h = w1l + 131072;
  short* w2l = w2h + 524288;
  short* wg1h = w2l + 524288;
  short* wg1l = wg1h + 131072;
  short* wg2h = wg1l + 131072;
  short* wg2l = wg2h + 32768;
  short* wslh = wg2l + 32768;
  short* wsll = wslh + 16384;
  short* wsrh = wsll + 16384;
  short* wsrl = wsrh + 16384;
  short* wc0h = wsrl + 16384;
  short* wc0l = wc0h + 16384;
  short* wc1h = wc0l + 16384;
  short* wc1l = wc1h + 16384;
  short* wgat1h = wc1l + 16384;
  short* wgat1l = wgat1h + 32768;
  short* wgat2h = wgat1l + 32768;
  short* wgat2l = wgat2h + 32768;
  short* X0 = wgat2l + 32768;
  short* H1 = X0 + (size_t)NN * 128;
  short* H2 = H1 + (size_t)10000 * 1024;

  bf16* x0b  = (bf16*)X0;
  bf16* h1b  = (bf16*)H1;
  bf16* h2b  = (bf16*)H2;
  bf16* xw1b = (bf16*)H1;
  float* g1f = (float*)H2;
  bf16* g1b  = (bf16*)(H1 + (size_t)NN * 256);
  bf16* xw2b = (bf16*)X0;
  float* x3f = (float*)H1;
  bf16* x3b  = (bf16*)H2;
  bf16* aggb = (bf16*)X0;
  bf16* x4b  = (bf16*)(H2 + (size_t)NN * 128);
  bf16* tx1b = (bf16*)X0;
  bf16* x5b  = (bf16*)(H2 + (size_t)NN * 256);
  bf16* xpb  = (bf16*)H1;
  bf16* x6b  = (bf16*)X0;

  auto mm = [&](const bf16* A1, const short* B1h, const short* B1l, int K1,
                const bf16* A2, const short* B2h, const short* B2l, int K2,
                const float* bias, bf16* C, int M, int N, int flags){
    int nx = N / 64;
    int ny = cdiv(M, 64);
    while ((nx * ny) & 7) ny++;
    dim3 g(nx, ny);
    int np = A2 ? 2 : 1;
    k_mm64<<<g, 256, 0, stream>>>(A1, B1h, B1l, K1, A2, B2h, B2l, K2,
                                  bias, C, M, N, flags, np);
  };

  hipMemsetAsync(diag, 0, (size_t)(4 + NN + 768) * 4, stream);

  // CSR build + norms
  k_ideg<<<cdiv(NE, 256), 256, 0, stream>>>(dst, ideg);
  k_scan1<<<NB, 256, 0, stream>>>(ideg, cursor, bsum);
  k_scan2<<<1, 128, 0, stream>>>(bsum, boff);
  k_scan3<<<NB, 256, 0, stream>>>(ideg, boff, rowptr, cursor, dg, dc, ic);
  k_fill<<<cdiv(NE, 256), 256, 0, stream>>>(src, dst, cursor, colsrc);

  // batched weight prep
  {
    WtPack p;
    const float* Ws[10] = {W1, W2, Wg1, Wg2, Wsl, Wsr, Wc0, Wc1, Wgat1, Wgat2};
    short* his[10] = {w1h, w2h, wg1h, wg2h, wslh, wsrh, wc0h, wc1h, wgat1h, wgat2h};
    short* los[10] = {w1l, w2l, wg1l, wg2l, wsll, wsrl, wc0l, wc1l, wgat1l, wgat2l};
    int Ks[10] = {128, 1024, 512, 256, 128, 128, 128, 128, 128, 128};
    int nss[10] = {10, 9, 8, 7, 7, 7, 7, 7, 8, 8};
    int off = 0;
    for (int i = 0; i < 10; i++){
      p.W[i] = Ws[i]; p.hi[i] = his[i]; p.lo[i] = los[i];
      p.K[i] = Ks[i]; p.nshift[i] = nss[i]; p.base[i] = off;
      off += Ks[i] << nss[i];
    }
    p.base[10] = off;
    k_wtall<<<cdiv(off, 256), 256, 0, stream>>>(p);
  }

  k_gather<<<cdiv(NN * 128, 256), 256, 0, stream>>>(uidx, iidx, ue, ie, x0b);

  // Phase A — MLP (two 10000-row chunks)
  for (int ofs = 0; ofs < NN; ofs += 10000){
    mm(x0b + (size_t)ofs * 128, w1h, w1l, 128, nullptr, nullptr, nullptr, 0,
       b1, h1b, 10000, 1024, GF_BIAS | GF_RELU);
    mm(h1b, w2h, w2l, 1024, nullptr, nullptr, nullptr, 0,
       b2, h2b + (size_t)ofs * 512, 10000, 512, GF_BIAS | GF_RELU);
  }

  // Phase B — GCN1 (512->256) + BN + relu
  mm(h2b, wg1h, wg1l, 512, nullptr, nullptr, nullptr, 0, nullptr, xw1b, NN, 256, 0);
  k_agg<<<cdiv(NN * 64, 256), 256, 0, stream>>>(rowptr, colsrc, xw1b, dg, nullptr, bg1, g1f, nullptr, 6, 0);
  k_bn_stats<<<cdiv(NN, 128), 256, 0, stream>>>(g1f, stats1, 256);
  k_bn_apply<<<cdiv(NN * 256, 256), 256, 0, stream>>>(g1f, stats1, gamma1, beta1, 8, NN * 256, g1b);

  // Phase C — GCN2 (256->128) + BN + relu
  mm(g1b, wg2h, wg2l, 256, nullptr, nullptr, nullptr, 0, nullptr, xw2b, NN, 128, 0);
  k_agg<<<cdiv(NN * 32, 256), 256, 0, stream>>>(rowptr, colsrc, xw2b, dg, nullptr, bg2, x3f, nullptr, 5, 0);
  k_bn_stats<<<cdiv(NN, 128), 256, 0, stream>>>(x3f, stats2, 128);
  k_bn_apply<<<cdiv(NN * 128, 256), 256, 0, stream>>>(x3f, stats2, gamma2, beta2, 7, NN * 128, x3b);

  // Phase D — SAGE
  k_agg<<<cdiv(NN * 32, 256), 256, 0, stream>>>(rowptr, colsrc, x3b, nullptr, ic, nullptr, nullptr, aggb, 5, 1);
  mm(aggb, wslh, wsll, 128, x3b, wsrh, wsrl, 128, bsl, x4b, NN, 128, GF_BIAS | GF_RELU);

  // Phase E — Cheb
  k_agg<<<cdiv(NN * 32, 256), 256, 0, stream>>>(rowptr, colsrc, x4b, dc, nullptr, nullptr, nullptr, tx1b, 5, 2);
  mm(x4b, wc0h, wc0l, 128, tx1b, wc1h, wc1l, 128, bc, x5b, NN, 128, GF_BIAS | GF_RELU);

  // Phase F — GAT1
  mm(x5b, wgat1h, wgat1l, 128, nullptr, nullptr, nullptr, 0, nullptr, xpb, NN, 256, 0);
  k_gat_alar<<<cdiv(NN, 4), 256, 0, stream>>>(xpb, as1, ad1, al, ar);
  k_gat<<<NN, 64, 0, stream>>>(rowptr, colsrc, xpb, al, ar, bgat1, x6b,
                               nullptr, nullptr, nullptr);
  k_chk_bf<<<256, 256, 0, stream>>>((const unsigned short*)x6b, NN * 128, 16, diag);

  // Phase G — GAT2 (final projection fused -> fp32 out)
  mm(x6b, wgat2h, wgat2l, 128, nullptr, nullptr, nullptr, 0, nullptr, xpb, NN, 256, 0);
  k_gat_alar<<<cdiv(NN, 4), 256, 0, stream>>>(xpb, as2, ad2, al, ar);
  k_gat<<<NN, 64, 0, stream>>>(rowptr, colsrc, xpb, al, ar, bgat2, nullptr,
                               Wp, bp, (float*)d_out);
  k_diag_out<<<cdiv(NN, 256), 256, 0, stream>>>(diag, (float*)d_out);
}

// Round 13
// 617.125 us; speedup vs baseline: 6.3844x; 1.0297x over previous
//
#include <hip/hip_runtime.h>
#include <hip/hip_bf16.h>

typedef __hip_bfloat16 bf16;
typedef short s8v __attribute__((ext_vector_type(8)));
typedef float f4v __attribute__((ext_vector_type(4)));

#define NN 20000
#define NE 160000
#define BN_EPS 1e-5f
#define NB 79   // cdiv(NN,256)

#define GF_BIAS 1
#define GF_RELU 2

static __device__ __forceinline__ float b2f(const bf16 x){ return __bfloat162float(x); }
static __device__ __forceinline__ float bits2f(unsigned int u){ return __uint_as_float(u << 16); }
static __device__ __forceinline__ unsigned short f2bits(float f){
  bf16 h = __float2bfloat16(f);
  unsigned short u; __builtin_memcpy(&u, &h, 2); return u;
}
static __device__ __forceinline__ float lrelu(float v){ return (v > 0.f) ? v : 0.2f * v; }

static inline int cdiv(int a, int b){ return (a + b - 1) / b; }

// ---------------- diagnostics ----------------

__global__ void k_chk_bf(const unsigned short* __restrict__ x, int n, int code,
                         int* __restrict__ diag){
  bool bad = false;
  for (int k = blockIdx.x * 256 + threadIdx.x; k < n; k += gridDim.x * 256)
    if ((x[k] & 0x7F80u) == 0x7F80u) bad = true;
  if (bad) atomicCAS(diag, 0, code);
}

__global__ void k_diag_out(const int* __restrict__ diag, float* __restrict__ out){
  int d = *diag;
  if (d == 0) return;
  int i = blockIdx.x * 256 + threadIdx.x;
  if (i < NN) out[i] = (float)(d * 100);
}

// ---------------- CSR build (hierarchical, coalesced) ----------------

__global__ void k_ideg(const int* __restrict__ dst, int* __restrict__ ideg){
  int e = blockIdx.x * 256 + threadIdx.x;
  if (e < NE) atomicAdd(&ideg[dst[e]], 1);
}

__global__ __launch_bounds__(256) void k_scan1(const int* __restrict__ ideg,
                                               int* __restrict__ tmp,
                                               int* __restrict__ bsum){
  __shared__ int lds[256];
  int tid = threadIdx.x;
  int i = blockIdx.x * 256 + tid;
  int v = (i < NN) ? ideg[i] : 0;
  lds[tid] = v;
  __syncthreads();
  for (int off = 1; off < 256; off <<= 1){
    int t = (tid >= off) ? lds[tid - off] : 0;
    __syncthreads();
    lds[tid] += t;
    __syncthreads();
  }
  if (i < NN) tmp[i] = lds[tid];
  if (tid == 255) bsum[blockIdx.x] = lds[255];
}

__global__ __launch_bounds__(128) void k_scan2(const int* __restrict__ bsum,
                                               int* __restrict__ boff){
  __shared__ int lds[128];
  int tid = threadIdx.x;
  int v = (tid < NB) ? bsum[tid] : 0;
  lds[tid] = v;
  __syncthreads();
  for (int off = 1; off < 128; off <<= 1){
    int t = (tid >= off) ? lds[tid - off] : 0;
    __syncthreads();
    lds[tid] += t;
    __syncthreads();
  }
  if (tid < NB) boff[tid] = lds[tid] - v;
}

__global__ __launch_bounds__(256) void k_scan3(const int* __restrict__ ideg,
                                               const int* __restrict__ boff,
                                               int* __restrict__ rowptr,
                                               int* __restrict__ cursor,
                                               float* __restrict__ dg,
                                               float* __restrict__ dc,
                                               float* __restrict__ ic){
  int i = blockIdx.x * 256 + threadIdx.x;
  if (i == 0) rowptr[NN] = NE;
  if (i >= NN) return;
  int v = ideg[i];
  int excl = cursor[i] - v + boff[blockIdx.x];
  rowptr[i] = excl;
  cursor[i] = excl;
  float d = (float)v;
  dg[i] = rsqrtf(d + 1.0f);
  dc[i] = (d > 0.f) ? rsqrtf(d) : 0.f;
  ic[i] = 1.0f / fmaxf(d, 1.0f);
}

__global__ void k_fill(const int* __restrict__ src, const int* __restrict__ dst,
                       int* __restrict__ cursor, int* __restrict__ colsrc){
  int e = blockIdx.x * 256 + threadIdx.x;
  if (e >= NE) return;
  int pos = atomicAdd(&cursor[dst[e]], 1);
  colsrc[pos] = src[e];
}

// ---- batched weight prep ----

struct WtPack {
  const float* W[10]; short* hi[10]; short* lo[10];
  int K[10]; int nshift[10]; int base[11];
};

__global__ __launch_bounds__(256) void k_wtall(WtPack p){
  int idx = blockIdx.x * 256 + threadIdx.x;
  if (idx >= p.base[10]) return;
  int seg = 0;
#pragma unroll
  for (int i = 1; i < 10; i++) seg += (idx >= p.base[i]) ? 1 : 0;
  int local = idx - p.base[seg];
  int K = p.K[seg], ns = p.nshift[seg];
  int n = local & ((1 << ns) - 1), k = local >> ns;
  float w = p.W[seg][local];
  unsigned short h = f2bits(w);
  unsigned short l = f2bits(w - bits2f(h));
  p.hi[seg][(size_t)n * K + k] = (short)h;
  p.lo[seg][(size_t)n * K + k] = (short)l;
}

// ---------------- gather ----------------

__global__ void k_gather(const int* __restrict__ uidx, const int* __restrict__ iidx,
                         const float* __restrict__ ue, const float* __restrict__ ie,
                         bf16* __restrict__ x0){
  int idx = blockIdx.x * 256 + threadIdx.x;
  if (idx >= NN * 128) return;
  int i = idx >> 7, c = idx & 127;
  float v = (c < 64) ? ue[(size_t)uidx[i] * 64 + c] : ie[(size_t)iidx[i] * 64 + (c - 64)];
  x0[idx] = __float2bfloat16(v);
}

// ------- MFMA GEMM, 64x64 tile, hi/lo fused, XCD swizzle, K=64/iter + reg prefetch -------
// All K must be multiples of 64 (true here: 128/256/512/1024).

__global__ __launch_bounds__(256) void k_mm64(
    const bf16* A0, const short* B0h, const short* B0l, int K0,
    const bf16* A1, const short* B1h, const short* B1l, int K1,
    const float* __restrict__ bias, bf16* __restrict__ C,
    int M, int Ncol, int flags, int npass){
  __shared__ short As[64][72];    // 64 K-shorts + 8 pad (16B-aligned rows)
  __shared__ short Bhs[64][72];
  __shared__ short Bls[64][72];
  const int tid = threadIdx.x;
  const int bid = blockIdx.y * gridDim.x + blockIdx.x;
  const int total = gridDim.x * gridDim.y;
  const int L = (bid & 7) * (total >> 3) + (bid >> 3);
  const int row0 = (L / gridDim.x) * 64, col0 = (L % gridDim.x) * 64;
  if (row0 >= M) return;
  const int wid = tid >> 6, lane = tid & 63;
  const int wr = (wid >> 1) * 32, wc = (wid & 1) * 32;
  const int lr = lane & 15, lq = lane >> 4;
  const int sr = tid >> 2, sq = (tid & 3) * 16;  // staging: row sr, 16 shorts from sq

  f4v acc[2][2];
#pragma unroll
  for (int i = 0; i < 2; i++)
#pragma unroll
    for (int j = 0; j < 2; j++)
      acc[i][j] = f4v{0.f, 0.f, 0.f, 0.f};

  const bf16* Aarr[2] = {A0, A1};
  const short* Bharr[2] = {B0h, B1h};
  const short* Blarr[2] = {B0l, B1l};
  const int Karr[2] = {K0, K1};

  const bool arow_ok = (row0 + sr) < M;

  for (int p = 0; p < npass; p++){
    const short* A = (const short*)Aarr[p];
    const short* Bh = Bharr[p];
    const short* Bl = Blarr[p];
    const int K = Karr[p];
    const short* arow = A + (size_t)(row0 + sr) * K + sq;
    const short* bhrow = Bh + (size_t)(col0 + sr) * K + sq;
    const short* blrow = Bl + (size_t)(col0 + sr) * K + sq;

    // prologue: load tile k0=0 into registers
    uint4 ra0 = make_uint4(0,0,0,0), ra1 = make_uint4(0,0,0,0);
    if (arow_ok){ ra0 = *(const uint4*)(arow); ra1 = *(const uint4*)(arow + 8); }
    uint4 rb0 = *(const uint4*)(bhrow), rb1 = *(const uint4*)(bhrow + 8);
    uint4 rc0 = *(const uint4*)(blrow), rc1 = *(const uint4*)(blrow + 8);

    for (int k0 = 0; k0 < K; k0 += 64){
      // commit staged registers to LDS
      *(uint4*)&As[sr][sq] = ra0;  *(uint4*)&As[sr][sq + 8] = ra1;
      *(uint4*)&Bhs[sr][sq] = rb0; *(uint4*)&Bhs[sr][sq + 8] = rb1;
      *(uint4*)&Bls[sr][sq] = rc0; *(uint4*)&Bls[sr][sq + 8] = rc1;
      __syncthreads();
      // prefetch next tile while this one computes (overlaps global latency)
      if (k0 + 64 < K){
        int off = k0 + 64;
        if (arow_ok){ ra0 = *(const uint4*)(arow + off); ra1 = *(const uint4*)(arow + off + 8); }
        rb0 = *(const uint4*)(bhrow + off); rb1 = *(const uint4*)(bhrow + off + 8);
        rc0 = *(const uint4*)(blrow + off); rc1 = *(const uint4*)(blrow + off + 8);
      }
#pragma unroll
      for (int t = 0; t < 2; t++){
        s8v a[2], bh2[2], bl2[2];
#pragma unroll
        for (int i = 0; i < 2; i++) a[i] = *(const s8v*)&As[wr + i * 16 + lr][t * 32 + lq * 8];
#pragma unroll
        for (int j = 0; j < 2; j++){
          bh2[j] = *(const s8v*)&Bhs[wc + j * 16 + lr][t * 32 + lq * 8];
          bl2[j] = *(const s8v*)&Bls[wc + j * 16 + lr][t * 32 + lq * 8];
        }
#pragma unroll
        for (int i = 0; i < 2; i++)
#pragma unroll
          for (int j = 0; j < 2; j++){
            acc[i][j] = __builtin_amdgcn_mfma_f32_16x16x32_bf16(a[i], bh2[j], acc[i][j], 0, 0, 0);
            acc[i][j] = __builtin_amdgcn_mfma_f32_16x16x32_bf16(a[i], bl2[j], acc[i][j], 0, 0, 0);
          }
      }
      __syncthreads();
    }
  }

#pragma unroll
  for (int i = 0; i < 2; i++){
#pragma unroll
    for (int rg = 0; rg < 4; rg++){
      int row = row0 + wr + i * 16 + lq * 4 + rg;
      if (row >= M) continue;
#pragma unroll
      for (int j = 0; j < 2; j++){
        int col = col0 + wc + j * 16 + lr;
        float v = acc[i][j][rg];
        if (flags & GF_BIAS) v += bias[col];
        if (flags & GF_RELU) v = fmaxf(v, 0.f);
        C[(size_t)row * Ncol + col] = __float2bfloat16(v);
      }
    }
  }
}

// ------- CSR aggregation: 4 cols/thread, 4-edge batched -------

__global__ __launch_bounds__(256) void k_agg(
    const int* __restrict__ rowptr, const int* __restrict__ colsrc,
    const bf16* __restrict__ x, const float* __restrict__ wn,
    const float* __restrict__ icv, const float* __restrict__ bias,
    float* __restrict__ outf, bf16* __restrict__ outb,
    int qshift, int mode){
  int idx = blockIdx.x * 256 + threadIdx.x;
  int total = NN << qshift;
  if (idx >= total) return;
  int d = idx >> qshift, q = idx & ((1 << qshift) - 1);
  int F = 4 << qshift;
  int c = q * 4;
  int r0 = rowptr[d], r1 = rowptr[d + 1];
  float s0 = 0.f, s1 = 0.f, s2 = 0.f, s3 = 0.f;
  const short* xs = (const short*)x;
  for (int r = r0; r < r1; r += 4){
    int n = r1 - r;
    int i0 = colsrc[r];
    int i1 = (n > 1) ? colsrc[r + 1] : 0;
    int i2 = (n > 2) ? colsrc[r + 2] : 0;
    int i3 = (n > 3) ? colsrc[r + 3] : 0;
    float w0 = (mode == 1) ? 1.f : wn[i0];
    float w1 = (n > 1) ? ((mode == 1) ? 1.f : wn[i1]) : 0.f;
    float w2 = (n > 2) ? ((mode == 1) ? 1.f : wn[i2]) : 0.f;
    float w3 = (n > 3) ? ((mode == 1) ? 1.f : wn[i3]) : 0.f;
    uint2 v0 = *(const uint2*)(xs + (size_t)i0 * F + c);
    uint2 v1 = *(const uint2*)(xs + (size_t)i1 * F + c);
    uint2 v2 = *(const uint2*)(xs + (size_t)i2 * F + c);
    uint2 v3 = *(const uint2*)(xs + (size_t)i3 * F + c);
    s0 += w0 * bits2f(v0.x & 0xffffu) + w1 * bits2f(v1.x & 0xffffu)
        + w2 * bits2f(v2.x & 0xffffu) + w3 * bits2f(v3.x & 0xffffu);
    s1 += w0 * bits2f(v0.x >> 16) + w1 * bits2f(v1.x >> 16)
        + w2 * bits2f(v2.x >> 16) + w3 * bits2f(v3.x >> 16);
    s2 += w0 * bits2f(v0.y & 0xffffu) + w1 * bits2f(v1.y & 0xffffu)
        + w2 * bits2f(v2.y & 0xffffu) + w3 * bits2f(v3.y & 0xffffu);
    s3 += w0 * bits2f(v0.y >> 16) + w1 * bits2f(v1.y >> 16)
        + w2 * bits2f(v2.y >> 16) + w3 * bits2f(v3.y >> 16);
  }
  if (mode == 0){
    float w = wn[d], w2 = w * w;
    uint2 vd = *(const uint2*)(xs + (size_t)d * F + c);
    float4 o;
    o.x = w * s0 + w2 * bits2f(vd.x & 0xffffu) + bias[c + 0];
    o.y = w * s1 + w2 * bits2f(vd.x >> 16)     + bias[c + 1];
    o.z = w * s2 + w2 * bits2f(vd.y & 0xffffu) + bias[c + 2];
    o.w = w * s3 + w2 * bits2f(vd.y >> 16)     + bias[c + 3];
    *(float4*)(outf + (size_t)d * F + c) = o;
  } else {
    float m = (mode == 1) ? icv[d] : -wn[d];
    unsigned int lo = (unsigned int)f2bits(s0 * m) | ((unsigned int)f2bits(s1 * m) << 16);
    unsigned int hi = (unsigned int)f2bits(s2 * m) | ((unsigned int)f2bits(s3 * m) << 16);
    *(uint2*)((short*)outb + (size_t)d * F + c) = make_uint2(lo, hi);
  }
}

// ---------------- batchnorm ----------------

__global__ void k_bn_stats(const float* __restrict__ x, float* __restrict__ stats, int F){
  int c = threadIdx.x & (F - 1);
  int rsub = threadIdx.x / F;
  int rpi = 256 / F;
  int r0 = blockIdx.x * 128;
  int rend = min(NN, r0 + 128);
  float s1 = 0.f, s2 = 0.f;
  for (int r = r0 + rsub; r < rend; r += rpi){
    float v = x[(size_t)r * F + c];
    s1 += v; s2 += v * v;
  }
  atomicAdd(&stats[c], s1);
  atomicAdd(&stats[F + c], s2);
}

__global__ void k_bn_apply(const float* __restrict__ x, const float* __restrict__ stats,
                           const float* __restrict__ g, const float* __restrict__ b,
                           int fshift, int total, bf16* __restrict__ out){
  int idx = blockIdx.x * 256 + threadIdx.x;
  if (idx >= total) return;
  int F = 1 << fshift;
  int c = idx & (F - 1);
  float mu = stats[c] * (1.0f / NN);
  float var = fmaxf(stats[F + c] * (1.0f / NN) - mu * mu, 0.f);
  float v = (x[idx] - mu) * rsqrtf(var + BN_EPS) * g[c] + b[c];
  out[idx] = __float2bfloat16(fmaxf(v, 0.f));
}

// ---------------- GAT ----------------

__global__ __launch_bounds__(256) void k_gat_alar(const bf16* __restrict__ xp,
                                                  const float* __restrict__ as_,
                                                  const float* __restrict__ ad_,
                                                  float* __restrict__ al,
                                                  float* __restrict__ ar){
  int d = blockIdx.x * 4 + (threadIdx.x >> 6);
  int lane = threadIdx.x & 63;
  if (d >= NN) return;
  int c0 = lane * 2;
  unsigned int p0 = *(const unsigned int*)((const short*)xp + (size_t)d * 256 + c0);
  unsigned int p1 = *(const unsigned int*)((const short*)xp + (size_t)d * 256 + 128 + c0);
  float x00 = bits2f(p0 & 0xffffu), x01 = bits2f(p0 >> 16);
  float x10 = bits2f(p1 & 0xffffu), x11 = bits2f(p1 >> 16);
  float sa0 = x00 * as_[c0] + x01 * as_[c0 + 1];
  float sd0 = x00 * ad_[c0] + x01 * ad_[c0 + 1];
  float sa1 = x10 * as_[128 + c0] + x11 * as_[128 + c0 + 1];
  float sd1 = x10 * ad_[128 + c0] + x11 * ad_[128 + c0 + 1];
#pragma unroll
  for (int off = 32; off > 0; off >>= 1){
    sa0 += __shfl_xor(sa0, off); sd0 += __shfl_xor(sd0, off);
    sa1 += __shfl_xor(sa1, off); sd1 += __shfl_xor(sd1, off);
  }
  if (lane == 0){
    al[d * 2] = sa0;     ar[d * 2] = sd0;
    al[d * 2 + 1] = sa1; ar[d * 2 + 1] = sd1;
  }
}

__global__ __launch_bounds__(64) void k_gat(const int* __restrict__ rowptr,
                                            const int* __restrict__ colsrc,
                                            const bf16* __restrict__ xp,
                                            const float* __restrict__ al,
                                            const float* __restrict__ ar,
                                            const float* __restrict__ bias,
                                            bf16* __restrict__ outb,
                                            const float* __restrict__ wp,
                                            const float* __restrict__ bp,
                                            float* __restrict__ outf){
  __shared__ float w0s[64], w1s[64];
  __shared__ int ss[64];
  int d = blockIdx.x;
  int lane = threadIdx.x;
  int r0 = rowptr[d], r1 = rowptr[d + 1];
  float ard0 = ar[d * 2], ard1 = ar[d * 2 + 1];
  float e0 = lrelu(al[d * 2] + ard0);
  float e1 = lrelu(al[d * 2 + 1] + ard1);
  float mx0 = e0, mx1 = e1;
  for (int r = r0 + lane; r < r1; r += 64){
    int s = colsrc[r];
    mx0 = fmaxf(mx0, lrelu(al[s * 2] + ard0));
    mx1 = fmaxf(mx1, lrelu(al[s * 2 + 1] + ard1));
  }
#pragma unroll
  for (int off = 32; off > 0; off >>= 1){
    mx0 = fmaxf(mx0, __shfl_xor(mx0, off));
    mx1 = fmaxf(mx1, __shfl_xor(mx1, off));
  }
  float ps0 = (lane == 0) ? expf(e0 - mx0) : 0.f;
  float ps1 = (lane == 0) ? expf(e1 - mx1) : 0.f;
  for (int r = r0 + lane; r < r1; r += 64){
    int s = colsrc[r];
    ps0 += expf(lrelu(al[s * 2] + ard0) - mx0);
    ps1 += expf(lrelu(al[s * 2 + 1] + ard1) - mx1);
  }
#pragma unroll
  for (int off = 32; off > 0; off >>= 1){
    ps0 += __shfl_xor(ps0, off);
    ps1 += __shfl_xor(ps1, off);
  }
  int c0 = lane * 2;
  float a00, a01, a10, a11;
  {
    float w0 = expf(e0 - mx0), w1 = expf(e1 - mx1);
    unsigned int p0 = *(const unsigned int*)((const short*)xp + (size_t)d * 256 + c0);
    unsigned int p1 = *(const unsigned int*)((const short*)xp + (size_t)d * 256 + 128 + c0);
    a00 = w0 * bits2f(p0 & 0xffffu); a01 = w0 * bits2f(p0 >> 16);
    a10 = w1 * bits2f(p1 & 0xffffu); a11 = w1 * bits2f(p1 >> 16);
  }
  for (int t0 = r0; t0 < r1; t0 += 64){
    int nt = min(64, r1 - t0);
    __syncthreads();
    if (lane < nt){
      int s = colsrc[t0 + lane];
      ss[lane] = s;
      w0s[lane] = expf(lrelu(al[s * 2] + ard0) - mx0);
      w1s[lane] = expf(lrelu(al[s * 2 + 1] + ard1) - mx1);
    }
    __syncthreads();
    for (int r = 0; r < nt; r++){
      int s = ss[r];
      float w0 = w0s[r], w1 = w1s[r];
      unsigned int p0 = *(const unsigned int*)((const short*)xp + (size_t)s * 256 + c0);
      unsigned int p1 = *(const unsigned int*)((const short*)xp + (size_t)s * 256 + 128 + c0);
      a00 += w0 * bits2f(p0 & 0xffffu); a01 += w0 * bits2f(p0 >> 16);
      a10 += w1 * bits2f(p1 & 0xffffu); a11 += w1 * bits2f(p1 >> 16);
    }
  }
  float v0 = 0.5f * (a00 / ps0 + a10 / ps1) + bias[c0];
  float v1 = 0.5f * (a01 / ps0 + a11 / ps1) + bias[c0 + 1];
  v0 = (v0 > 0.f) ? v0 : expm1f(v0);
  v1 = (v1 > 0.f) ? v1 : expm1f(v1);
  if (wp == nullptr){
    unsigned int packed = (unsigned int)f2bits(v0) | ((unsigned int)f2bits(v1) << 16);
    *(unsigned int*)((short*)outb + (size_t)d * 128 + c0) = packed;
  } else {
    float pv = v0 * wp[c0] + v1 * wp[c0 + 1];
#pragma unroll
    for (int off = 32; off > 0; off >>= 1) pv += __shfl_down(pv, off);
    if (lane == 0) outf[d] = pv + bp[0];
  }
}

// ---------------- host ----------------

extern "C" void kernel_launch(void* const* d_in, const int* in_sizes, int n_in,
                              void* d_out, int out_size, void* d_ws, size_t ws_size,
                              hipStream_t stream){
  const int* uidx = (const int*)d_in[0];
  const int* iidx = (const int*)d_in[1];
  const int* eidx = (const int*)d_in[2];
  const int* src = eidx;
  const int* dst = eidx + NE;
  const float* ue  = (const float*)d_in[3];
  const float* ie  = (const float*)d_in[4];
  const float* W1  = (const float*)d_in[5];  const float* b1  = (const float*)d_in[6];
  const float* W2  = (const float*)d_in[7];  const float* b2  = (const float*)d_in[8];
  const float* Wg1 = (const float*)d_in[9];  const float* bg1 = (const float*)d_in[10];
  const float* gamma1 = (const float*)d_in[11]; const float* beta1 = (const float*)d_in[12];
  const float* Wg2 = (const float*)d_in[13]; const float* bg2 = (const float*)d_in[14];
  const float* gamma2 = (const float*)d_in[15]; const float* beta2 = (const float*)d_in[16];
  const float* Wsl = (const float*)d_in[17]; const float* bsl = (const float*)d_in[18];
  const float* Wsr = (const float*)d_in[19];
  const float* Wc0 = (const float*)d_in[20]; const float* Wc1 = (const float*)d_in[21];
  const float* bc  = (const float*)d_in[22];
  const float* Wgat1 = (const float*)d_in[23]; const float* as1 = (const float*)d_in[24];
  const float* ad1 = (const float*)d_in[25];   const float* bgat1 = (const float*)d_in[26];
  const float* Wgat2 = (const float*)d_in[27]; const float* as2 = (const float*)d_in[28];
  const float* ad2 = (const float*)d_in[29];   const float* bgat2 = (const float*)d_in[30];
  const float* Wp  = (const float*)d_in[31];   const float* bp  = (const float*)d_in[32];

  // ---- workspace (~51.3 MB) ----
  int* diag   = (int*)d_ws;
  int* ideg   = diag + 4;
  float* stats1 = (float*)(ideg + NN);
  float* stats2 = stats1 + 512;
  int* bsum   = (int*)(stats2 + 256);
  int* boff   = bsum + 128;
  int* rowptr = boff + 128;
  int* cursor = rowptr + NN + 4;
  int* colsrc = cursor + NN;
  float* dg = (float*)(colsrc + NE);
  float* dc = dg + NN;
  float* ic = dc + NN;
  float* al = ic + NN;
  float* ar = al + 2 * NN;
  short* w1h = (short*)(ar + 2 * NN);
  short* w1l = w1h + 131072;
  short* w2h = w1l + 131072;
  short* w2l = w2h + 524288;
  short* wg1h = w2l + 524288;
  short* wg1l = wg1h + 131072;
  short* wg2h = wg1l + 131072;
  short* wg2l = wg2h + 32768;
  short* wslh = wg2l + 32768;
  short* wsll = wslh + 16384;
  short* wsrh = wsll + 16384;
  short* wsrl = wsrh + 16384;
  short* wc0h = wsrl + 16384;
  short* wc0l = wc0h + 16384;
  short* wc1h = wc0l + 16384;
  short* wc1l = wc1h + 16384;
  short* wgat1h = wc1l + 16384;
  short* wgat1l = wgat1h + 32768;
  short* wgat2h = wgat1l + 32768;
  short* wgat2l = wgat2h + 32768;
  short* X0 = wgat2l + 32768;
  short* H1 = X0 + (size_t)NN * 128;
  short* H2 = H1 + (size_t)10000 * 1024;

  bf16* x0b  = (bf16*)X0;
  bf16* h1b  = (bf16*)H1;
  bf16* h2b  = (bf16*)H2;
  bf16* xw1b = (bf16*)H1;
  float* g1f = (float*)H2;
  bf16* g1b  = (bf16*)(H1 + (size_t)NN * 256);
  bf16* xw2b = (bf16*)X0;
  float* x3f = (float*)H1;
  bf16* x3b  = (bf16*)H2;
  bf16* aggb = (bf16*)X0;
  bf16* x4b  = (bf16*)(H2 + (size_t)NN * 128);
  bf16* tx1b = (bf16*)X0;
  bf16* x5b  = (bf16*)(H2 + (size_t)NN * 256);
  bf16* xpb  = (bf16*)H1;
  bf16* x6b  = (bf16*)X0;

  auto mm = [&](const bf16* A1, const short* B1h, const short* B1l, int K1,
                const bf16* A2, const short* B2h, const short* B2l, int K2,
                const float* bias, bf16* C, int M, int N, int flags){
    int nx = N / 64;
    int ny = cdiv(M, 64);
    while ((nx * ny) & 7) ny++;
    dim3 g(nx, ny);
    int np = A2 ? 2 : 1;
    k_mm64<<<g, 256, 0, stream>>>(A1, B1h, B1l, K1, A2, B2h, B2l, K2,
                                  bias, C, M, N, flags, np);
  };

  hipMemsetAsync(diag, 0, (size_t)(4 + NN + 768) * 4, stream);

  // CSR build + norms
  k_ideg<<<cdiv(NE, 256), 256, 0, stream>>>(dst, ideg);
  k_scan1<<<NB, 256, 0, stream>>>(ideg, cursor, bsum);
  k_scan2<<<1, 128, 0, stream>>>(bsum, boff);
  k_scan3<<<NB, 256, 0, stream>>>(ideg, boff, rowptr, cursor, dg, dc, ic);
  k_fill<<<cdiv(NE, 256), 256, 0, stream>>>(src, dst, cursor, colsrc);

  // batched weight prep
  {
    WtPack p;
    const float* Ws[10] = {W1, W2, Wg1, Wg2, Wsl, Wsr, Wc0, Wc1, Wgat1, Wgat2};
    short* his[10] = {w1h, w2h, wg1h, wg2h, wslh, wsrh, wc0h, wc1h, wgat1h, wgat2h};
    short* los[10] = {w1l, w2l, wg1l, wg2l, wsll, wsrl, wc0l, wc1l, wgat1l, wgat2l};
    int Ks[10] = {128, 1024, 512, 256, 128, 128, 128, 128, 128, 128};
    int nss[10] = {10, 9, 8, 7, 7, 7, 7, 7, 8, 8};
    int off = 0;
    for (int i = 0; i < 10; i++){
      p.W[i] = Ws[i]; p.hi[i] = his[i]; p.lo[i] = los[i];
      p.K[i] = Ks[i]; p.nshift[i] = nss[i]; p.base[i] = off;
      off += Ks[i] << nss[i];
    }
    p.base[10] = off;
    k_wtall<<<cdiv(off, 256), 256, 0, stream>>>(p);
  }

  k_gather<<<cdiv(NN * 128, 256), 256, 0, stream>>>(uidx, iidx, ue, ie, x0b);

  // Phase A — MLP (two 10000-row chunks)
  for (int ofs = 0; ofs < NN; ofs += 10000){
    mm(x0b + (size_t)ofs * 128, w1h, w1l, 128, nullptr, nullptr, nullptr, 0,
       b1, h1b, 10000, 1024, GF_BIAS | GF_RELU);
    mm(h1b, w2h, w2l, 1024, nullptr, nullptr, nullptr, 0,
       b2, h2b + (size_t)ofs * 512, 10000, 512, GF_BIAS | GF_RELU);
  }

  // Phase B — GCN1 (512->256) + BN + relu
  mm(h2b, wg1h, wg1l, 512, nullptr, nullptr, nullptr, 0, nullptr, xw1b, NN, 256, 0);
  k_agg<<<cdiv(NN * 64, 256), 256, 0, stream>>>(rowptr, colsrc, xw1b, dg, nullptr, bg1, g1f, nullptr, 6, 0);
  k_bn_stats<<<cdiv(NN, 128), 256, 0, stream>>>(g1f, stats1, 256);
  k_bn_apply<<<cdiv(NN * 256, 256), 256, 0, stream>>>(g1f, stats1, gamma1, beta1, 8, NN * 256, g1b);

  // Phase C — GCN2 (256->128) + BN + relu
  mm(g1b, wg2h, wg2l, 256, nullptr, nullptr, nullptr, 0, nullptr, xw2b, NN, 128, 0);
  k_agg<<<cdiv(NN * 32, 256), 256, 0, stream>>>(rowptr, colsrc, xw2b, dg, nullptr, bg2, x3f, nullptr, 5, 0);
  k_bn_stats<<<cdiv(NN, 128), 256, 0, stream>>>(x3f, stats2, 128);
  k_bn_apply<<<cdiv(NN * 128, 256), 256, 0, stream>>>(x3f, stats2, gamma2, beta2, 7, NN * 128, x3b);

  // Phase D — SAGE
  k_agg<<<cdiv(NN * 32, 256), 256, 0, stream>>>(rowptr, colsrc, x3b, nullptr, ic, nullptr, nullptr, aggb, 5, 1);
  mm(aggb, wslh, wsll, 128, x3b, wsrh, wsrl, 128, bsl, x4b, NN, 128, GF_BIAS | GF_RELU);

  // Phase E — Cheb
  k_agg<<<cdiv(NN * 32, 256), 256, 0, stream>>>(rowptr, colsrc, x4b, dc, nullptr, nullptr, nullptr, tx1b, 5, 2);
  mm(x4b, wc0h, wc0l, 128, tx1b, wc1h, wc1l, 128, bc, x5b, NN, 128, GF_BIAS | GF_RELU);

  // Phase F — GAT1
  mm(x5b, wgat1h, wgat1l, 128, nullptr, nullptr, nullptr, 0, nullptr, xpb, NN, 256, 0);
  k_gat_alar<<<cdiv(NN, 4), 256, 0, stream>>>(xpb, as1, ad1, al, ar);
  k_gat<<<NN, 64, 0, stream>>>(rowptr, colsrc, xpb, al, ar, bgat1, x6b,
                               nullptr, nullptr, nullptr);
  k_chk_bf<<<256, 256, 0, stream>>>((const unsigned short*)x6b, NN * 128, 16, diag);

  // Phase G — GAT2 (final projection fused -> fp32 out)
  mm(x6b, wgat2h, wgat2l, 128, nullptr, nullptr, nullptr, 0, nullptr, xpb, NN, 256, 0);
  k_gat_alar<<<cdiv(NN, 4), 256, 0, stream>>>(xpb, as2, ad2, al, ar);
  k_gat<<<NN, 64, 0, stream>>>(rowptr, colsrc, xpb, al, ar, bgat2, nullptr,
                               Wp, bp, (float*)d_out);
  k_diag_out<<<cdiv(NN, 256), 256, 0, stream>>>(diag, (float*)d_out);
}